// Round 4
// baseline (893.282 us; speedup 1.0000x reference)
//
#include <hip/hip_runtime.h>
#include <hip/hip_bf16.h>
#include <math.h>
#include <stdint.h>

using bf16 = __hip_bfloat16;
typedef unsigned short u16;
typedef unsigned int   u32;

static constexpr int NN   = 20000;
static constexpr int EE   = 320000;
static constexpr int ELN  = 100000;
static constexpr int ETOT = EE + NN;
static constexpr int INC  = 256;
static constexpr int C1   = 512;
static constexpr int C2   = 128;

__device__ __forceinline__ float us2f(u16 u){ union{u32 i; float f;}x; x.i=((u32)u)<<16; return x.f; }
__device__ __forceinline__ u16  f2us(float f){ union{bf16 h; u16 u;}c; c.h=__float2bfloat16(f); return c.u; }
__device__ __forceinline__ float gelu_f(float x){
  float t = tanhf(0.7978845608028654f*(x + 0.044715f*x*x*x));
  return 0.5f*x*(1.0f+t);
}
__device__ __forceinline__ float ldel(const float* p, size_t i){ return p[i]; }
__device__ __forceinline__ float ldel(const u16* p, size_t i){ return us2f(p[i]); }
__device__ __forceinline__ void ld4v(const float* p, float* o){ float4 v=*(const float4*)p; o[0]=v.x;o[1]=v.y;o[2]=v.z;o[3]=v.w; }
__device__ __forceinline__ void ld4v(const u16* p, float* o){ uint2 v=*(const uint2*)p;
  o[0]=us2f(v.x&0xffff);o[1]=us2f(v.x>>16);o[2]=us2f(v.y&0xffff);o[3]=us2f(v.y>>16); }
__device__ __forceinline__ void ld8v(const float* p, float* o){ ld4v(p,o); ld4v(p+4,o+4); }
__device__ __forceinline__ void ld8v(const u16* p, float* o){ uint4 v=*(const uint4*)p;
  o[0]=us2f(v.x&0xffff);o[1]=us2f(v.x>>16);o[2]=us2f(v.y&0xffff);o[3]=us2f(v.y>>16);
  o[4]=us2f(v.z&0xffff);o[5]=us2f(v.z>>16);o[6]=us2f(v.w&0xffff);o[7]=us2f(v.w>>16); }
__device__ __forceinline__ void st4v(float* p, const float* v){ *(float4*)p = make_float4(v[0],v[1],v[2],v[3]); }
__device__ __forceinline__ void st4v(u16* p, const float* v){ uint2 o;
  o.x=f2us(v[0])|((u32)f2us(v[1])<<16); o.y=f2us(v[2])|((u32)f2us(v[3])<<16); *(uint2*)p=o; }
__device__ __forceinline__ void st8v(float* p, const float* v){ st4v(p,v); st4v(p+4,v+4); }
__device__ __forceinline__ void st8v(u16* p, const float* v){ uint4 o;
  o.x=f2us(v[0])|((u32)f2us(v[1])<<16); o.y=f2us(v[2])|((u32)f2us(v[3])<<16);
  o.z=f2us(v[4])|((u32)f2us(v[5])<<16); o.w=f2us(v[6])|((u32)f2us(v[7])<<16); *(uint4*)p=o; }

// ---------------- CSR ----------------
__global__ void k_hist(const int* __restrict__ ei, int* __restrict__ cnt) {
  int e = blockIdx.x*blockDim.x + threadIdx.x;
  if (e < ETOT) {
    int d = (e < EE) ? ei[EE + e] : (e - EE);
    if ((u32)d < (u32)NN) atomicAdd(&cnt[d], 1);
  }
}
__global__ void k_scan(const int* __restrict__ cnt, int* __restrict__ row_ptr) {
  __shared__ int buf[1024];
  __shared__ int carry_s;
  int tid = threadIdx.x;
  if (tid == 0) carry_s = 0;
  __syncthreads();
  for (int base = 0; base < NN; base += 1024) {
    int idx = base + tid;
    int v = (idx < NN) ? cnt[idx] : 0;
    buf[tid] = v;
    __syncthreads();
    for (int off = 1; off < 1024; off <<= 1) {
      int t = (tid >= off) ? buf[tid - off] : 0;
      __syncthreads();
      buf[tid] += t;
      __syncthreads();
    }
    if (idx < NN) row_ptr[idx] = carry_s + buf[tid] - v;
    __syncthreads();
    if (tid == 0) carry_s += buf[1023];
    __syncthreads();
  }
  if (tid == 0) row_ptr[NN] = carry_s;
}
__global__ void k_copy(const int* __restrict__ a, int* __restrict__ b) {
  int i = blockIdx.x*blockDim.x + threadIdx.x;
  if (i < NN) b[i] = a[i];
}
__global__ void k_scatter(const int* __restrict__ ei, int* __restrict__ cur,
                          int* __restrict__ col) {
  int e = blockIdx.x*blockDim.x + threadIdx.x;
  if (e < ETOT) {
    int s, d;
    if (e < EE) { s = ei[e]; d = ei[EE + e]; } else { s = d = e - EE; }
    if ((u32)d >= (u32)NN) d = 0;
    int pos = atomicAdd(&cur[d], 1);
    if ((u32)pos < (u32)ETOT) col[pos] = s;
  }
}

// ---------------- GEMM: C[M,Nc] = A[M,K] @ W[K,Nc] + bias ----------------
template <typename AT, typename CT>
__global__ __launch_bounds__(256) void k_gemm(const AT* __restrict__ A,
                                              const float* __restrict__ W,
                                              const float* __restrict__ bias,
                                              CT* __restrict__ C,
                                              int M, int Nc, int K) {
  __shared__ __align__(16) float As[16][64];
  __shared__ __align__(16) float Bs[16][64];
  int tid = threadIdx.x;
  int m0 = blockIdx.x*64, n0 = blockIdx.y*64;
  int ty = tid >> 4, tx = tid & 15;
  int lrow = tid >> 2;
  int lk   = (tid & 3)*4;
  int wk   = tid >> 4;
  int wn   = (tid & 15)*4;
  float acc[4][4] = {};
  for (int k0 = 0; k0 < K; k0 += 16) {
    int row = m0 + lrow;
    if (row < M) {
      float a4[4]; ld4v(&A[(size_t)row*K + k0 + lk], a4);
      As[lk+0][lrow]=a4[0]; As[lk+1][lrow]=a4[1]; As[lk+2][lrow]=a4[2]; As[lk+3][lrow]=a4[3];
    } else {
      #pragma unroll
      for (int j=0;j<4;++j) As[lk+j][lrow]=0.f;
    }
    {
      float4 bv4 = *(const float4*)&W[(size_t)(k0+wk)*Nc + n0 + wn];
      Bs[wk][wn+0]=bv4.x; Bs[wk][wn+1]=bv4.y; Bs[wk][wn+2]=bv4.z; Bs[wk][wn+3]=bv4.w;
    }
    __syncthreads();
    #pragma unroll
    for (int kk=0;kk<16;++kk) {
      float4 av = *(const float4*)&As[kk][ty*4];
      float4 bv = *(const float4*)&Bs[kk][tx*4];
      float a[4]={av.x,av.y,av.z,av.w}, b[4]={bv.x,bv.y,bv.z,bv.w};
      #pragma unroll
      for (int i=0;i<4;++i)
        #pragma unroll
        for (int j=0;j<4;++j)
          acc[i][j] += a[i]*b[j];
    }
    __syncthreads();
  }
  float bv[4];
  #pragma unroll
  for (int j=0;j<4;++j) bv[j] = bias[n0 + tx*4 + j];
  #pragma unroll
  for (int i=0;i<4;++i) {
    int row = m0 + ty*4 + i;
    if (row < M) {
      float o4[4] = {acc[i][0]+bv[0], acc[i][1]+bv[1], acc[i][2]+bv[2], acc[i][3]+bv[3]};
      st4v(&C[(size_t)row*Nc + n0 + tx*4], o4);
    }
  }
}

// ---------------- edge layer 1 (H=4, C=128), gelu fused ----------------
template <typename T>
__global__ __launch_bounds__(256) void k_edge1(const T* __restrict__ xl,
                                               const T* __restrict__ xr,
                                               const float* __restrict__ att,
                                               const float* __restrict__ bias,
                                               const int* __restrict__ row_ptr,
                                               const int* __restrict__ col,
                                               T* __restrict__ z1) {
  int wid = (blockIdx.x*blockDim.x + threadIdx.x) >> 6;
  if (wid >= NN) return;
  int lane = threadIdx.x & 63;
  int c8 = lane*8;
  float xi[8], av[8], acc[8] = {};
  ld8v(&xr[(size_t)wid*C1 + c8], xi);
  #pragma unroll
  for (int j=0;j<8;++j) av[j] = att[c8+j];
  float m = -1e30f, s = 0.f;
  int e0 = row_ptr[wid], e1 = row_ptr[wid+1];
  for (int e = e0; e < e1; ++e) {
    int sn = col[e]; if ((u32)sn >= (u32)NN) sn = 0;
    float xj[8];
    ld8v(&xl[(size_t)sn*C1 + c8], xj);
    float part = 0.f;
    #pragma unroll
    for (int j=0;j<8;++j) {
      float t = xi[j] + xj[j];
      t = t > 0.f ? t : 0.2f*t;      // leaky_relu 0.2
      part += t*av[j];
    }
    part += __shfl_xor(part,1); part += __shfl_xor(part,2);
    part += __shfl_xor(part,4); part += __shfl_xor(part,8);
    float mn = fmaxf(m, part);
    float f = __expf(m - mn), w = __expf(part - mn);
    s = s*f + w;
    #pragma unroll
    for (int j=0;j<8;++j) acc[j] = acc[j]*f + w*xj[j];
    m = mn;
  }
  float inv = 1.f/s, o[8];
  #pragma unroll
  for (int j=0;j<8;++j) o[j] = gelu_f(acc[j]*inv + bias[c8+j]);
  st8v(&z1[(size_t)wid*C1 + c8], o);
}

// ---------------- edge layer 2 (H=1, C=128) ----------------
__global__ __launch_bounds__(256) void k_edge2(const float* __restrict__ xl,
                                               const float* __restrict__ xr,
                                               const float* __restrict__ att,
                                               const float* __restrict__ bias,
                                               const int* __restrict__ row_ptr,
                                               const int* __restrict__ col,
                                               float* __restrict__ z2) {
  int wid = (blockIdx.x*blockDim.x + threadIdx.x) >> 6;
  if (wid >= NN) return;
  int lane = threadIdx.x & 63;
  int c2 = lane*2;
  float2 xiv = *(const float2*)(xr + (size_t)wid*C2 + c2);
  float a0 = att[c2], a1 = att[c2+1];
  float m = -1e30f, s = 0.f, ac0 = 0.f, ac1 = 0.f;
  int e0 = row_ptr[wid], e1 = row_ptr[wid+1];
  for (int e = e0; e < e1; ++e) {
    int sn = col[e]; if ((u32)sn >= (u32)NN) sn = 0;
    float2 xj = *(const float2*)(xl + (size_t)sn*C2 + c2);
    float t0 = xiv.x + xj.x; t0 = t0 > 0.f ? t0 : 0.2f*t0;
    float t1 = xiv.y + xj.y; t1 = t1 > 0.f ? t1 : 0.2f*t1;
    float part = t0*a0 + t1*a1;
    part += __shfl_xor(part,1);  part += __shfl_xor(part,2);
    part += __shfl_xor(part,4);  part += __shfl_xor(part,8);
    part += __shfl_xor(part,16); part += __shfl_xor(part,32);
    float mn = fmaxf(m, part);
    float f = __expf(m - mn), w = __expf(part - mn);
    s = s*f + w;
    ac0 = ac0*f + w*xj.x;
    ac1 = ac1*f + w*xj.y;
    m = mn;
  }
  float inv = 1.f/s;
  z2[(size_t)wid*C2 + c2]   = ac0*inv + bias[c2];
  z2[(size_t)wid*C2 + c2+1] = ac1*inv + bias[c2+1];
}

// ---------------- decoder: out = gelu(concat(z[a],z[b])@Wd1+b1)@Wd2+b2 ----------------
__global__ __launch_bounds__(256) void k_dec(const float* __restrict__ z2,
                                             const int* __restrict__ eli,
                                             const float* __restrict__ Wd1,
                                             const float* __restrict__ bd1,
                                             const float* __restrict__ Wd2,
                                             const float* __restrict__ bd2,
                                             float* __restrict__ out) {
  __shared__ __align__(16) u16 wl[256*128];   // Wd1 as bf16 bits (64 KB LDS)
  __shared__ float hb[4][256];
  int tid = threadIdx.x;
  for (int i = tid; i < 256*128; i += 256) wl[i] = f2us(Wd1[i]);
  __syncthreads();
  int wave = tid >> 6, lane = tid & 63;
  int nw = gridDim.x*4;
  int gw = blockIdx.x*4 + wave;
  float b2  = bd2[0];
  float w2a = Wd2[lane], w2b = Wd2[lane+64];
  float b1a = bd1[lane], b1b = bd1[lane+64];
  int iters = (ELN + nw - 1)/nw;
  for (int it = 0; it < iters; ++it) {
    int e = it*nw + gw;
    bool valid = e < ELN;
    int a = valid ? eli[e] : 0;       if ((u32)a >= (u32)NN) a = 0;
    int b = valid ? eli[ELN+e] : 0;   if ((u32)b >= (u32)NN) b = 0;
    hb[wave][lane]     = z2[(size_t)a*128 + lane];
    hb[wave][64+lane]  = z2[(size_t)a*128 + 64 + lane];
    hb[wave][128+lane] = z2[(size_t)b*128 + lane];
    hb[wave][192+lane] = z2[(size_t)b*128 + 64 + lane];
    __syncthreads();
    float a0 = 0.f, a1 = 0.f;
    #pragma unroll 8
    for (int k = 0; k < 256; ++k) {
      float hv = hb[wave][k];
      a0 += hv*us2f(wl[k*128 + lane]);
      a1 += hv*us2f(wl[k*128 + lane + 64]);
    }
    float g0 = gelu_f(a0 + b1a), g1 = gelu_f(a1 + b1b);
    float p = g0*w2a + g1*w2b;
    p += __shfl_xor(p,1);  p += __shfl_xor(p,2);  p += __shfl_xor(p,4);
    p += __shfl_xor(p,8);  p += __shfl_xor(p,16); p += __shfl_xor(p,32);
    if (valid && lane == 0) out[e] = p + b2;
    __syncthreads();
  }
}

__global__ void k_tiny(float* out, float code) {
  if (threadIdx.x == 0) out[0] = code;
}

// ---------------- launch ----------------
extern "C" void kernel_launch(void* const* d_in, const int* in_sizes, int n_in,
                              void* d_out, int out_size, void* d_ws, size_t ws_size,
                              hipStream_t stream) {
  const float* x     = (const float*)d_in[0];
  const int*   ei    = (const int*)  d_in[1];
  const int*   eli   = (const int*)  d_in[2];
  const float* Wl1   = (const float*)d_in[3];
  const float* bl1   = (const float*)d_in[4];
  const float* Wr1   = (const float*)d_in[5];
  const float* br1   = (const float*)d_in[6];
  const float* att1  = (const float*)d_in[7];
  const float* bias1 = (const float*)d_in[8];
  const float* Wl2   = (const float*)d_in[9];
  const float* bl2   = (const float*)d_in[10];
  const float* Wr2   = (const float*)d_in[11];
  const float* br2   = (const float*)d_in[12];
  const float* att2  = (const float*)d_in[13];
  const float* bias2 = (const float*)d_in[14];
  const float* Wd1   = (const float*)d_in[15];
  const float* bd1   = (const float*)d_in[16];
  const float* Wd2   = (const float*)d_in[17];
  const float* bd2   = (const float*)d_in[18];
  float* out = (float*)d_out;

  constexpr size_t INTW = (size_t)(NN+1) + NN + ETOT;          // 380001 words
  constexpr size_t FULL_WORDS = 3ull*NN*C1 + INTW;             // ~31.1M words = 124.4 MB
  constexpr size_t CMP_WORDS  = 3ull*NN*C1/2 + INTW;           // ~15.7M words = 63 MB

  bool full    = ws_size >= FULL_WORDS*4;
  bool compact = !full && ws_size >= CMP_WORDS*4;
  if (!full && !compact) {
    size_t mb = ws_size >> 20;
    k_tiny<<<1, 64, 0, stream>>>(out, 16384.f + (float)mb);
    return;
  }

  size_t regA = full ? (size_t)NN*C1 : (size_t)NN*C1/2;   // words per region
  char* base = (char*)d_ws;
  void* wA = base;
  void* wB = base + regA*4;
  void* wC = base + 2*regA*4;
  int* row_ptr = (int*)(base + 3*regA*4);
  int* cnt     = row_ptr + (NN + 1);
  int* col     = cnt + NN;

  float* xl2 = (float*)wA;   // layer-2 intermediates f32 (overlay, layer-1 dead)
  float* xr2 = (float*)wB;
  float* z2  = (float*)wC;

  // CSR over dst
  hipMemsetAsync(cnt, 0, NN*sizeof(int), stream);
  k_hist<<<(ETOT+255)/256, 256, 0, stream>>>(ei, cnt);
  k_scan<<<1, 1024, 0, stream>>>(cnt, row_ptr);
  k_copy<<<(NN+255)/256, 256, 0, stream>>>(row_ptr, cnt);
  k_scatter<<<(ETOT+255)/256, 256, 0, stream>>>(ei, cnt, col);

  dim3 g1((NN+63)/64, C1/64);
  dim3 g2((NN+63)/64, C2/64);

  if (full) {
    float* xl1 = (float*)wA;
    float* xr1 = (float*)wB;
    float* z1  = (float*)wC;
    k_gemm<float,float><<<g1, 256, 0, stream>>>(x, Wl1, bl1, xl1, NN, C1, INC);
    k_gemm<float,float><<<g1, 256, 0, stream>>>(x, Wr1, br1, xr1, NN, C1, INC);
    k_edge1<float><<<NN/4, 256, 0, stream>>>(xl1, xr1, att1, bias1, row_ptr, col, z1);
    k_gemm<float,float><<<g2, 256, 0, stream>>>(z1, Wl2, bl2, xl2, NN, C2, C1);
    k_gemm<float,float><<<g2, 256, 0, stream>>>(z1, Wr2, br2, xr2, NN, C2, C1);
  } else {
    u16* xl1 = (u16*)wA;
    u16* xr1 = (u16*)wB;
    u16* z1  = (u16*)wC;
    k_gemm<float,u16><<<g1, 256, 0, stream>>>(x, Wl1, bl1, xl1, NN, C1, INC);
    k_gemm<float,u16><<<g1, 256, 0, stream>>>(x, Wr1, br1, xr1, NN, C1, INC);
    k_edge1<u16><<<NN/4, 256, 0, stream>>>(xl1, xr1, att1, bias1, row_ptr, col, z1);
    k_gemm<u16,float><<<g2, 256, 0, stream>>>(z1, Wl2, bl2, xl2, NN, C2, C1);
    k_gemm<u16,float><<<g2, 256, 0, stream>>>(z1, Wr2, br2, xr2, NN, C2, C1);
  }

  k_edge2<<<NN/4, 256, 0, stream>>>(xl2, xr2, att2, bias2, row_ptr, col, z2);
  k_dec<<<512, 256, 0, stream>>>(z2, eli, Wd1, bd1, Wd2, bd2, out);
}

// Round 5
// 667.040 us; speedup vs baseline: 1.3392x; 1.3392x over previous
//
#include <hip/hip_runtime.h>
#include <hip/hip_bf16.h>
#include <math.h>
#include <stdint.h>

using bf16 = __hip_bfloat16;
typedef unsigned short u16;
typedef unsigned int   u32;

static constexpr int NN   = 20000;
static constexpr int EE   = 320000;
static constexpr int ELN  = 100000;
static constexpr int ETOT = EE + NN;
static constexpr int INC  = 256;
static constexpr int C1   = 512;
static constexpr int C2   = 128;
static constexpr int NB   = (NN + 255) / 256;   // scan blocks = 79

__device__ __forceinline__ float us2f(u16 u){ union{u32 i; float f;}x; x.i=((u32)u)<<16; return x.f; }
__device__ __forceinline__ u16  f2us(float f){ union{bf16 h; u16 u;}c; c.h=__float2bfloat16(f); return c.u; }
__device__ __forceinline__ float gelu_f(float x){
  float t = tanhf(0.7978845608028654f*(x + 0.044715f*x*x*x));
  return 0.5f*x*(1.0f+t);
}
__device__ __forceinline__ void ld4v(const float* p, float* o){ float4 v=*(const float4*)p; o[0]=v.x;o[1]=v.y;o[2]=v.z;o[3]=v.w; }
__device__ __forceinline__ void ld4v(const u16* p, float* o){ uint2 v=*(const uint2*)p;
  o[0]=us2f(v.x&0xffff);o[1]=us2f(v.x>>16);o[2]=us2f(v.y&0xffff);o[3]=us2f(v.y>>16); }
__device__ __forceinline__ void ld8v(const float* p, float* o){ ld4v(p,o); ld4v(p+4,o+4); }
__device__ __forceinline__ void ld8v(const u16* p, float* o){ uint4 v=*(const uint4*)p;
  o[0]=us2f(v.x&0xffff);o[1]=us2f(v.x>>16);o[2]=us2f(v.y&0xffff);o[3]=us2f(v.y>>16);
  o[4]=us2f(v.z&0xffff);o[5]=us2f(v.z>>16);o[6]=us2f(v.w&0xffff);o[7]=us2f(v.w>>16); }
__device__ __forceinline__ void st4v(float* p, const float* v){ *(float4*)p = make_float4(v[0],v[1],v[2],v[3]); }
__device__ __forceinline__ void st4v(u16* p, const float* v){ uint2 o;
  o.x=f2us(v[0])|((u32)f2us(v[1])<<16); o.y=f2us(v[2])|((u32)f2us(v[3])<<16); *(uint2*)p=o; }
__device__ __forceinline__ void st8v(float* p, const float* v){ st4v(p,v); st4v(p+4,v+4); }
__device__ __forceinline__ void st8v(u16* p, const float* v){ uint4 o;
  o.x=f2us(v[0])|((u32)f2us(v[1])<<16); o.y=f2us(v[2])|((u32)f2us(v[3])<<16);
  o.z=f2us(v[4])|((u32)f2us(v[5])<<16); o.w=f2us(v[6])|((u32)f2us(v[7])<<16); *(uint4*)p=o; }

// ---------------- CSR ----------------
__global__ void k_hist(const int* __restrict__ ei, int* __restrict__ cnt) {
  int e = blockIdx.x*blockDim.x + threadIdx.x;
  if (e < ETOT) {
    int d = (e < EE) ? ei[EE + e] : (e - EE);
    if ((u32)d < (u32)NN) atomicAdd(&cnt[d], 1);
  }
}
// hierarchical exclusive scan: a) per-block scan + block sums, b) scan sums, c) add offsets
__global__ void k_scan_a(const int* __restrict__ cnt, int* __restrict__ row_ptr,
                         int* __restrict__ bsum) {
  __shared__ int buf[256];
  int idx = blockIdx.x*256 + threadIdx.x;
  int v = (idx < NN) ? cnt[idx] : 0;
  buf[threadIdx.x] = v;
  __syncthreads();
  for (int off = 1; off < 256; off <<= 1) {
    int t = (threadIdx.x >= off) ? buf[threadIdx.x - off] : 0;
    __syncthreads();
    buf[threadIdx.x] += t;
    __syncthreads();
  }
  if (idx < NN) row_ptr[idx] = buf[threadIdx.x] - v;   // exclusive within block
  if (threadIdx.x == 255) bsum[blockIdx.x] = buf[255];
}
__global__ void k_scan_b(int* __restrict__ bsum, int* __restrict__ row_ptr) {
  __shared__ int buf[128];
  int v = (threadIdx.x < NB) ? bsum[threadIdx.x] : 0;
  buf[threadIdx.x] = v;
  __syncthreads();
  for (int off = 1; off < 128; off <<= 1) {
    int t = (threadIdx.x >= off) ? buf[threadIdx.x - off] : 0;
    __syncthreads();
    buf[threadIdx.x] += t;
    __syncthreads();
  }
  if (threadIdx.x < NB) bsum[threadIdx.x] = buf[threadIdx.x] - v;  // exclusive
  if (threadIdx.x == 127) row_ptr[NN] = buf[127];                  // total
}
__global__ void k_scan_c(int* __restrict__ row_ptr, const int* __restrict__ bsum) {
  int idx = blockIdx.x*256 + threadIdx.x;
  if (idx < NN) row_ptr[idx] += bsum[blockIdx.x];
}
__global__ void k_copy(const int* __restrict__ a, int* __restrict__ b) {
  int i = blockIdx.x*blockDim.x + threadIdx.x;
  if (i < NN) b[i] = a[i];
}
__global__ void k_scatter(const int* __restrict__ ei, int* __restrict__ cur,
                          int* __restrict__ col) {
  int e = blockIdx.x*blockDim.x + threadIdx.x;
  if (e < ETOT) {
    int s, d;
    if (e < EE) { s = ei[e]; d = ei[EE + e]; } else { s = d = e - EE; }
    if ((u32)d >= (u32)NN) d = 0;
    int pos = atomicAdd(&cur[d], 1);
    if ((u32)pos < (u32)ETOT) col[pos] = s;
  }
}

// ---------------- GEMM: C[M,Nc] = A[M,K] @ W[K,Nc] + bias ----------------
template <typename AT, typename CT>
__global__ __launch_bounds__(256) void k_gemm(const AT* __restrict__ A,
                                              const float* __restrict__ W,
                                              const float* __restrict__ bias,
                                              CT* __restrict__ C,
                                              int M, int Nc, int K) {
  __shared__ __align__(16) float As[16][64];
  __shared__ __align__(16) float Bs[16][64];
  int tid = threadIdx.x;
  int m0 = blockIdx.x*64, n0 = blockIdx.y*64;
  int ty = tid >> 4, tx = tid & 15;
  int lrow = tid >> 2;
  int lk   = (tid & 3)*4;
  int wk   = tid >> 4;
  int wn   = (tid & 15)*4;
  float acc[4][4] = {};
  for (int k0 = 0; k0 < K; k0 += 16) {
    int row = m0 + lrow;
    if (row < M) {
      float a4[4]; ld4v(&A[(size_t)row*K + k0 + lk], a4);
      As[lk+0][lrow]=a4[0]; As[lk+1][lrow]=a4[1]; As[lk+2][lrow]=a4[2]; As[lk+3][lrow]=a4[3];
    } else {
      #pragma unroll
      for (int j=0;j<4;++j) As[lk+j][lrow]=0.f;
    }
    {
      float4 bv4 = *(const float4*)&W[(size_t)(k0+wk)*Nc + n0 + wn];
      Bs[wk][wn+0]=bv4.x; Bs[wk][wn+1]=bv4.y; Bs[wk][wn+2]=bv4.z; Bs[wk][wn+3]=bv4.w;
    }
    __syncthreads();
    #pragma unroll
    for (int kk=0;kk<16;++kk) {
      float4 av = *(const float4*)&As[kk][ty*4];
      float4 bv = *(const float4*)&Bs[kk][tx*4];
      float a[4]={av.x,av.y,av.z,av.w}, b[4]={bv.x,bv.y,bv.z,bv.w};
      #pragma unroll
      for (int i=0;i<4;++i)
        #pragma unroll
        for (int j=0;j<4;++j)
          acc[i][j] += a[i]*b[j];
    }
    __syncthreads();
  }
  float bv[4];
  #pragma unroll
  for (int j=0;j<4;++j) bv[j] = bias[n0 + tx*4 + j];
  #pragma unroll
  for (int i=0;i<4;++i) {
    int row = m0 + ty*4 + i;
    if (row < M) {
      float o4[4] = {acc[i][0]+bv[0], acc[i][1]+bv[1], acc[i][2]+bv[2], acc[i][3]+bv[3]};
      st4v(&C[(size_t)row*Nc + n0 + tx*4], o4);
    }
  }
}

// ---------------- edge layer 1 (H=4, C=128), gelu fused ----------------
template <typename T>
__global__ __launch_bounds__(256) void k_edge1(const T* __restrict__ xl,
                                               const T* __restrict__ xr,
                                               const float* __restrict__ att,
                                               const float* __restrict__ bias,
                                               const int* __restrict__ row_ptr,
                                               const int* __restrict__ col,
                                               T* __restrict__ z1) {
  int wid = (blockIdx.x*blockDim.x + threadIdx.x) >> 6;
  if (wid >= NN) return;
  int lane = threadIdx.x & 63;
  int c8 = lane*8;
  float xi[8], av[8], acc[8] = {};
  ld8v(&xr[(size_t)wid*C1 + c8], xi);
  #pragma unroll
  for (int j=0;j<8;++j) av[j] = att[c8+j];
  float m = -1e30f, s = 0.f;
  int e0 = row_ptr[wid], e1 = row_ptr[wid+1];
  for (int e = e0; e < e1; ++e) {
    int sn = col[e]; if ((u32)sn >= (u32)NN) sn = 0;
    float xj[8];
    ld8v(&xl[(size_t)sn*C1 + c8], xj);
    float part = 0.f;
    #pragma unroll
    for (int j=0;j<8;++j) {
      float t = xi[j] + xj[j];
      t = t > 0.f ? t : 0.2f*t;      // leaky_relu 0.2
      part += t*av[j];
    }
    part += __shfl_xor(part,1); part += __shfl_xor(part,2);
    part += __shfl_xor(part,4); part += __shfl_xor(part,8);
    float mn = fmaxf(m, part);
    float f = __expf(m - mn), w = __expf(part - mn);
    s = s*f + w;
    #pragma unroll
    for (int j=0;j<8;++j) acc[j] = acc[j]*f + w*xj[j];
    m = mn;
  }
  float inv = 1.f/s, o[8];
  #pragma unroll
  for (int j=0;j<8;++j) o[j] = gelu_f(acc[j]*inv + bias[c8+j]);
  st8v(&z1[(size_t)wid*C1 + c8], o);
}

// ---------------- edge layer 2 (H=1, C=128) ----------------
__global__ __launch_bounds__(256) void k_edge2(const float* __restrict__ xl,
                                               const float* __restrict__ xr,
                                               const float* __restrict__ att,
                                               const float* __restrict__ bias,
                                               const int* __restrict__ row_ptr,
                                               const int* __restrict__ col,
                                               float* __restrict__ z2) {
  int wid = (blockIdx.x*blockDim.x + threadIdx.x) >> 6;
  if (wid >= NN) return;
  int lane = threadIdx.x & 63;
  int c2 = lane*2;
  float2 xiv = *(const float2*)(xr + (size_t)wid*C2 + c2);
  float a0 = att[c2], a1 = att[c2+1];
  float m = -1e30f, s = 0.f, ac0 = 0.f, ac1 = 0.f;
  int e0 = row_ptr[wid], e1 = row_ptr[wid+1];
  for (int e = e0; e < e1; ++e) {
    int sn = col[e]; if ((u32)sn >= (u32)NN) sn = 0;
    float2 xj = *(const float2*)(xl + (size_t)sn*C2 + c2);
    float t0 = xiv.x + xj.x; t0 = t0 > 0.f ? t0 : 0.2f*t0;
    float t1 = xiv.y + xj.y; t1 = t1 > 0.f ? t1 : 0.2f*t1;
    float part = t0*a0 + t1*a1;
    part += __shfl_xor(part,1);  part += __shfl_xor(part,2);
    part += __shfl_xor(part,4);  part += __shfl_xor(part,8);
    part += __shfl_xor(part,16); part += __shfl_xor(part,32);
    float mn = fmaxf(m, part);
    float f = __expf(m - mn), w = __expf(part - mn);
    s = s*f + w;
    ac0 = ac0*f + w*xj.x;
    ac1 = ac1*f + w*xj.y;
    m = mn;
  }
  float inv = 1.f/s;
  z2[(size_t)wid*C2 + c2]   = ac0*inv + bias[c2];
  z2[(size_t)wid*C2 + c2+1] = ac1*inv + bias[c2+1];
}

// ---------------- decoder as tiled GEMM: 64 edges x 128 hidden per block ----------------
// h[e] = concat(z2[a], z2[b]) (256); hid = gelu(h @ Wd1 + bd1); out = hid . Wd2 + bd2
__global__ __launch_bounds__(256) void k_dec2(const float* __restrict__ z2,
                                              const int* __restrict__ eli,
                                              const float* __restrict__ Wd1,
                                              const float* __restrict__ bd1,
                                              const float* __restrict__ Wd2,
                                              const float* __restrict__ bd2,
                                              float* __restrict__ out) {
  __shared__ __align__(16) float As[16][64];    // [k][edge]
  __shared__ __align__(16) float Bs[16][128];   // [k][hid]
  int tid = threadIdx.x;
  int e0 = blockIdx.x * 64;
  int ty = tid >> 4, tx = tid & 15;       // compute map: rows ty*4+i, cols tx*8+j
  int lrow = tid >> 2;                    // A-load: edge within tile (0..63)
  int lk   = (tid & 3) * 4;               // A-load: k offset {0,4,8,12}
  int wk   = tid >> 4;                    // B-load: k row (0..15)
  int wn   = (tid & 15) * 8;              // B-load: hid cols (8 each)
  int e = e0 + lrow;
  bool ev = e < ELN;
  int ia = ev ? eli[e] : 0;       if ((u32)ia >= (u32)NN) ia = 0;
  int ib = ev ? eli[ELN+e] : 0;   if ((u32)ib >= (u32)NN) ib = 0;
  float acc[4][8] = {};
  for (int k0 = 0; k0 < 256; k0 += 16) {
    int kk4 = k0 + lk;   // multiple of 4; never straddles the 128 boundary
    const float* src = (kk4 < 128) ? &z2[(size_t)ia*128 + kk4]
                                   : &z2[(size_t)ib*128 + (kk4 - 128)];
    float4 a4 = ev ? *(const float4*)src : make_float4(0.f,0.f,0.f,0.f);
    As[lk+0][lrow]=a4.x; As[lk+1][lrow]=a4.y; As[lk+2][lrow]=a4.z; As[lk+3][lrow]=a4.w;
    *(float4*)&Bs[wk][wn]   = *(const float4*)&Wd1[(size_t)(k0+wk)*128 + wn];
    *(float4*)&Bs[wk][wn+4] = *(const float4*)&Wd1[(size_t)(k0+wk)*128 + wn + 4];
    __syncthreads();
    #pragma unroll
    for (int kk = 0; kk < 16; ++kk) {
      float4 av = *(const float4*)&As[kk][ty*4];
      float a[4] = {av.x, av.y, av.z, av.w};
      float4 b0 = *(const float4*)&Bs[kk][tx*8];
      float4 b1 = *(const float4*)&Bs[kk][tx*8+4];
      float b[8] = {b0.x,b0.y,b0.z,b0.w,b1.x,b1.y,b1.z,b1.w};
      #pragma unroll
      for (int i = 0; i < 4; ++i)
        #pragma unroll
        for (int j = 0; j < 8; ++j)
          acc[i][j] += a[i]*b[j];
    }
    __syncthreads();
  }
  // epilogue: gelu + dot with Wd2, reduce over tx (16 lanes), write per-row scalar
  float w2[8], bb[8];
  #pragma unroll
  for (int j = 0; j < 8; ++j) { w2[j] = Wd2[tx*8+j]; bb[j] = bd1[tx*8+j]; }
  float b2 = bd2[0];
  #pragma unroll
  for (int i = 0; i < 4; ++i) {
    float part = 0.f;
    #pragma unroll
    for (int j = 0; j < 8; ++j)
      part += gelu_f(acc[i][j] + bb[j]) * w2[j];
    part += __shfl_xor(part,1); part += __shfl_xor(part,2);
    part += __shfl_xor(part,4); part += __shfl_xor(part,8);
    int row = e0 + ty*4 + i;
    if (tx == 0 && row < ELN) out[row] = part + b2;
  }
}

__global__ void k_tiny(float* out, float code) {
  if (threadIdx.x == 0) out[0] = code;
}

// ---------------- launch ----------------
extern "C" void kernel_launch(void* const* d_in, const int* in_sizes, int n_in,
                              void* d_out, int out_size, void* d_ws, size_t ws_size,
                              hipStream_t stream) {
  const float* x     = (const float*)d_in[0];
  const int*   ei    = (const int*)  d_in[1];
  const int*   eli   = (const int*)  d_in[2];
  const float* Wl1   = (const float*)d_in[3];
  const float* bl1   = (const float*)d_in[4];
  const float* Wr1   = (const float*)d_in[5];
  const float* br1   = (const float*)d_in[6];
  const float* att1  = (const float*)d_in[7];
  const float* bias1 = (const float*)d_in[8];
  const float* Wl2   = (const float*)d_in[9];
  const float* bl2   = (const float*)d_in[10];
  const float* Wr2   = (const float*)d_in[11];
  const float* br2   = (const float*)d_in[12];
  const float* att2  = (const float*)d_in[13];
  const float* bias2 = (const float*)d_in[14];
  const float* Wd1   = (const float*)d_in[15];
  const float* bd1   = (const float*)d_in[16];
  const float* Wd2   = (const float*)d_in[17];
  const float* bd2   = (const float*)d_in[18];
  float* out = (float*)d_out;

  constexpr size_t INTW = (size_t)(NN+1) + NN + ETOT;          // 380001 words
  constexpr size_t FULL_WORDS = 3ull*NN*C1 + INTW;             // ~124.4 MB
  constexpr size_t CMP_WORDS  = 3ull*NN*C1/2 + INTW;           // ~63 MB

  bool full    = ws_size >= FULL_WORDS*4;
  bool compact = !full && ws_size >= CMP_WORDS*4;
  if (!full && !compact) {
    size_t mb = ws_size >> 20;
    k_tiny<<<1, 64, 0, stream>>>(out, 16384.f + (float)mb);
    return;
  }

  size_t regA = full ? (size_t)NN*C1 : (size_t)NN*C1/2;   // words per region
  char* base = (char*)d_ws;
  void* wA = base;
  void* wB = base + regA*4;
  void* wC = base + 2*regA*4;
  int* row_ptr = (int*)(base + 3*regA*4);
  int* cnt     = row_ptr + (NN + 1);
  int* col     = cnt + NN;
  int* bsum    = (int*)wA;   // scan scratch: wA region is dead during CSR phase

  float* xl2 = (float*)wA;   // layer-2 intermediates f32 (overlay, layer-1 dead)
  float* xr2 = (float*)wB;
  float* z2  = (float*)wC;

  // CSR over dst
  hipMemsetAsync(cnt, 0, NN*sizeof(int), stream);
  k_hist<<<(ETOT+255)/256, 256, 0, stream>>>(ei, cnt);
  k_scan_a<<<NB, 256, 0, stream>>>(cnt, row_ptr, bsum);
  k_scan_b<<<1, 128, 0, stream>>>(bsum, row_ptr);
  k_scan_c<<<NB, 256, 0, stream>>>(row_ptr, bsum);
  k_copy<<<(NN+255)/256, 256, 0, stream>>>(row_ptr, cnt);
  k_scatter<<<(ETOT+255)/256, 256, 0, stream>>>(ei, cnt, col);

  dim3 g1((NN+63)/64, C1/64);
  dim3 g2((NN+63)/64, C2/64);

  if (full) {
    float* xl1 = (float*)wA;
    float* xr1 = (float*)wB;
    float* z1  = (float*)wC;
    k_gemm<float,float><<<g1, 256, 0, stream>>>(x, Wl1, bl1, xl1, NN, C1, INC);
    k_gemm<float,float><<<g1, 256, 0, stream>>>(x, Wr1, br1, xr1, NN, C1, INC);
    k_edge1<float><<<NN/4, 256, 0, stream>>>(xl1, xr1, att1, bias1, row_ptr, col, z1);
    k_gemm<float,float><<<g2, 256, 0, stream>>>(z1, Wl2, bl2, xl2, NN, C2, C1);
    k_gemm<float,float><<<g2, 256, 0, stream>>>(z1, Wr2, br2, xr2, NN, C2, C1);
  } else {
    u16* xl1 = (u16*)wA;
    u16* xr1 = (u16*)wB;
    u16* z1  = (u16*)wC;
    k_gemm<float,u16><<<g1, 256, 0, stream>>>(x, Wl1, bl1, xl1, NN, C1, INC);
    k_gemm<float,u16><<<g1, 256, 0, stream>>>(x, Wr1, br1, xr1, NN, C1, INC);
    k_edge1<u16><<<NN/4, 256, 0, stream>>>(xl1, xr1, att1, bias1, row_ptr, col, z1);
    k_gemm<u16,float><<<g2, 256, 0, stream>>>(z1, Wl2, bl2, xl2, NN, C2, C1);
    k_gemm<u16,float><<<g2, 256, 0, stream>>>(z1, Wr2, br2, xr2, NN, C2, C1);
  }

  k_edge2<<<NN/4, 256, 0, stream>>>(xl2, xr2, att2, bias2, row_ptr, col, z2);
  k_dec2<<<(ELN+63)/64, 256, 0, stream>>>(z2, eli, Wd1, bd1, Wd2, bd2, out);
}

// Round 6
// 573.418 us; speedup vs baseline: 1.5578x; 1.1633x over previous
//
#include <hip/hip_runtime.h>
#include <hip/hip_bf16.h>
#include <math.h>
#include <stdint.h>

using bf16 = __hip_bfloat16;
typedef unsigned short u16;
typedef unsigned int   u32;
typedef __attribute__((ext_vector_type(8))) short short8;   // 8 bf16 bit patterns
typedef __attribute__((ext_vector_type(4))) float f32x4;

static constexpr int NN   = 20000;
static constexpr int EE   = 320000;
static constexpr int ELN  = 100000;
static constexpr int ETOT = EE + NN;
static constexpr int INC  = 256;
static constexpr int C1   = 512;
static constexpr int C2   = 128;
static constexpr int NB   = (NN + 255) / 256;   // scan blocks = 79

__device__ __forceinline__ float us2f(u16 u){ union{u32 i; float f;}x; x.i=((u32)u)<<16; return x.f; }
__device__ __forceinline__ u16  f2us(float f){ union{bf16 h; u16 u;}c; c.h=__float2bfloat16(f); return c.u; }
__device__ __forceinline__ float gelu_f(float x){
  float t = tanhf(0.7978845608028654f*(x + 0.044715f*x*x*x));
  return 0.5f*x*(1.0f+t);
}
__device__ __forceinline__ void ld4v(const float* p, float* o){ float4 v=*(const float4*)p; o[0]=v.x;o[1]=v.y;o[2]=v.z;o[3]=v.w; }
__device__ __forceinline__ void ld4v(const u16* p, float* o){ uint2 v=*(const uint2*)p;
  o[0]=us2f(v.x&0xffff);o[1]=us2f(v.x>>16);o[2]=us2f(v.y&0xffff);o[3]=us2f(v.y>>16); }
__device__ __forceinline__ void ld8v(const float* p, float* o){ ld4v(p,o); ld4v(p+4,o+4); }
__device__ __forceinline__ void ld8v(const u16* p, float* o){ uint4 v=*(const uint4*)p;
  o[0]=us2f(v.x&0xffff);o[1]=us2f(v.x>>16);o[2]=us2f(v.y&0xffff);o[3]=us2f(v.y>>16);
  o[4]=us2f(v.z&0xffff);o[5]=us2f(v.z>>16);o[6]=us2f(v.w&0xffff);o[7]=us2f(v.w>>16); }
__device__ __forceinline__ void st4v(float* p, const float* v){ *(float4*)p = make_float4(v[0],v[1],v[2],v[3]); }
__device__ __forceinline__ void st4v(u16* p, const float* v){ uint2 o;
  o.x=f2us(v[0])|((u32)f2us(v[1])<<16); o.y=f2us(v[2])|((u32)f2us(v[3])<<16); *(uint2*)p=o; }
__device__ __forceinline__ void st8v(float* p, const float* v){ st4v(p,v); st4v(p+4,v+4); }
__device__ __forceinline__ void st8v(u16* p, const float* v){ uint4 o;
  o.x=f2us(v[0])|((u32)f2us(v[1])<<16); o.y=f2us(v[2])|((u32)f2us(v[3])<<16);
  o.z=f2us(v[4])|((u32)f2us(v[5])<<16); o.w=f2us(v[6])|((u32)f2us(v[7])<<16); *(uint4*)p=o; }

// ---------------- CSR ----------------
__global__ void k_hist(const int* __restrict__ ei, int* __restrict__ cnt) {
  int e = blockIdx.x*blockDim.x + threadIdx.x;
  if (e < ETOT) {
    int d = (e < EE) ? ei[EE + e] : (e - EE);
    if ((u32)d < (u32)NN) atomicAdd(&cnt[d], 1);
  }
}
__global__ void k_scan_a(const int* __restrict__ cnt, int* __restrict__ row_ptr,
                         int* __restrict__ bsum) {
  __shared__ int buf[256];
  int idx = blockIdx.x*256 + threadIdx.x;
  int v = (idx < NN) ? cnt[idx] : 0;
  buf[threadIdx.x] = v;
  __syncthreads();
  for (int off = 1; off < 256; off <<= 1) {
    int t = (threadIdx.x >= off) ? buf[threadIdx.x - off] : 0;
    __syncthreads();
    buf[threadIdx.x] += t;
    __syncthreads();
  }
  if (idx < NN) row_ptr[idx] = buf[threadIdx.x] - v;
  if (threadIdx.x == 255) bsum[blockIdx.x] = buf[255];
}
__global__ void k_scan_b(int* __restrict__ bsum, int* __restrict__ row_ptr) {
  __shared__ int buf[128];
  int v = (threadIdx.x < NB) ? bsum[threadIdx.x] : 0;
  buf[threadIdx.x] = v;
  __syncthreads();
  for (int off = 1; off < 128; off <<= 1) {
    int t = (threadIdx.x >= off) ? buf[threadIdx.x - off] : 0;
    __syncthreads();
    buf[threadIdx.x] += t;
    __syncthreads();
  }
  if (threadIdx.x < NB) bsum[threadIdx.x] = buf[threadIdx.x] - v;
  if (threadIdx.x == 127) row_ptr[NN] = buf[127];
}
__global__ void k_scan_c(int* __restrict__ row_ptr, const int* __restrict__ bsum) {
  int idx = blockIdx.x*256 + threadIdx.x;
  if (idx < NN) row_ptr[idx] += bsum[blockIdx.x];
}
__global__ void k_copy(const int* __restrict__ a, int* __restrict__ b) {
  int i = blockIdx.x*blockDim.x + threadIdx.x;
  if (i < NN) b[i] = a[i];
}
__global__ void k_scatter(const int* __restrict__ ei, int* __restrict__ cur,
                          int* __restrict__ col) {
  int e = blockIdx.x*blockDim.x + threadIdx.x;
  if (e < ETOT) {
    int s, d;
    if (e < EE) { s = ei[e]; d = ei[EE + e]; } else { s = d = e - EE; }
    if ((u32)d >= (u32)NN) d = 0;
    int pos = atomicAdd(&cur[d], 1);
    if ((u32)pos < (u32)ETOT) col[pos] = s;
  }
}

// ---------------- weight transpose + hi/lo split: W[K,N] f32 -> Th/Tl[N,K] bf16 ----------------
__global__ void k_wsplit(const float* __restrict__ W, u16* __restrict__ Th,
                         u16* __restrict__ Tl, int K, int N) {
  int idx = blockIdx.x*256 + threadIdx.x;
  if (idx >= K*N) return;
  int n = idx / K, k = idx - n*K;
  float v = W[(size_t)k*N + n];
  u16 h = f2us(v);
  Th[idx] = h;
  Tl[idx] = f2us(v - us2f(h));
}

// ---------------- MFMA GEMM: C[M,N] = A[M,K](f32) @ B + bias ----------------
// B given as transposed hi/lo bf16 planes Bt[N][K]. A split to hi/lo in staging.
// D = Ah*Bh + Ah*Bl + Al*Bh  (error ~2^-18 relative, f32-equivalent here).
// BM=128, BN=128, BK=32; 256 thr = 4 waves; wave w owns 64x64: (m=(w&1)*64, n=(w>>1)*64).
__global__ __launch_bounds__(256, 2)
void k_mgemm(const float* __restrict__ A,
             const u16* __restrict__ Bth, const u16* __restrict__ Btl,
             const float* __restrict__ bias, float* __restrict__ C,
             int M, int N, int K) {
  __shared__ __align__(16) u16 Ah[128][32], Al[128][32];
  __shared__ __align__(16) u16 Bh[128][32], Bl[128][32];
  int tid = threadIdx.x;
  int m0 = blockIdx.x * 128, n0 = blockIdx.y * 128;
  int wave = tid >> 6, lane = tid & 63;
  int wm = (wave & 1) * 64, wn = (wave >> 1) * 64;
  int l15 = lane & 15, quad = lane >> 4;
  f32x4 acc[4][4] = {};            // [i=m-tile][j=n-tile]
  int ar = tid >> 3;               // A staging: rows ar+32*i
  int ak = (tid & 7) * 4;          // A staging: k offset
  int bn = tid >> 2;               // B staging: rows bn+64*i
  int bc = (tid & 3) * 8;          // B staging: k offset (8 bf16 = 16B)
  for (int k0 = 0; k0 < K; k0 += 32) {
    #pragma unroll
    for (int i = 0; i < 4; ++i) {
      int row = ar + 32*i;
      int gr = m0 + row;
      float4 v = (gr < M) ? *(const float4*)&A[(size_t)gr*K + k0 + ak]
                          : make_float4(0.f,0.f,0.f,0.f);
      float hv[4] = {v.x, v.y, v.z, v.w};
      u16 hi[4], lo[4];
      #pragma unroll
      for (int j = 0; j < 4; ++j) {
        hi[j] = f2us(hv[j]);
        lo[j] = f2us(hv[j] - us2f(hi[j]));
      }
      *(uint2*)&Ah[row][ak] = make_uint2(hi[0]|((u32)hi[1]<<16), hi[2]|((u32)hi[3]<<16));
      *(uint2*)&Al[row][ak] = make_uint2(lo[0]|((u32)lo[1]<<16), lo[2]|((u32)lo[3]<<16));
    }
    #pragma unroll
    for (int i = 0; i < 2; ++i) {
      int n = bn + 64*i;   // N and grid are exact multiples of 128 -> no guard
      *(uint4*)&Bh[n][bc] = *(const uint4*)&Bth[(size_t)(n0+n)*K + k0 + bc];
      *(uint4*)&Bl[n][bc] = *(const uint4*)&Btl[(size_t)(n0+n)*K + k0 + bc];
    }
    __syncthreads();
    short8 af_h[4], af_l[4], bf_h[4], bf_l[4];
    #pragma unroll
    for (int i = 0; i < 4; ++i) {
      af_h[i] = *(const short8*)&Ah[wm + i*16 + l15][quad*8];
      af_l[i] = *(const short8*)&Al[wm + i*16 + l15][quad*8];
      bf_h[i] = *(const short8*)&Bh[wn + i*16 + l15][quad*8];
      bf_l[i] = *(const short8*)&Bl[wn + i*16 + l15][quad*8];
    }
    #pragma unroll
    for (int i = 0; i < 4; ++i)
      #pragma unroll
      for (int j = 0; j < 4; ++j) {
        acc[i][j] = __builtin_amdgcn_mfma_f32_16x16x32_bf16(af_h[i], bf_l[j], acc[i][j], 0,0,0);
        acc[i][j] = __builtin_amdgcn_mfma_f32_16x16x32_bf16(af_l[i], bf_h[j], acc[i][j], 0,0,0);
        acc[i][j] = __builtin_amdgcn_mfma_f32_16x16x32_bf16(af_h[i], bf_h[j], acc[i][j], 0,0,0);
      }
    __syncthreads();
  }
  // epilogue: C/D layout col=lane&15, row=quad*4+r (verified m89/m91)
  #pragma unroll
  for (int j = 0; j < 4; ++j) {
    int col = n0 + wn + j*16 + l15;
    float bv = bias[col];
    #pragma unroll
    for (int i = 0; i < 4; ++i) {
      int rbase = m0 + wm + i*16 + quad*4;
      #pragma unroll
      for (int r = 0; r < 4; ++r) {
        int row = rbase + r;
        if (row < M) C[(size_t)row*N + col] = acc[i][j][r] + bv;
      }
    }
  }
}

// ---------------- fallback f32 GEMM (compact path only) ----------------
template <typename AT, typename CT>
__global__ __launch_bounds__(256) void k_gemm(const AT* __restrict__ A,
                                              const float* __restrict__ W,
                                              const float* __restrict__ bias,
                                              CT* __restrict__ C,
                                              int M, int Nc, int K) {
  __shared__ __align__(16) float As[16][64];
  __shared__ __align__(16) float Bs[16][64];
  int tid = threadIdx.x;
  int m0 = blockIdx.x*64, n0 = blockIdx.y*64;
  int ty = tid >> 4, tx = tid & 15;
  int lrow = tid >> 2;
  int lk   = (tid & 3)*4;
  int wk   = tid >> 4;
  int wn   = (tid & 15)*4;
  float acc[4][4] = {};
  for (int k0 = 0; k0 < K; k0 += 16) {
    int row = m0 + lrow;
    if (row < M) {
      float a4[4]; ld4v(&A[(size_t)row*K + k0 + lk], a4);
      As[lk+0][lrow]=a4[0]; As[lk+1][lrow]=a4[1]; As[lk+2][lrow]=a4[2]; As[lk+3][lrow]=a4[3];
    } else {
      #pragma unroll
      for (int j=0;j<4;++j) As[lk+j][lrow]=0.f;
    }
    {
      float4 bv4 = *(const float4*)&W[(size_t)(k0+wk)*Nc + n0 + wn];
      Bs[wk][wn+0]=bv4.x; Bs[wk][wn+1]=bv4.y; Bs[wk][wn+2]=bv4.z; Bs[wk][wn+3]=bv4.w;
    }
    __syncthreads();
    #pragma unroll
    for (int kk=0;kk<16;++kk) {
      float4 av = *(const float4*)&As[kk][ty*4];
      float4 bv = *(const float4*)&Bs[kk][tx*4];
      float a[4]={av.x,av.y,av.z,av.w}, b[4]={bv.x,bv.y,bv.z,bv.w};
      #pragma unroll
      for (int i=0;i<4;++i)
        #pragma unroll
        for (int j=0;j<4;++j)
          acc[i][j] += a[i]*b[j];
    }
    __syncthreads();
  }
  float bv[4];
  #pragma unroll
  for (int j=0;j<4;++j) bv[j] = bias[n0 + tx*4 + j];
  #pragma unroll
  for (int i=0;i<4;++i) {
    int row = m0 + ty*4 + i;
    if (row < M) {
      float o4[4] = {acc[i][0]+bv[0], acc[i][1]+bv[1], acc[i][2]+bv[2], acc[i][3]+bv[3]};
      st4v(&C[(size_t)row*Nc + n0 + tx*4], o4);
    }
  }
}

// ---------------- edge layer 1 (H=4, C=128), gelu fused ----------------
template <typename T>
__global__ __launch_bounds__(256) void k_edge1(const T* __restrict__ xl,
                                               const T* __restrict__ xr,
                                               const float* __restrict__ att,
                                               const float* __restrict__ bias,
                                               const int* __restrict__ row_ptr,
                                               const int* __restrict__ col,
                                               T* __restrict__ z1) {
  int wid = (blockIdx.x*blockDim.x + threadIdx.x) >> 6;
  if (wid >= NN) return;
  int lane = threadIdx.x & 63;
  int c8 = lane*8;
  float xi[8], av[8], acc[8] = {};
  ld8v(&xr[(size_t)wid*C1 + c8], xi);
  #pragma unroll
  for (int j=0;j<8;++j) av[j] = att[c8+j];
  float m = -1e30f, s = 0.f;
  int e0 = row_ptr[wid], e1 = row_ptr[wid+1];
  for (int e = e0; e < e1; ++e) {
    int sn = col[e]; if ((u32)sn >= (u32)NN) sn = 0;
    float xj[8];
    ld8v(&xl[(size_t)sn*C1 + c8], xj);
    float part = 0.f;
    #pragma unroll
    for (int j=0;j<8;++j) {
      float t = xi[j] + xj[j];
      t = t > 0.f ? t : 0.2f*t;      // leaky_relu 0.2
      part += t*av[j];
    }
    part += __shfl_xor(part,1); part += __shfl_xor(part,2);
    part += __shfl_xor(part,4); part += __shfl_xor(part,8);
    float mn = fmaxf(m, part);
    float f = __expf(m - mn), w = __expf(part - mn);
    s = s*f + w;
    #pragma unroll
    for (int j=0;j<8;++j) acc[j] = acc[j]*f + w*xj[j];
    m = mn;
  }
  float inv = 1.f/s, o[8];
  #pragma unroll
  for (int j=0;j<8;++j) o[j] = gelu_f(acc[j]*inv + bias[c8+j]);
  st8v(&z1[(size_t)wid*C1 + c8], o);
}

// ---------------- edge layer 2 (H=1, C=128) ----------------
__global__ __launch_bounds__(256) void k_edge2(const float* __restrict__ xl,
                                               const float* __restrict__ xr,
                                               const float* __restrict__ att,
                                               const float* __restrict__ bias,
                                               const int* __restrict__ row_ptr,
                                               const int* __restrict__ col,
                                               float* __restrict__ z2) {
  int wid = (blockIdx.x*blockDim.x + threadIdx.x) >> 6;
  if (wid >= NN) return;
  int lane = threadIdx.x & 63;
  int c2 = lane*2;
  float2 xiv = *(const float2*)(xr + (size_t)wid*C2 + c2);
  float a0 = att[c2], a1 = att[c2+1];
  float m = -1e30f, s = 0.f, ac0 = 0.f, ac1 = 0.f;
  int e0 = row_ptr[wid], e1 = row_ptr[wid+1];
  for (int e = e0; e < e1; ++e) {
    int sn = col[e]; if ((u32)sn >= (u32)NN) sn = 0;
    float2 xj = *(const float2*)(xl + (size_t)sn*C2 + c2);
    float t0 = xiv.x + xj.x; t0 = t0 > 0.f ? t0 : 0.2f*t0;
    float t1 = xiv.y + xj.y; t1 = t1 > 0.f ? t1 : 0.2f*t1;
    float part = t0*a0 + t1*a1;
    part += __shfl_xor(part,1);  part += __shfl_xor(part,2);
    part += __shfl_xor(part,4);  part += __shfl_xor(part,8);
    part += __shfl_xor(part,16); part += __shfl_xor(part,32);
    float mn = fmaxf(m, part);
    float f = __expf(m - mn), w = __expf(part - mn);
    s = s*f + w;
    ac0 = ac0*f + w*xj.x;
    ac1 = ac1*f + w*xj.y;
    m = mn;
  }
  float inv = 1.f/s;
  z2[(size_t)wid*C2 + c2]   = ac0*inv + bias[c2];
  z2[(size_t)wid*C2 + c2+1] = ac1*inv + bias[c2+1];
}

// ---------------- decoder tiled GEMM: 64 edges x 128 hidden per block ----------------
// lane tx owns cols {tx*4..tx*4+3} u {64+tx*4..64+tx*4+3}: 16B bank stride -> 2-way (free)
__global__ __launch_bounds__(256) void k_dec2(const float* __restrict__ z2,
                                              const int* __restrict__ eli,
                                              const float* __restrict__ Wd1,
                                              const float* __restrict__ bd1,
                                              const float* __restrict__ Wd2,
                                              const float* __restrict__ bd2,
                                              float* __restrict__ out) {
  __shared__ __align__(16) float As[16][64];    // [k][edge]
  __shared__ __align__(16) float Bs[16][128];   // [k][hid]
  int tid = threadIdx.x;
  int e0 = blockIdx.x * 64;
  int ty = tid >> 4, tx = tid & 15;
  int lrow = tid >> 2;
  int lk   = (tid & 3) * 4;
  int wk   = tid >> 4;
  int wn   = (tid & 15) * 8;
  int e = e0 + lrow;
  bool ev = e < ELN;
  int ia = ev ? eli[e] : 0;       if ((u32)ia >= (u32)NN) ia = 0;
  int ib = ev ? eli[ELN+e] : 0;   if ((u32)ib >= (u32)NN) ib = 0;
  float acc[4][8] = {};
  for (int k0 = 0; k0 < 256; k0 += 16) {
    int kk4 = k0 + lk;
    const float* src = (kk4 < 128) ? &z2[(size_t)ia*128 + kk4]
                                   : &z2[(size_t)ib*128 + (kk4 - 128)];
    float4 a4 = ev ? *(const float4*)src : make_float4(0.f,0.f,0.f,0.f);
    As[lk+0][lrow]=a4.x; As[lk+1][lrow]=a4.y; As[lk+2][lrow]=a4.z; As[lk+3][lrow]=a4.w;
    *(float4*)&Bs[wk][wn]   = *(const float4*)&Wd1[(size_t)(k0+wk)*128 + wn];
    *(float4*)&Bs[wk][wn+4] = *(const float4*)&Wd1[(size_t)(k0+wk)*128 + wn + 4];
    __syncthreads();
    #pragma unroll
    for (int kk = 0; kk < 16; ++kk) {
      float4 av = *(const float4*)&As[kk][ty*4];
      float a[4] = {av.x, av.y, av.z, av.w};
      float4 b0 = *(const float4*)&Bs[kk][tx*4];
      float4 b1 = *(const float4*)&Bs[kk][64 + tx*4];
      float b[8] = {b0.x,b0.y,b0.z,b0.w,b1.x,b1.y,b1.z,b1.w};
      #pragma unroll
      for (int i = 0; i < 4; ++i)
        #pragma unroll
        for (int j = 0; j < 8; ++j)
          acc[i][j] += a[i]*b[j];
    }
    __syncthreads();
  }
  float w2[8], bb[8];
  #pragma unroll
  for (int j = 0; j < 4; ++j) {
    w2[j]   = Wd2[tx*4+j];      bb[j]   = bd1[tx*4+j];
    w2[j+4] = Wd2[64+tx*4+j];   bb[j+4] = bd1[64+tx*4+j];
  }
  float b2 = bd2[0];
  #pragma unroll
  for (int i = 0; i < 4; ++i) {
    float part = 0.f;
    #pragma unroll
    for (int j = 0; j < 8; ++j)
      part += gelu_f(acc[i][j] + bb[j]) * w2[j];
    part += __shfl_xor(part,1); part += __shfl_xor(part,2);
    part += __shfl_xor(part,4); part += __shfl_xor(part,8);
    int row = e0 + ty*4 + i;
    if (tx == 0 && row < ELN) out[row] = part + b2;
  }
}

__global__ void k_tiny(float* out, float code) {
  if (threadIdx.x == 0) out[0] = code;
}

// ---------------- launch ----------------
extern "C" void kernel_launch(void* const* d_in, const int* in_sizes, int n_in,
                              void* d_out, int out_size, void* d_ws, size_t ws_size,
                              hipStream_t stream) {
  const float* x     = (const float*)d_in[0];
  const int*   ei    = (const int*)  d_in[1];
  const int*   eli   = (const int*)  d_in[2];
  const float* Wl1   = (const float*)d_in[3];
  const float* bl1   = (const float*)d_in[4];
  const float* Wr1   = (const float*)d_in[5];
  const float* br1   = (const float*)d_in[6];
  const float* att1  = (const float*)d_in[7];
  const float* bias1 = (const float*)d_in[8];
  const float* Wl2   = (const float*)d_in[9];
  const float* bl2   = (const float*)d_in[10];
  const float* Wr2   = (const float*)d_in[11];
  const float* br2   = (const float*)d_in[12];
  const float* att2  = (const float*)d_in[13];
  const float* bias2 = (const float*)d_in[14];
  const float* Wd1   = (const float*)d_in[15];
  const float* bd1   = (const float*)d_in[16];
  const float* Wd2   = (const float*)d_in[17];
  const float* bd2   = (const float*)d_in[18];
  float* out = (float*)d_out;

  constexpr size_t INTW = (size_t)(NN+1) + NN + ETOT;          // 380001 words
  constexpr size_t FULL_WORDS = 3ull*NN*C1 + INTW;             // ~124.4 MB (proven available)
  constexpr size_t CMP_WORDS  = 3ull*NN*C1/2 + INTW;           // ~63 MB

  bool full    = ws_size >= FULL_WORDS*4;
  bool compact = !full && ws_size >= CMP_WORDS*4;
  if (!full && !compact) {
    size_t mb = ws_size >> 20;
    k_tiny<<<1, 64, 0, stream>>>(out, 16384.f + (float)mb);
    return;
  }

  size_t regA = full ? (size_t)NN*C1 : (size_t)NN*C1/2;   // words per region
  char* base = (char*)d_ws;
  void* wA = base;
  void* wB = base + regA*4;
  void* wC = base + 2*regA*4;
  int* row_ptr = (int*)(base + 3*regA*4);
  int* cnt     = row_ptr + (NN + 1);
  int* col     = cnt + NN;
  int* bsum    = (int*)wA;   // scan scratch: wA dead during CSR phase

  float* xl2 = (float*)wA;   // layer-2 intermediates (overlay, layer-1 dead)
  float* xr2 = (float*)wB;
  float* z2  = (float*)wC;

  // CSR over dst
  hipMemsetAsync(cnt, 0, NN*sizeof(int), stream);
  k_hist<<<(ETOT+255)/256, 256, 0, stream>>>(ei, cnt);
  k_scan_a<<<NB, 256, 0, stream>>>(cnt, row_ptr, bsum);
  k_scan_b<<<1, 128, 0, stream>>>(bsum, row_ptr);
  k_scan_c<<<NB, 256, 0, stream>>>(row_ptr, bsum);
  k_copy<<<(NN+255)/256, 256, 0, stream>>>(row_ptr, cnt);
  k_scatter<<<(ETOT+255)/256, 256, 0, stream>>>(ei, cnt, col);

  if (full) {
    float* xl1 = (float*)wA;
    float* xr1 = (float*)wB;
    float* z1  = (float*)wC;
    // Wt1 planes live at start of region C (dead once z1 is written in k_edge1)
    u16* wl1th = (u16*)wC;            u16* wl1tl = wl1th + 512*256;
    u16* wr1th = wl1tl + 512*256;     u16* wr1tl = wr1th + 512*256;
    // Wt2 planes live at region A + 16 MB (xl2 uses first 10.24 MB; written after k_edge1)
    u16* wl2th = (u16*)((char*)wA + (16u<<20));  u16* wl2tl = wl2th + 128*512;
    u16* wr2th = wl2tl + 128*512;                u16* wr2tl = wr2th + 128*512;

    k_wsplit<<<(512*256+255)/256, 256, 0, stream>>>(Wl1, wl1th, wl1tl, INC, C1);
    k_wsplit<<<(512*256+255)/256, 256, 0, stream>>>(Wr1, wr1th, wr1tl, INC, C1);
    dim3 gm1((NN+127)/128, C1/128);
    k_mgemm<<<gm1, 256, 0, stream>>>(x, wl1th, wl1tl, bl1, xl1, NN, C1, INC);
    k_mgemm<<<gm1, 256, 0, stream>>>(x, wr1th, wr1tl, br1, xr1, NN, C1, INC);
    k_edge1<float><<<NN/4, 256, 0, stream>>>(xl1, xr1, att1, bias1, row_ptr, col, z1);
    k_wsplit<<<(128*512+255)/256, 256, 0, stream>>>(Wl2, wl2th, wl2tl, C1, C2);
    k_wsplit<<<(128*512+255)/256, 256, 0, stream>>>(Wr2, wr2th, wr2tl, C1, C2);
    dim3 gm2((NN+127)/128, C2/128);
    k_mgemm<<<gm2, 256, 0, stream>>>(z1, wl2th, wl2tl, bl2, xl2, NN, C2, C1);
    k_mgemm<<<gm2, 256, 0, stream>>>(z1, wr2th, wr2tl, br2, xr2, NN, C2, C1);
  } else {
    u16* xl1 = (u16*)wA;
    u16* xr1 = (u16*)wB;
    u16* z1  = (u16*)wC;
    dim3 g1((NN+63)/64, C1/64);
    dim3 g2((NN+63)/64, C2/64);
    k_gemm<float,u16><<<g1, 256, 0, stream>>>(x, Wl1, bl1, xl1, NN, C1, INC);
    k_gemm<float,u16><<<g1, 256, 0, stream>>>(x, Wr1, br1, xr1, NN, C1, INC);
    k_edge1<u16><<<NN/4, 256, 0, stream>>>(xl1, xr1, att1, bias1, row_ptr, col, z1);
    k_gemm<u16,float><<<g2, 256, 0, stream>>>(z1, Wl2, bl2, xl2, NN, C2, C1);
    k_gemm<u16,float><<<g2, 256, 0, stream>>>(z1, Wr2, br2, xr2, NN, C2, C1);
  }

  k_edge2<<<NN/4, 256, 0, stream>>>(xl2, xr2, att2, bias2, row_ptr, col, z2);
  k_dec2<<<(ELN+63)/64, 256, 0, stream>>>(z2, eli, Wd1, bd1, Wd2, bd2, out);
}

// Round 7
// 512.048 us; speedup vs baseline: 1.7445x; 1.1199x over previous
//
#include <hip/hip_runtime.h>
#include <hip/hip_bf16.h>
#include <math.h>
#include <stdint.h>

using bf16 = __hip_bfloat16;
typedef unsigned short u16;
typedef unsigned int   u32;
typedef __attribute__((ext_vector_type(8))) short short8;   // 8 bf16 bit patterns
typedef __attribute__((ext_vector_type(4))) float f32x4;

static constexpr int NN   = 20000;
static constexpr int EE   = 320000;
static constexpr int ELN  = 100000;
static constexpr int ETOT = EE + NN;
static constexpr int INC  = 256;
static constexpr int C1   = 512;
static constexpr int C2   = 128;
static constexpr int NB   = (NN + 255) / 256;   // scan blocks = 79

__device__ __forceinline__ float us2f(u16 u){ union{u32 i; float f;}x; x.i=((u32)u)<<16; return x.f; }
__device__ __forceinline__ u16  f2us(float f){ union{bf16 h; u16 u;}c; c.h=__float2bfloat16(f); return c.u; }
// tanh-approx gelu via hw exp: tanh(t) = 1 - 2/(e^{2t}+1); |diff vs tanhf| < 1e-6
__device__ __forceinline__ float gelu_f(float x){
  float u = 1.5957691216057308f*(x + 0.044715f*x*x*x);   // 2*sqrt(2/pi)*(...)
  float ex = __expf(u);
  float th = 1.f - 2.f/(ex + 1.f);
  return 0.5f*x*(1.f+th);
}
__device__ __forceinline__ void ld4v(const float* p, float* o){ float4 v=*(const float4*)p; o[0]=v.x;o[1]=v.y;o[2]=v.z;o[3]=v.w; }
__device__ __forceinline__ void ld4v(const u16* p, float* o){ uint2 v=*(const uint2*)p;
  o[0]=us2f(v.x&0xffff);o[1]=us2f(v.x>>16);o[2]=us2f(v.y&0xffff);o[3]=us2f(v.y>>16); }
__device__ __forceinline__ void ld8v(const float* p, float* o){ ld4v(p,o); ld4v(p+4,o+4); }
__device__ __forceinline__ void ld8v(const u16* p, float* o){ uint4 v=*(const uint4*)p;
  o[0]=us2f(v.x&0xffff);o[1]=us2f(v.x>>16);o[2]=us2f(v.y&0xffff);o[3]=us2f(v.y>>16);
  o[4]=us2f(v.z&0xffff);o[5]=us2f(v.z>>16);o[6]=us2f(v.w&0xffff);o[7]=us2f(v.w>>16); }
__device__ __forceinline__ void st4v(float* p, const float* v){ *(float4*)p = make_float4(v[0],v[1],v[2],v[3]); }
__device__ __forceinline__ void st4v(u16* p, const float* v){ uint2 o;
  o.x=f2us(v[0])|((u32)f2us(v[1])<<16); o.y=f2us(v[2])|((u32)f2us(v[3])<<16); *(uint2*)p=o; }
__device__ __forceinline__ void st8v(float* p, const float* v){ st4v(p,v); st4v(p+4,v+4); }
__device__ __forceinline__ void st8v(u16* p, const float* v){ uint4 o;
  o.x=f2us(v[0])|((u32)f2us(v[1])<<16); o.y=f2us(v[2])|((u32)f2us(v[3])<<16);
  o.z=f2us(v[4])|((u32)f2us(v[5])<<16); o.w=f2us(v[6])|((u32)f2us(v[7])<<16); *(uint4*)p=o; }

// ---------------- CSR ----------------
__global__ void k_hist(const int* __restrict__ ei, int* __restrict__ cnt) {
  int e = blockIdx.x*blockDim.x + threadIdx.x;
  if (e < ETOT) {
    int d = (e < EE) ? ei[EE + e] : (e - EE);
    if ((u32)d < (u32)NN) atomicAdd(&cnt[d], 1);
  }
}
__global__ void k_scan_a(const int* __restrict__ cnt, int* __restrict__ row_ptr,
                         int* __restrict__ bsum) {
  __shared__ int buf[256];
  int idx = blockIdx.x*256 + threadIdx.x;
  int v = (idx < NN) ? cnt[idx] : 0;
  buf[threadIdx.x] = v;
  __syncthreads();
  for (int off = 1; off < 256; off <<= 1) {
    int t = (threadIdx.x >= off) ? buf[threadIdx.x - off] : 0;
    __syncthreads();
    buf[threadIdx.x] += t;
    __syncthreads();
  }
  if (idx < NN) row_ptr[idx] = buf[threadIdx.x] - v;
  if (threadIdx.x == 255) bsum[blockIdx.x] = buf[255];
}
__global__ void k_scan_b(int* __restrict__ bsum, int* __restrict__ row_ptr) {
  __shared__ int buf[128];
  int v = (threadIdx.x < NB) ? bsum[threadIdx.x] : 0;
  buf[threadIdx.x] = v;
  __syncthreads();
  for (int off = 1; off < 128; off <<= 1) {
    int t = (threadIdx.x >= off) ? buf[threadIdx.x - off] : 0;
    __syncthreads();
    buf[threadIdx.x] += t;
    __syncthreads();
  }
  if (threadIdx.x < NB) bsum[threadIdx.x] = buf[threadIdx.x] - v;
  if (threadIdx.x == 127) row_ptr[NN] = buf[127];
}
// adds block offsets AND writes the scatter cursor copy (folded k_copy)
__global__ void k_scan_c(int* __restrict__ row_ptr, const int* __restrict__ bsum,
                         int* __restrict__ cur) {
  int idx = blockIdx.x*256 + threadIdx.x;
  if (idx < NN) {
    int v = row_ptr[idx] + bsum[blockIdx.x];
    row_ptr[idx] = v;
    cur[idx] = v;
  }
}
__global__ void k_scatter(const int* __restrict__ ei, int* __restrict__ cur,
                          int* __restrict__ col) {
  int e = blockIdx.x*blockDim.x + threadIdx.x;
  if (e < ETOT) {
    int s, d;
    if (e < EE) { s = ei[e]; d = ei[EE + e]; } else { s = d = e - EE; }
    if ((u32)d >= (u32)NN) d = 0;
    int pos = atomicAdd(&cur[d], 1);
    if ((u32)pos < (u32)ETOT) col[pos] = s;
  }
}

// ---------------- weight transpose + hi/lo split: W[K,N] f32 -> Th/Tl[N,K] bf16 ----------------
__global__ void k_wsplit(const float* __restrict__ W, u16* __restrict__ Th,
                         u16* __restrict__ Tl, int K, int N) {
  int idx = blockIdx.x*256 + threadIdx.x;
  if (idx >= K*N) return;
  int n = idx / K, k = idx - n*K;
  float v = W[(size_t)k*N + n];
  u16 h = f2us(v);
  Th[idx] = h;
  Tl[idx] = f2us(v - us2f(h));
}

// ---------------- MFMA GEMM: C[M,N] = A[M,K](f32) @ B + bias ----------------
// D = Ah*Bh + Ah*Bl + Al*Bh  (f32-equivalent accuracy here).
__global__ __launch_bounds__(256, 2)
void k_mgemm(const float* __restrict__ A,
             const u16* __restrict__ Bth, const u16* __restrict__ Btl,
             const float* __restrict__ bias, float* __restrict__ C,
             int M, int N, int K) {
  __shared__ __align__(16) u16 Ah[128][32], Al[128][32];
  __shared__ __align__(16) u16 Bh[128][32], Bl[128][32];
  int tid = threadIdx.x;
  int m0 = blockIdx.x * 128, n0 = blockIdx.y * 128;
  int wave = tid >> 6, lane = tid & 63;
  int wm = (wave & 1) * 64, wn = (wave >> 1) * 64;
  int l15 = lane & 15, quad = lane >> 4;
  f32x4 acc[4][4] = {};
  int ar = tid >> 3;
  int ak = (tid & 7) * 4;
  int bn = tid >> 2;
  int bc = (tid & 3) * 8;
  for (int k0 = 0; k0 < K; k0 += 32) {
    #pragma unroll
    for (int i = 0; i < 4; ++i) {
      int row = ar + 32*i;
      int gr = m0 + row;
      float4 v = (gr < M) ? *(const float4*)&A[(size_t)gr*K + k0 + ak]
                          : make_float4(0.f,0.f,0.f,0.f);
      float hv[4] = {v.x, v.y, v.z, v.w};
      u16 hi[4], lo[4];
      #pragma unroll
      for (int j = 0; j < 4; ++j) {
        hi[j] = f2us(hv[j]);
        lo[j] = f2us(hv[j] - us2f(hi[j]));
      }
      *(uint2*)&Ah[row][ak] = make_uint2(hi[0]|((u32)hi[1]<<16), hi[2]|((u32)hi[3]<<16));
      *(uint2*)&Al[row][ak] = make_uint2(lo[0]|((u32)lo[1]<<16), lo[2]|((u32)lo[3]<<16));
    }
    #pragma unroll
    for (int i = 0; i < 2; ++i) {
      int n = bn + 64*i;
      *(uint4*)&Bh[n][bc] = *(const uint4*)&Bth[(size_t)(n0+n)*K + k0 + bc];
      *(uint4*)&Bl[n][bc] = *(const uint4*)&Btl[(size_t)(n0+n)*K + k0 + bc];
    }
    __syncthreads();
    short8 af_h[4], af_l[4], bf_h[4], bf_l[4];
    #pragma unroll
    for (int i = 0; i < 4; ++i) {
      af_h[i] = *(const short8*)&Ah[wm + i*16 + l15][quad*8];
      af_l[i] = *(const short8*)&Al[wm + i*16 + l15][quad*8];
      bf_h[i] = *(const short8*)&Bh[wn + i*16 + l15][quad*8];
      bf_l[i] = *(const short8*)&Bl[wn + i*16 + l15][quad*8];
    }
    #pragma unroll
    for (int i = 0; i < 4; ++i)
      #pragma unroll
      for (int j = 0; j < 4; ++j) {
        acc[i][j] = __builtin_amdgcn_mfma_f32_16x16x32_bf16(af_h[i], bf_l[j], acc[i][j], 0,0,0);
        acc[i][j] = __builtin_amdgcn_mfma_f32_16x16x32_bf16(af_l[i], bf_h[j], acc[i][j], 0,0,0);
        acc[i][j] = __builtin_amdgcn_mfma_f32_16x16x32_bf16(af_h[i], bf_h[j], acc[i][j], 0,0,0);
      }
    __syncthreads();
  }
  #pragma unroll
  for (int j = 0; j < 4; ++j) {
    int col = n0 + wn + j*16 + l15;
    float bv = bias[col];
    #pragma unroll
    for (int i = 0; i < 4; ++i) {
      int rbase = m0 + wm + i*16 + quad*4;
      #pragma unroll
      for (int r = 0; r < 4; ++r) {
        int row = rbase + r;
        if (row < M) C[(size_t)row*N + col] = acc[i][j][r] + bv;
      }
    }
  }
}

// ---------------- MFMA decoder: out[e] = Wd2 . gelu(concat(z2[a],z2[b]) @ Wd1 + bd1) + bd2
// BM=128 edges, BN=128 hidden (full), K=256. Wd1 pre-transposed/split planes [128][256].
__global__ __launch_bounds__(256, 2)
void k_dec3(const float* __restrict__ z2,
            const int* __restrict__ eli,
            const u16* __restrict__ Wth, const u16* __restrict__ Wtl,
            const float* __restrict__ bd1,
            const float* __restrict__ Wd2, const float* __restrict__ bd2,
            float* __restrict__ out) {
  __shared__ __align__(16) u16 Ah[128][32], Al[128][32];
  __shared__ __align__(16) u16 Bh[128][32], Bl[128][32];
  __shared__ float pr[128][2];
  int tid = threadIdx.x;
  int e0 = blockIdx.x * 128;
  int wave = tid >> 6, lane = tid & 63;
  int wm = (wave & 1) * 64, wn = (wave >> 1) * 64;
  int l15 = lane & 15, quad = lane >> 4;
  int ar = tid >> 3;
  int ak = (tid & 7) * 4;
  int bn = tid >> 2;
  int bc = (tid & 3) * 8;
  int ia4[4], ib4[4];
  #pragma unroll
  for (int i = 0; i < 4; ++i) {
    int e = e0 + ar + 32*i;
    bool ev = e < ELN;
    int a = ev ? eli[e] : 0;      if ((u32)a >= (u32)NN) a = 0;
    int b = ev ? eli[ELN+e] : 0;  if ((u32)b >= (u32)NN) b = 0;
    ia4[i] = a; ib4[i] = b;
  }
  f32x4 acc[4][4] = {};
  for (int k0 = 0; k0 < 256; k0 += 32) {
    #pragma unroll
    for (int i = 0; i < 4; ++i) {
      int row = ar + 32*i;
      int kk = k0 + ak;     // 4-aligned, never straddles the 128 concat boundary
      const float* src = (kk < 128) ? &z2[(size_t)ia4[i]*128 + kk]
                                    : &z2[(size_t)ib4[i]*128 + (kk - 128)];
      float4 v = *(const float4*)src;
      float hv[4] = {v.x, v.y, v.z, v.w};
      u16 hi[4], lo[4];
      #pragma unroll
      for (int j = 0; j < 4; ++j) {
        hi[j] = f2us(hv[j]);
        lo[j] = f2us(hv[j] - us2f(hi[j]));
      }
      *(uint2*)&Ah[row][ak] = make_uint2(hi[0]|((u32)hi[1]<<16), hi[2]|((u32)hi[3]<<16));
      *(uint2*)&Al[row][ak] = make_uint2(lo[0]|((u32)lo[1]<<16), lo[2]|((u32)lo[3]<<16));
    }
    #pragma unroll
    for (int i = 0; i < 2; ++i) {
      int n = bn + 64*i;
      *(uint4*)&Bh[n][bc] = *(const uint4*)&Wth[(size_t)n*256 + k0 + bc];
      *(uint4*)&Bl[n][bc] = *(const uint4*)&Wtl[(size_t)n*256 + k0 + bc];
    }
    __syncthreads();
    short8 af_h[4], af_l[4], bf_h[4], bf_l[4];
    #pragma unroll
    for (int i = 0; i < 4; ++i) {
      af_h[i] = *(const short8*)&Ah[wm + i*16 + l15][quad*8];
      af_l[i] = *(const short8*)&Al[wm + i*16 + l15][quad*8];
      bf_h[i] = *(const short8*)&Bh[wn + i*16 + l15][quad*8];
      bf_l[i] = *(const short8*)&Bl[wn + i*16 + l15][quad*8];
    }
    #pragma unroll
    for (int i = 0; i < 4; ++i)
      #pragma unroll
      for (int j = 0; j < 4; ++j) {
        acc[i][j] = __builtin_amdgcn_mfma_f32_16x16x32_bf16(af_h[i], bf_l[j], acc[i][j], 0,0,0);
        acc[i][j] = __builtin_amdgcn_mfma_f32_16x16x32_bf16(af_l[i], bf_h[j], acc[i][j], 0,0,0);
        acc[i][j] = __builtin_amdgcn_mfma_f32_16x16x32_bf16(af_h[i], bf_h[j], acc[i][j], 0,0,0);
      }
    __syncthreads();
  }
  // epilogue: gelu + Wd2 dot. acc[i][j][r]: row=wm+i*16+quad*4+r, col=wn+j*16+l15
  float w2c[4], bbc[4];
  #pragma unroll
  for (int j = 0; j < 4; ++j) {
    int col = wn + j*16 + l15;
    w2c[j] = Wd2[col];
    bbc[j] = bd1[col];
  }
  #pragma unroll
  for (int i = 0; i < 4; ++i) {
    #pragma unroll
    for (int r = 0; r < 4; ++r) {
      float part = 0.f;
      #pragma unroll
      for (int j = 0; j < 4; ++j)
        part += gelu_f(acc[i][j][r] + bbc[j]) * w2c[j];
      part += __shfl_xor(part,1); part += __shfl_xor(part,2);
      part += __shfl_xor(part,4); part += __shfl_xor(part,8);
      if (l15 == 0) pr[wm + i*16 + quad*4 + r][wn>>6] = part;
    }
  }
  __syncthreads();
  if (tid < 128) {
    int e = e0 + tid;
    if (e < ELN) out[e] = pr[tid][0] + pr[tid][1] + bd2[0];
  }
}

// ---------------- fallback f32 GEMM (compact path only) ----------------
template <typename AT, typename CT>
__global__ __launch_bounds__(256) void k_gemm(const AT* __restrict__ A,
                                              const float* __restrict__ W,
                                              const float* __restrict__ bias,
                                              CT* __restrict__ C,
                                              int M, int Nc, int K) {
  __shared__ __align__(16) float As[16][64];
  __shared__ __align__(16) float Bs[16][64];
  int tid = threadIdx.x;
  int m0 = blockIdx.x*64, n0 = blockIdx.y*64;
  int ty = tid >> 4, tx = tid & 15;
  int lrow = tid >> 2;
  int lk   = (tid & 3)*4;
  int wk   = tid >> 4;
  int wn   = (tid & 15)*4;
  float acc[4][4] = {};
  for (int k0 = 0; k0 < K; k0 += 16) {
    int row = m0 + lrow;
    if (row < M) {
      float a4[4]; ld4v(&A[(size_t)row*K + k0 + lk], a4);
      As[lk+0][lrow]=a4[0]; As[lk+1][lrow]=a4[1]; As[lk+2][lrow]=a4[2]; As[lk+3][lrow]=a4[3];
    } else {
      #pragma unroll
      for (int j=0;j<4;++j) As[lk+j][lrow]=0.f;
    }
    {
      float4 bv4 = *(const float4*)&W[(size_t)(k0+wk)*Nc + n0 + wn];
      Bs[wk][wn+0]=bv4.x; Bs[wk][wn+1]=bv4.y; Bs[wk][wn+2]=bv4.z; Bs[wk][wn+3]=bv4.w;
    }
    __syncthreads();
    #pragma unroll
    for (int kk=0;kk<16;++kk) {
      float4 av = *(const float4*)&As[kk][ty*4];
      float4 bv = *(const float4*)&Bs[kk][tx*4];
      float a[4]={av.x,av.y,av.z,av.w}, b[4]={bv.x,bv.y,bv.z,bv.w};
      #pragma unroll
      for (int i=0;i<4;++i)
        #pragma unroll
        for (int j=0;j<4;++j)
          acc[i][j] += a[i]*b[j];
    }
    __syncthreads();
  }
  float bv[4];
  #pragma unroll
  for (int j=0;j<4;++j) bv[j] = bias[n0 + tx*4 + j];
  #pragma unroll
  for (int i=0;i<4;++i) {
    int row = m0 + ty*4 + i;
    if (row < M) {
      float o4[4] = {acc[i][0]+bv[0], acc[i][1]+bv[1], acc[i][2]+bv[2], acc[i][3]+bv[3]};
      st4v(&C[(size_t)row*Nc + n0 + tx*4], o4);
    }
  }
}

// ---------------- edge layer 1 (H=4, C=128), gelu fused ----------------
template <typename T>
__global__ __launch_bounds__(256) void k_edge1(const T* __restrict__ xl,
                                               const T* __restrict__ xr,
                                               const float* __restrict__ att,
                                               const float* __restrict__ bias,
                                               const int* __restrict__ row_ptr,
                                               const int* __restrict__ col,
                                               T* __restrict__ z1) {
  int wid = (blockIdx.x*blockDim.x + threadIdx.x) >> 6;
  if (wid >= NN) return;
  int lane = threadIdx.x & 63;
  int c8 = lane*8;
  float xi[8], av[8], acc[8] = {};
  ld8v(&xr[(size_t)wid*C1 + c8], xi);
  #pragma unroll
  for (int j=0;j<8;++j) av[j] = att[c8+j];
  float m = -1e30f, s = 0.f;
  int e0 = row_ptr[wid], e1 = row_ptr[wid+1];
  for (int e = e0; e < e1; ++e) {
    int sn = col[e]; if ((u32)sn >= (u32)NN) sn = 0;
    float xj[8];
    ld8v(&xl[(size_t)sn*C1 + c8], xj);
    float part = 0.f;
    #pragma unroll
    for (int j=0;j<8;++j) {
      float t = xi[j] + xj[j];
      t = t > 0.f ? t : 0.2f*t;      // leaky_relu 0.2
      part += t*av[j];
    }
    part += __shfl_xor(part,1); part += __shfl_xor(part,2);
    part += __shfl_xor(part,4); part += __shfl_xor(part,8);
    float mn = fmaxf(m, part);
    float f = __expf(m - mn), w = __expf(part - mn);
    s = s*f + w;
    #pragma unroll
    for (int j=0;j<8;++j) acc[j] = acc[j]*f + w*xj[j];
    m = mn;
  }
  float inv = 1.f/s, o[8];
  #pragma unroll
  for (int j=0;j<8;++j) o[j] = gelu_f(acc[j]*inv + bias[c8+j]);
  st8v(&z1[(size_t)wid*C1 + c8], o);
}

// ---------------- edge layer 2 (H=1, C=128) ----------------
__global__ __launch_bounds__(256) void k_edge2(const float* __restrict__ xl,
                                               const float* __restrict__ xr,
                                               const float* __restrict__ att,
                                               const float* __restrict__ bias,
                                               const int* __restrict__ row_ptr,
                                               const int* __restrict__ col,
                                               float* __restrict__ z2) {
  int wid = (blockIdx.x*blockDim.x + threadIdx.x) >> 6;
  if (wid >= NN) return;
  int lane = threadIdx.x & 63;
  int c2 = lane*2;
  float2 xiv = *(const float2*)(xr + (size_t)wid*C2 + c2);
  float a0 = att[c2], a1 = att[c2+1];
  float m = -1e30f, s = 0.f, ac0 = 0.f, ac1 = 0.f;
  int e0 = row_ptr[wid], e1 = row_ptr[wid+1];
  for (int e = e0; e < e1; ++e) {
    int sn = col[e]; if ((u32)sn >= (u32)NN) sn = 0;
    float2 xj = *(const float2*)(xl + (size_t)sn*C2 + c2);
    float t0 = xiv.x + xj.x; t0 = t0 > 0.f ? t0 : 0.2f*t0;
    float t1 = xiv.y + xj.y; t1 = t1 > 0.f ? t1 : 0.2f*t1;
    float part = t0*a0 + t1*a1;
    part += __shfl_xor(part,1);  part += __shfl_xor(part,2);
    part += __shfl_xor(part,4);  part += __shfl_xor(part,8);
    part += __shfl_xor(part,16); part += __shfl_xor(part,32);
    float mn = fmaxf(m, part);
    float f = __expf(m - mn), w = __expf(part - mn);
    s = s*f + w;
    ac0 = ac0*f + w*xj.x;
    ac1 = ac1*f + w*xj.y;
    m = mn;
  }
  float inv = 1.f/s;
  z2[(size_t)wid*C2 + c2]   = ac0*inv + bias[c2];
  z2[(size_t)wid*C2 + c2+1] = ac1*inv + bias[c2+1];
}

// ---------------- f32 decoder (compact path fallback) ----------------
__global__ __launch_bounds__(256) void k_dec2(const float* __restrict__ z2,
                                              const int* __restrict__ eli,
                                              const float* __restrict__ Wd1,
                                              const float* __restrict__ bd1,
                                              const float* __restrict__ Wd2,
                                              const float* __restrict__ bd2,
                                              float* __restrict__ out) {
  __shared__ __align__(16) float As[16][64];
  __shared__ __align__(16) float Bs[16][128];
  int tid = threadIdx.x;
  int e0 = blockIdx.x * 64;
  int ty = tid >> 4, tx = tid & 15;
  int lrow = tid >> 2;
  int lk   = (tid & 3) * 4;
  int wk   = tid >> 4;
  int wn   = (tid & 15) * 8;
  int e = e0 + lrow;
  bool ev = e < ELN;
  int ia = ev ? eli[e] : 0;       if ((u32)ia >= (u32)NN) ia = 0;
  int ib = ev ? eli[ELN+e] : 0;   if ((u32)ib >= (u32)NN) ib = 0;
  float acc[4][8] = {};
  for (int k0 = 0; k0 < 256; k0 += 16) {
    int kk4 = k0 + lk;
    const float* src = (kk4 < 128) ? &z2[(size_t)ia*128 + kk4]
                                   : &z2[(size_t)ib*128 + (kk4 - 128)];
    float4 a4 = ev ? *(const float4*)src : make_float4(0.f,0.f,0.f,0.f);
    As[lk+0][lrow]=a4.x; As[lk+1][lrow]=a4.y; As[lk+2][lrow]=a4.z; As[lk+3][lrow]=a4.w;
    *(float4*)&Bs[wk][wn]   = *(const float4*)&Wd1[(size_t)(k0+wk)*128 + wn];
    *(float4*)&Bs[wk][wn+4] = *(const float4*)&Wd1[(size_t)(k0+wk)*128 + wn + 4];
    __syncthreads();
    #pragma unroll
    for (int kk = 0; kk < 16; ++kk) {
      float4 av = *(const float4*)&As[kk][ty*4];
      float a[4] = {av.x, av.y, av.z, av.w};
      float4 b0 = *(const float4*)&Bs[kk][tx*4];
      float4 b1 = *(const float4*)&Bs[kk][64 + tx*4];
      float b[8] = {b0.x,b0.y,b0.z,b0.w,b1.x,b1.y,b1.z,b1.w};
      #pragma unroll
      for (int i = 0; i < 4; ++i)
        #pragma unroll
        for (int j = 0; j < 8; ++j)
          acc[i][j] += a[i]*b[j];
    }
    __syncthreads();
  }
  float w2[8], bb[8];
  #pragma unroll
  for (int j = 0; j < 4; ++j) {
    w2[j]   = Wd2[tx*4+j];      bb[j]   = bd1[tx*4+j];
    w2[j+4] = Wd2[64+tx*4+j];   bb[j+4] = bd1[64+tx*4+j];
  }
  float b2 = bd2[0];
  #pragma unroll
  for (int i = 0; i < 4; ++i) {
    float part = 0.f;
    #pragma unroll
    for (int j = 0; j < 8; ++j)
      part += gelu_f(acc[i][j] + bb[j]) * w2[j];
    part += __shfl_xor(part,1); part += __shfl_xor(part,2);
    part += __shfl_xor(part,4); part += __shfl_xor(part,8);
    int row = e0 + ty*4 + i;
    if (tx == 0 && row < ELN) out[row] = part + b2;
  }
}

__global__ void k_tiny(float* out, float code) {
  if (threadIdx.x == 0) out[0] = code;
}

// ---------------- launch ----------------
extern "C" void kernel_launch(void* const* d_in, const int* in_sizes, int n_in,
                              void* d_out, int out_size, void* d_ws, size_t ws_size,
                              hipStream_t stream) {
  const float* x     = (const float*)d_in[0];
  const int*   ei    = (const int*)  d_in[1];
  const int*   eli   = (const int*)  d_in[2];
  const float* Wl1   = (const float*)d_in[3];
  const float* bl1   = (const float*)d_in[4];
  const float* Wr1   = (const float*)d_in[5];
  const float* br1   = (const float*)d_in[6];
  const float* att1  = (const float*)d_in[7];
  const float* bias1 = (const float*)d_in[8];
  const float* Wl2   = (const float*)d_in[9];
  const float* bl2   = (const float*)d_in[10];
  const float* Wr2   = (const float*)d_in[11];
  const float* br2   = (const float*)d_in[12];
  const float* att2  = (const float*)d_in[13];
  const float* bias2 = (const float*)d_in[14];
  const float* Wd1   = (const float*)d_in[15];
  const float* bd1   = (const float*)d_in[16];
  const float* Wd2   = (const float*)d_in[17];
  const float* bd2   = (const float*)d_in[18];
  float* out = (float*)d_out;

  constexpr size_t INTW = (size_t)(NN+1) + NN + ETOT;          // 380001 words
  constexpr size_t FULL_WORDS = 3ull*NN*C1 + INTW;             // ~124.4 MB (proven available)
  constexpr size_t CMP_WORDS  = 3ull*NN*C1/2 + INTW;           // ~63 MB

  bool full    = ws_size >= FULL_WORDS*4;
  bool compact = !full && ws_size >= CMP_WORDS*4;
  if (!full && !compact) {
    size_t mb = ws_size >> 20;
    k_tiny<<<1, 64, 0, stream>>>(out, 16384.f + (float)mb);
    return;
  }

  size_t regA = full ? (size_t)NN*C1 : (size_t)NN*C1/2;   // words per region
  char* base = (char*)d_ws;
  void* wA = base;
  void* wB = base + regA*4;
  void* wC = base + 2*regA*4;
  int* row_ptr = (int*)(base + 3*regA*4);
  int* cnt     = row_ptr + (NN + 1);
  int* col     = cnt + NN;
  int* bsum    = (int*)wA;   // scan scratch: wA dead during CSR phase

  float* xl2 = (float*)wA;   // layer-2 intermediates (overlay, layer-1 dead)
  float* xr2 = (float*)wB;
  float* z2  = (float*)wC;

  // CSR over dst
  hipMemsetAsync(cnt, 0, NN*sizeof(int), stream);
  k_hist<<<(ETOT+255)/256, 256, 0, stream>>>(ei, cnt);
  k_scan_a<<<NB, 256, 0, stream>>>(cnt, row_ptr, bsum);
  k_scan_b<<<1, 128, 0, stream>>>(bsum, row_ptr);
  k_scan_c<<<NB, 256, 0, stream>>>(row_ptr, bsum, cnt);
  k_scatter<<<(ETOT+255)/256, 256, 0, stream>>>(ei, cnt, col);

  if (full) {
    float* xl1 = (float*)wA;
    float* xr1 = (float*)wB;
    float* z1  = (float*)wC;
    // Wt1 planes at start of region C (dead once z1 written in k_edge1)
    u16* wl1th = (u16*)wC;            u16* wl1tl = wl1th + 512*256;
    u16* wr1th = wl1tl + 512*256;     u16* wr1tl = wr1th + 512*256;
    // layer-2 + decoder weight planes at wA+16MB (xl1 dead after k_edge1; xl2 uses first 10.24 MB)
    u16* wl2th = (u16*)((char*)wA + (16u<<20));  u16* wl2tl = wl2th + 128*512;
    u16* wr2th = wl2tl + 128*512;                u16* wr2tl = wr2th + 128*512;
    u16* wdth  = wr2tl + 128*512;                u16* wdtl  = wdth  + 128*256;

    k_wsplit<<<(512*256+255)/256, 256, 0, stream>>>(Wl1, wl1th, wl1tl, INC, C1);
    k_wsplit<<<(512*256+255)/256, 256, 0, stream>>>(Wr1, wr1th, wr1tl, INC, C1);
    dim3 gm1((NN+127)/128, C1/128);
    k_mgemm<<<gm1, 256, 0, stream>>>(x, wl1th, wl1tl, bl1, xl1, NN, C1, INC);
    k_mgemm<<<gm1, 256, 0, stream>>>(x, wr1th, wr1tl, br1, xr1, NN, C1, INC);
    k_edge1<float><<<NN/4, 256, 0, stream>>>(xl1, xr1, att1, bias1, row_ptr, col, z1);
    k_wsplit<<<(128*512+255)/256, 256, 0, stream>>>(Wl2, wl2th, wl2tl, C1, C2);
    k_wsplit<<<(128*512+255)/256, 256, 0, stream>>>(Wr2, wr2th, wr2tl, C1, C2);
    k_wsplit<<<(128*256+255)/256, 256, 0, stream>>>(Wd1, wdth, wdtl, 256, 128);
    dim3 gm2((NN+127)/128, C2/128);
    k_mgemm<<<gm2, 256, 0, stream>>>(z1, wl2th, wl2tl, bl2, xl2, NN, C2, C1);
    k_mgemm<<<gm2, 256, 0, stream>>>(z1, wr2th, wr2tl, br2, xr2, NN, C2, C1);
    k_edge2<<<NN/4, 256, 0, stream>>>(xl2, xr2, att2, bias2, row_ptr, col, z2);
    k_dec3<<<(ELN+127)/128, 256, 0, stream>>>(z2, eli, wdth, wdtl, bd1, Wd2, bd2, out);
  } else {
    u16* xl1 = (u16*)wA;
    u16* xr1 = (u16*)wB;
    u16* z1  = (u16*)wC;
    dim3 g1((NN+63)/64, C1/64);
    dim3 g2((NN+63)/64, C2/64);
    k_gemm<float,u16><<<g1, 256, 0, stream>>>(x, Wl1, bl1, xl1, NN, C1, INC);
    k_gemm<float,u16><<<g1, 256, 0, stream>>>(x, Wr1, br1, xr1, NN, C1, INC);
    k_edge1<u16><<<NN/4, 256, 0, stream>>>(xl1, xr1, att1, bias1, row_ptr, col, z1);
    k_gemm<u16,float><<<g2, 256, 0, stream>>>(z1, Wl2, bl2, xl2, NN, C2, C1);
    k_gemm<u16,float><<<g2, 256, 0, stream>>>(z1, Wr2, br2, xr2, NN, C2, C1);
    k_edge2<<<NN/4, 256, 0, stream>>>(xl2, xr2, att2, bias2, row_ptr, col, z2);
    k_dec2<<<(ELN+63)/64, 256, 0, stream>>>(z2, eli, Wd1, bd1, Wd2, bd2, out);
  }
}

// Round 8
// 475.858 us; speedup vs baseline: 1.8772x; 1.0761x over previous
//
#include <hip/hip_runtime.h>
#include <hip/hip_bf16.h>
#include <math.h>
#include <stdint.h>

using bf16 = __hip_bfloat16;
typedef unsigned short u16;
typedef unsigned int   u32;
typedef __attribute__((ext_vector_type(8))) short short8;   // 8 bf16 bit patterns
typedef __attribute__((ext_vector_type(4))) float f32x4;

static constexpr int NN   = 20000;
static constexpr int EE   = 320000;
static constexpr int ELN  = 100000;
static constexpr int ETOT = EE + NN;
static constexpr int INC  = 256;
static constexpr int C1   = 512;
static constexpr int C2   = 128;
static constexpr int NB   = (NN + 255) / 256;   // scan blocks = 79

__device__ __forceinline__ float us2f(u16 u){ union{u32 i; float f;}x; x.i=((u32)u)<<16; return x.f; }
__device__ __forceinline__ u16  f2us(float f){ union{bf16 h; u16 u;}c; c.h=__float2bfloat16(f); return c.u; }
__device__ __forceinline__ float h2f(u16 u){ union{u16 u; _Float16 h;}c; c.u=u; return (float)c.h; }
// tanh-approx gelu via hw exp: tanh(t) = 1 - 2/(e^{2t}+1)
__device__ __forceinline__ float gelu_f(float x){
  float u = 1.5957691216057308f*(x + 0.044715f*x*x*x);
  float ex = __expf(u);
  float th = 1.f - 2.f/(ex + 1.f);
  return 0.5f*x*(1.f+th);
}
__device__ __forceinline__ void ld4v(const float* p, float* o){ float4 v=*(const float4*)p; o[0]=v.x;o[1]=v.y;o[2]=v.z;o[3]=v.w; }
__device__ __forceinline__ void ld4v(const u16* p, float* o){ uint2 v=*(const uint2*)p;
  o[0]=us2f(v.x&0xffff);o[1]=us2f(v.x>>16);o[2]=us2f(v.y&0xffff);o[3]=us2f(v.y>>16); }
__device__ __forceinline__ void ld8v(const float* p, float* o){ ld4v(p,o); ld4v(p+4,o+4); }
__device__ __forceinline__ void ld8v(const u16* p, float* o){ uint4 v=*(const uint4*)p;
  o[0]=us2f(v.x&0xffff);o[1]=us2f(v.x>>16);o[2]=us2f(v.y&0xffff);o[3]=us2f(v.y>>16);
  o[4]=us2f(v.z&0xffff);o[5]=us2f(v.z>>16);o[6]=us2f(v.w&0xffff);o[7]=us2f(v.w>>16); }
__device__ __forceinline__ void ld8v(const _Float16* p, float* o){ uint4 v=*(const uint4*)p;
  o[0]=h2f(v.x&0xffff);o[1]=h2f(v.x>>16);o[2]=h2f(v.y&0xffff);o[3]=h2f(v.y>>16);
  o[4]=h2f(v.z&0xffff);o[5]=h2f(v.z>>16);o[6]=h2f(v.w&0xffff);o[7]=h2f(v.w>>16); }
__device__ __forceinline__ void ld2v(const float* p, float* o){ float2 v=*(const float2*)p; o[0]=v.x;o[1]=v.y; }
__device__ __forceinline__ void ld2v(const _Float16* p, float* o){ u32 w=*(const u32*)p;
  o[0]=h2f(w&0xffff); o[1]=h2f(w>>16); }
__device__ __forceinline__ void st4v(float* p, const float* v){ *(float4*)p = make_float4(v[0],v[1],v[2],v[3]); }
__device__ __forceinline__ void st4v(u16* p, const float* v){ uint2 o;
  o.x=f2us(v[0])|((u32)f2us(v[1])<<16); o.y=f2us(v[2])|((u32)f2us(v[3])<<16); *(uint2*)p=o; }
__device__ __forceinline__ void st8v(float* p, const float* v){ st4v(p,v); st4v(p+4,v+4); }
__device__ __forceinline__ void st8v(u16* p, const float* v){ uint4 o;
  o.x=f2us(v[0])|((u32)f2us(v[1])<<16); o.y=f2us(v[2])|((u32)f2us(v[3])<<16);
  o.z=f2us(v[4])|((u32)f2us(v[5])<<16); o.w=f2us(v[6])|((u32)f2us(v[7])<<16); *(uint4*)p=o; }

// ---------------- CSR ----------------
__global__ void k_hist(const int* __restrict__ ei, int* __restrict__ cnt) {
  int e = blockIdx.x*blockDim.x + threadIdx.x;
  if (e < ETOT) {
    int d = (e < EE) ? ei[EE + e] : (e - EE);
    if ((u32)d < (u32)NN) atomicAdd(&cnt[d], 1);
  }
}
__global__ void k_scan_a(const int* __restrict__ cnt, int* __restrict__ row_ptr,
                         int* __restrict__ bsum) {
  __shared__ int buf[256];
  int idx = blockIdx.x*256 + threadIdx.x;
  int v = (idx < NN) ? cnt[idx] : 0;
  buf[threadIdx.x] = v;
  __syncthreads();
  for (int off = 1; off < 256; off <<= 1) {
    int t = (threadIdx.x >= off) ? buf[threadIdx.x - off] : 0;
    __syncthreads();
    buf[threadIdx.x] += t;
    __syncthreads();
  }
  if (idx < NN) row_ptr[idx] = buf[threadIdx.x] - v;
  if (threadIdx.x == 255) bsum[blockIdx.x] = buf[255];
}
__global__ void k_scan_b(int* __restrict__ bsum, int* __restrict__ row_ptr) {
  __shared__ int buf[128];
  int v = (threadIdx.x < NB) ? bsum[threadIdx.x] : 0;
  buf[threadIdx.x] = v;
  __syncthreads();
  for (int off = 1; off < 128; off <<= 1) {
    int t = (threadIdx.x >= off) ? buf[threadIdx.x - off] : 0;
    __syncthreads();
    buf[threadIdx.x] += t;
    __syncthreads();
  }
  if (threadIdx.x < NB) bsum[threadIdx.x] = buf[threadIdx.x] - v;
  if (threadIdx.x == 127) row_ptr[NN] = buf[127];
}
__global__ void k_scan_c(int* __restrict__ row_ptr, const int* __restrict__ bsum,
                         int* __restrict__ cur) {
  int idx = blockIdx.x*256 + threadIdx.x;
  if (idx < NN) {
    int v = row_ptr[idx] + bsum[blockIdx.x];
    row_ptr[idx] = v;
    cur[idx] = v;
  }
}
__global__ void k_scatter(const int* __restrict__ ei, int* __restrict__ cur,
                          int* __restrict__ col) {
  int e = blockIdx.x*blockDim.x + threadIdx.x;
  if (e < ETOT) {
    int s, d;
    if (e < EE) { s = ei[e]; d = ei[EE + e]; } else { s = d = e - EE; }
    if ((u32)d >= (u32)NN) d = 0;
    int pos = atomicAdd(&cur[d], 1);
    if ((u32)pos < (u32)ETOT) col[pos] = s;
  }
}

// ---------------- weight transpose + hi/lo split: W[K,N] f32 -> Th/Tl[N,K] bf16 ----------------
__global__ void k_wsplit(const float* __restrict__ W, u16* __restrict__ Th,
                         u16* __restrict__ Tl, int K, int N) {
  int idx = blockIdx.x*256 + threadIdx.x;
  if (idx >= K*N) return;
  int n = idx / K, k = idx - n*K;
  float v = W[(size_t)k*N + n];
  u16 h = f2us(v);
  Th[idx] = h;
  Tl[idx] = f2us(v - us2f(h));
}

// ---------------- MFMA GEMM: C[M,N] = A[M,K](f32) @ B + bias ----------------
// D = Ah*Bh + Ah*Bl + Al*Bh  (f32-equivalent accuracy). CT: float or _Float16.
template <typename CT>
__global__ __launch_bounds__(256, 2)
void k_mgemm(const float* __restrict__ A,
             const u16* __restrict__ Bth, const u16* __restrict__ Btl,
             const float* __restrict__ bias, CT* __restrict__ C,
             int M, int N, int K) {
  __shared__ __align__(16) u16 Ah[128][32], Al[128][32];
  __shared__ __align__(16) u16 Bh[128][32], Bl[128][32];
  int tid = threadIdx.x;
  int m0 = blockIdx.x * 128, n0 = blockIdx.y * 128;
  int wave = tid >> 6, lane = tid & 63;
  int wm = (wave & 1) * 64, wn = (wave >> 1) * 64;
  int l15 = lane & 15, quad = lane >> 4;
  f32x4 acc[4][4] = {};
  int ar = tid >> 3;
  int ak = (tid & 7) * 4;
  int bn = tid >> 2;
  int bc = (tid & 3) * 8;
  for (int k0 = 0; k0 < K; k0 += 32) {
    #pragma unroll
    for (int i = 0; i < 4; ++i) {
      int row = ar + 32*i;
      int gr = m0 + row;
      float4 v = (gr < M) ? *(const float4*)&A[(size_t)gr*K + k0 + ak]
                          : make_float4(0.f,0.f,0.f,0.f);
      float hv[4] = {v.x, v.y, v.z, v.w};
      u16 hi[4], lo[4];
      #pragma unroll
      for (int j = 0; j < 4; ++j) {
        hi[j] = f2us(hv[j]);
        lo[j] = f2us(hv[j] - us2f(hi[j]));
      }
      *(uint2*)&Ah[row][ak] = make_uint2(hi[0]|((u32)hi[1]<<16), hi[2]|((u32)hi[3]<<16));
      *(uint2*)&Al[row][ak] = make_uint2(lo[0]|((u32)lo[1]<<16), lo[2]|((u32)lo[3]<<16));
    }
    #pragma unroll
    for (int i = 0; i < 2; ++i) {
      int n = bn + 64*i;
      *(uint4*)&Bh[n][bc] = *(const uint4*)&Bth[(size_t)(n0+n)*K + k0 + bc];
      *(uint4*)&Bl[n][bc] = *(const uint4*)&Btl[(size_t)(n0+n)*K + k0 + bc];
    }
    __syncthreads();
    short8 af_h[4], af_l[4], bf_h[4], bf_l[4];
    #pragma unroll
    for (int i = 0; i < 4; ++i) {
      af_h[i] = *(const short8*)&Ah[wm + i*16 + l15][quad*8];
      af_l[i] = *(const short8*)&Al[wm + i*16 + l15][quad*8];
      bf_h[i] = *(const short8*)&Bh[wn + i*16 + l15][quad*8];
      bf_l[i] = *(const short8*)&Bl[wn + i*16 + l15][quad*8];
    }
    #pragma unroll
    for (int i = 0; i < 4; ++i)
      #pragma unroll
      for (int j = 0; j < 4; ++j) {
        acc[i][j] = __builtin_amdgcn_mfma_f32_16x16x32_bf16(af_h[i], bf_l[j], acc[i][j], 0,0,0);
        acc[i][j] = __builtin_amdgcn_mfma_f32_16x16x32_bf16(af_l[i], bf_h[j], acc[i][j], 0,0,0);
        acc[i][j] = __builtin_amdgcn_mfma_f32_16x16x32_bf16(af_h[i], bf_h[j], acc[i][j], 0,0,0);
      }
    __syncthreads();
  }
  #pragma unroll
  for (int j = 0; j < 4; ++j) {
    int col = n0 + wn + j*16 + l15;
    float bv = bias[col];
    #pragma unroll
    for (int i = 0; i < 4; ++i) {
      int rbase = m0 + wm + i*16 + quad*4;
      #pragma unroll
      for (int r = 0; r < 4; ++r) {
        int row = rbase + r;
        if (row < M) C[(size_t)row*N + col] = (CT)(acc[i][j][r] + bv);
      }
    }
  }
}

// ---------------- MFMA decoder ----------------
__global__ __launch_bounds__(256, 2)
void k_dec3(const float* __restrict__ z2,
            const int* __restrict__ eli,
            const u16* __restrict__ Wth, const u16* __restrict__ Wtl,
            const float* __restrict__ bd1,
            const float* __restrict__ Wd2, const float* __restrict__ bd2,
            float* __restrict__ out) {
  __shared__ __align__(16) u16 Ah[128][32], Al[128][32];
  __shared__ __align__(16) u16 Bh[128][32], Bl[128][32];
  __shared__ float pr[128][2];
  int tid = threadIdx.x;
  int e0 = blockIdx.x * 128;
  int wave = tid >> 6, lane = tid & 63;
  int wm = (wave & 1) * 64, wn = (wave >> 1) * 64;
  int l15 = lane & 15, quad = lane >> 4;
  int ar = tid >> 3;
  int ak = (tid & 7) * 4;
  int bn = tid >> 2;
  int bc = (tid & 3) * 8;
  int ia4[4], ib4[4];
  #pragma unroll
  for (int i = 0; i < 4; ++i) {
    int e = e0 + ar + 32*i;
    bool ev = e < ELN;
    int a = ev ? eli[e] : 0;      if ((u32)a >= (u32)NN) a = 0;
    int b = ev ? eli[ELN+e] : 0;  if ((u32)b >= (u32)NN) b = 0;
    ia4[i] = a; ib4[i] = b;
  }
  f32x4 acc[4][4] = {};
  for (int k0 = 0; k0 < 256; k0 += 32) {
    #pragma unroll
    for (int i = 0; i < 4; ++i) {
      int row = ar + 32*i;
      int kk = k0 + ak;
      const float* src = (kk < 128) ? &z2[(size_t)ia4[i]*128 + kk]
                                    : &z2[(size_t)ib4[i]*128 + (kk - 128)];
      float4 v = *(const float4*)src;
      float hv[4] = {v.x, v.y, v.z, v.w};
      u16 hi[4], lo[4];
      #pragma unroll
      for (int j = 0; j < 4; ++j) {
        hi[j] = f2us(hv[j]);
        lo[j] = f2us(hv[j] - us2f(hi[j]));
      }
      *(uint2*)&Ah[row][ak] = make_uint2(hi[0]|((u32)hi[1]<<16), hi[2]|((u32)hi[3]<<16));
      *(uint2*)&Al[row][ak] = make_uint2(lo[0]|((u32)lo[1]<<16), lo[2]|((u32)lo[3]<<16));
    }
    #pragma unroll
    for (int i = 0; i < 2; ++i) {
      int n = bn + 64*i;
      *(uint4*)&Bh[n][bc] = *(const uint4*)&Wth[(size_t)n*256 + k0 + bc];
      *(uint4*)&Bl[n][bc] = *(const uint4*)&Wtl[(size_t)n*256 + k0 + bc];
    }
    __syncthreads();
    short8 af_h[4], af_l[4], bf_h[4], bf_l[4];
    #pragma unroll
    for (int i = 0; i < 4; ++i) {
      af_h[i] = *(const short8*)&Ah[wm + i*16 + l15][quad*8];
      af_l[i] = *(const short8*)&Al[wm + i*16 + l15][quad*8];
      bf_h[i] = *(const short8*)&Bh[wn + i*16 + l15][quad*8];
      bf_l[i] = *(const short8*)&Bl[wn + i*16 + l15][quad*8];
    }
    #pragma unroll
    for (int i = 0; i < 4; ++i)
      #pragma unroll
      for (int j = 0; j < 4; ++j) {
        acc[i][j] = __builtin_amdgcn_mfma_f32_16x16x32_bf16(af_h[i], bf_l[j], acc[i][j], 0,0,0);
        acc[i][j] = __builtin_amdgcn_mfma_f32_16x16x32_bf16(af_l[i], bf_h[j], acc[i][j], 0,0,0);
        acc[i][j] = __builtin_amdgcn_mfma_f32_16x16x32_bf16(af_h[i], bf_h[j], acc[i][j], 0,0,0);
      }
    __syncthreads();
  }
  float w2c[4], bbc[4];
  #pragma unroll
  for (int j = 0; j < 4; ++j) {
    int col = wn + j*16 + l15;
    w2c[j] = Wd2[col];
    bbc[j] = bd1[col];
  }
  #pragma unroll
  for (int i = 0; i < 4; ++i) {
    #pragma unroll
    for (int r = 0; r < 4; ++r) {
      float part = 0.f;
      #pragma unroll
      for (int j = 0; j < 4; ++j)
        part += gelu_f(acc[i][j][r] + bbc[j]) * w2c[j];
      part += __shfl_xor(part,1); part += __shfl_xor(part,2);
      part += __shfl_xor(part,4); part += __shfl_xor(part,8);
      if (l15 == 0) pr[wm + i*16 + quad*4 + r][wn>>6] = part;
    }
  }
  __syncthreads();
  if (tid < 128) {
    int e = e0 + tid;
    if (e < ELN) out[e] = pr[tid][0] + pr[tid][1] + bd2[0];
  }
}

// ---------------- fallback f32 GEMM (compact path only) ----------------
template <typename AT, typename CT>
__global__ __launch_bounds__(256) void k_gemm(const AT* __restrict__ A,
                                              const float* __restrict__ W,
                                              const float* __restrict__ bias,
                                              CT* __restrict__ C,
                                              int M, int Nc, int K) {
  __shared__ __align__(16) float As[16][64];
  __shared__ __align__(16) float Bs[16][64];
  int tid = threadIdx.x;
  int m0 = blockIdx.x*64, n0 = blockIdx.y*64;
  int ty = tid >> 4, tx = tid & 15;
  int lrow = tid >> 2;
  int lk   = (tid & 3)*4;
  int wk   = tid >> 4;
  int wn   = (tid & 15)*4;
  float acc[4][4] = {};
  for (int k0 = 0; k0 < K; k0 += 16) {
    int row = m0 + lrow;
    if (row < M) {
      float a4[4]; ld4v(&A[(size_t)row*K + k0 + lk], a4);
      As[lk+0][lrow]=a4[0]; As[lk+1][lrow]=a4[1]; As[lk+2][lrow]=a4[2]; As[lk+3][lrow]=a4[3];
    } else {
      #pragma unroll
      for (int j=0;j<4;++j) As[lk+j][lrow]=0.f;
    }
    {
      float4 bv4 = *(const float4*)&W[(size_t)(k0+wk)*Nc + n0 + wn];
      Bs[wk][wn+0]=bv4.x; Bs[wk][wn+1]=bv4.y; Bs[wk][wn+2]=bv4.z; Bs[wk][wn+3]=bv4.w;
    }
    __syncthreads();
    #pragma unroll
    for (int kk=0;kk<16;++kk) {
      float4 av = *(const float4*)&As[kk][ty*4];
      float4 bv = *(const float4*)&Bs[kk][tx*4];
      float a[4]={av.x,av.y,av.z,av.w}, b[4]={bv.x,bv.y,bv.z,bv.w};
      #pragma unroll
      for (int i=0;i<4;++i)
        #pragma unroll
        for (int j=0;j<4;++j)
          acc[i][j] += a[i]*b[j];
    }
    __syncthreads();
  }
  float bv[4];
  #pragma unroll
  for (int j=0;j<4;++j) bv[j] = bias[n0 + tx*4 + j];
  #pragma unroll
  for (int i=0;i<4;++i) {
    int row = m0 + ty*4 + i;
    if (row < M) {
      float o4[4] = {acc[i][0]+bv[0], acc[i][1]+bv[1], acc[i][2]+bv[2], acc[i][3]+bv[3]};
      st4v(&C[(size_t)row*Nc + n0 + tx*4], o4);
    }
  }
}

// ---------------- edge layer 1 (H=4, C=128), gelu fused ----------------
template <typename TI, typename TO>
__global__ __launch_bounds__(256) void k_edge1(const TI* __restrict__ xl,
                                               const TI* __restrict__ xr,
                                               const float* __restrict__ att,
                                               const float* __restrict__ bias,
                                               const int* __restrict__ row_ptr,
                                               const int* __restrict__ col,
                                               TO* __restrict__ z1) {
  int wid = (blockIdx.x*blockDim.x + threadIdx.x) >> 6;
  if (wid >= NN) return;
  int lane = threadIdx.x & 63;
  int c8 = lane*8;
  float xi[8], av[8], acc[8] = {};
  ld8v(&xr[(size_t)wid*C1 + c8], xi);
  #pragma unroll
  for (int j=0;j<8;++j) av[j] = att[c8+j];
  float m = -1e30f, s = 0.f;
  int e0 = row_ptr[wid], e1 = row_ptr[wid+1];
  for (int e = e0; e < e1; ++e) {
    int sn = col[e]; if ((u32)sn >= (u32)NN) sn = 0;
    float xj[8];
    ld8v(&xl[(size_t)sn*C1 + c8], xj);
    float part = 0.f;
    #pragma unroll
    for (int j=0;j<8;++j) {
      float t = xi[j] + xj[j];
      t = t > 0.f ? t : 0.2f*t;      // leaky_relu 0.2
      part += t*av[j];
    }
    part += __shfl_xor(part,1); part += __shfl_xor(part,2);
    part += __shfl_xor(part,4); part += __shfl_xor(part,8);
    float mn = fmaxf(m, part);
    float f = __expf(m - mn), w = __expf(part - mn);
    s = s*f + w;
    #pragma unroll
    for (int j=0;j<8;++j) acc[j] = acc[j]*f + w*xj[j];
    m = mn;
  }
  float inv = 1.f/s, o[8];
  #pragma unroll
  for (int j=0;j<8;++j) o[j] = gelu_f(acc[j]*inv + bias[c8+j]);
  st8v(&z1[(size_t)wid*C1 + c8], o);
}

// ---------------- edge layer 2 (H=1, C=128) ----------------
template <typename TI>
__global__ __launch_bounds__(256) void k_edge2(const TI* __restrict__ xl,
                                               const TI* __restrict__ xr,
                                               const float* __restrict__ att,
                                               const float* __restrict__ bias,
                                               const int* __restrict__ row_ptr,
                                               const int* __restrict__ col,
                                               float* __restrict__ z2) {
  int wid = (blockIdx.x*blockDim.x + threadIdx.x) >> 6;
  if (wid >= NN) return;
  int lane = threadIdx.x & 63;
  int c2 = lane*2;
  float xiv[2];
  ld2v(&xr[(size_t)wid*C2 + c2], xiv);
  float a0 = att[c2], a1 = att[c2+1];
  float m = -1e30f, s = 0.f, ac0 = 0.f, ac1 = 0.f;
  int e0 = row_ptr[wid], e1 = row_ptr[wid+1];
  for (int e = e0; e < e1; ++e) {
    int sn = col[e]; if ((u32)sn >= (u32)NN) sn = 0;
    float xj[2];
    ld2v(&xl[(size_t)sn*C2 + c2], xj);
    float t0 = xiv[0] + xj[0]; t0 = t0 > 0.f ? t0 : 0.2f*t0;
    float t1 = xiv[1] + xj[1]; t1 = t1 > 0.f ? t1 : 0.2f*t1;
    float part = t0*a0 + t1*a1;
    part += __shfl_xor(part,1);  part += __shfl_xor(part,2);
    part += __shfl_xor(part,4);  part += __shfl_xor(part,8);
    part += __shfl_xor(part,16); part += __shfl_xor(part,32);
    float mn = fmaxf(m, part);
    float f = __expf(m - mn), w = __expf(part - mn);
    s = s*f + w;
    ac0 = ac0*f + w*xj[0];
    ac1 = ac1*f + w*xj[1];
    m = mn;
  }
  float inv = 1.f/s;
  z2[(size_t)wid*C2 + c2]   = ac0*inv + bias[c2];
  z2[(size_t)wid*C2 + c2+1] = ac1*inv + bias[c2+1];
}

// ---------------- f32 decoder (compact path fallback) ----------------
__global__ __launch_bounds__(256) void k_dec2(const float* __restrict__ z2,
                                              const int* __restrict__ eli,
                                              const float* __restrict__ Wd1,
                                              const float* __restrict__ bd1,
                                              const float* __restrict__ Wd2,
                                              const float* __restrict__ bd2,
                                              float* __restrict__ out) {
  __shared__ __align__(16) float As[16][64];
  __shared__ __align__(16) float Bs[16][128];
  int tid = threadIdx.x;
  int e0 = blockIdx.x * 64;
  int ty = tid >> 4, tx = tid & 15;
  int lrow = tid >> 2;
  int lk   = (tid & 3) * 4;
  int wk   = tid >> 4;
  int wn   = (tid & 15) * 8;
  int e = e0 + lrow;
  bool ev = e < ELN;
  int ia = ev ? eli[e] : 0;       if ((u32)ia >= (u32)NN) ia = 0;
  int ib = ev ? eli[ELN+e] : 0;   if ((u32)ib >= (u32)NN) ib = 0;
  float acc[4][8] = {};
  for (int k0 = 0; k0 < 256; k0 += 16) {
    int kk4 = k0 + lk;
    const float* src = (kk4 < 128) ? &z2[(size_t)ia*128 + kk4]
                                   : &z2[(size_t)ib*128 + (kk4 - 128)];
    float4 a4 = ev ? *(const float4*)src : make_float4(0.f,0.f,0.f,0.f);
    As[lk+0][lrow]=a4.x; As[lk+1][lrow]=a4.y; As[lk+2][lrow]=a4.z; As[lk+3][lrow]=a4.w;
    *(float4*)&Bs[wk][wn]   = *(const float4*)&Wd1[(size_t)(k0+wk)*128 + wn];
    *(float4*)&Bs[wk][wn+4] = *(const float4*)&Wd1[(size_t)(k0+wk)*128 + wn + 4];
    __syncthreads();
    #pragma unroll
    for (int kk = 0; kk < 16; ++kk) {
      float4 av = *(const float4*)&As[kk][ty*4];
      float a[4] = {av.x, av.y, av.z, av.w};
      float4 b0 = *(const float4*)&Bs[kk][tx*4];
      float4 b1 = *(const float4*)&Bs[kk][64 + tx*4];
      float b[8] = {b0.x,b0.y,b0.z,b0.w,b1.x,b1.y,b1.z,b1.w};
      #pragma unroll
      for (int i = 0; i < 4; ++i)
        #pragma unroll
        for (int j = 0; j < 8; ++j)
          acc[i][j] += a[i]*b[j];
    }
    __syncthreads();
  }
  float w2[8], bb[8];
  #pragma unroll
  for (int j = 0; j < 4; ++j) {
    w2[j]   = Wd2[tx*4+j];      bb[j]   = bd1[tx*4+j];
    w2[j+4] = Wd2[64+tx*4+j];   bb[j+4] = bd1[64+tx*4+j];
  }
  float b2 = bd2[0];
  #pragma unroll
  for (int i = 0; i < 4; ++i) {
    float part = 0.f;
    #pragma unroll
    for (int j = 0; j < 8; ++j)
      part += gelu_f(acc[i][j] + bb[j]) * w2[j];
    part += __shfl_xor(part,1); part += __shfl_xor(part,2);
    part += __shfl_xor(part,4); part += __shfl_xor(part,8);
    int row = e0 + ty*4 + i;
    if (tx == 0 && row < ELN) out[row] = part + b2;
  }
}

__global__ void k_tiny(float* out, float code) {
  if (threadIdx.x == 0) out[0] = code;
}

// ---------------- launch ----------------
extern "C" void kernel_launch(void* const* d_in, const int* in_sizes, int n_in,
                              void* d_out, int out_size, void* d_ws, size_t ws_size,
                              hipStream_t stream) {
  const float* x     = (const float*)d_in[0];
  const int*   ei    = (const int*)  d_in[1];
  const int*   eli   = (const int*)  d_in[2];
  const float* Wl1   = (const float*)d_in[3];
  const float* bl1   = (const float*)d_in[4];
  const float* Wr1   = (const float*)d_in[5];
  const float* br1   = (const float*)d_in[6];
  const float* att1  = (const float*)d_in[7];
  const float* bias1 = (const float*)d_in[8];
  const float* Wl2   = (const float*)d_in[9];
  const float* bl2   = (const float*)d_in[10];
  const float* Wr2   = (const float*)d_in[11];
  const float* br2   = (const float*)d_in[12];
  const float* att2  = (const float*)d_in[13];
  const float* bias2 = (const float*)d_in[14];
  const float* Wd1   = (const float*)d_in[15];
  const float* bd1   = (const float*)d_in[16];
  const float* Wd2   = (const float*)d_in[17];
  const float* bd2   = (const float*)d_in[18];
  float* out = (float*)d_out;

  constexpr size_t INTW = (size_t)(NN+1) + NN + ETOT;          // 380001 words
  constexpr size_t FULL_WORDS = 3ull*NN*C1 + INTW;             // ~124.4 MB (proven available)
  constexpr size_t CMP_WORDS  = 3ull*NN*C1/2 + INTW;           // ~63 MB

  bool full    = ws_size >= FULL_WORDS*4;
  bool compact = !full && ws_size >= CMP_WORDS*4;
  if (!full && !compact) {
    size_t mb = ws_size >> 20;
    k_tiny<<<1, 64, 0, stream>>>(out, 16384.f + (float)mb);
    return;
  }

  size_t regA = full ? (size_t)NN*C1 : (size_t)NN*C1/2;   // words per region
  char* base = (char*)d_ws;
  void* wA = base;
  void* wB = base + regA*4;
  void* wC = base + 2*regA*4;
  int* row_ptr = (int*)(base + 3*regA*4);
  int* cnt     = row_ptr + (NN + 1);
  int* col     = cnt + NN;
  int* bsum    = (int*)wA;   // scan scratch: wA dead during CSR phase

  // CSR over dst
  hipMemsetAsync(cnt, 0, NN*sizeof(int), stream);
  k_hist<<<(ETOT+255)/256, 256, 0, stream>>>(ei, cnt);
  k_scan_a<<<NB, 256, 0, stream>>>(cnt, row_ptr, bsum);
  k_scan_b<<<1, 128, 0, stream>>>(bsum, row_ptr);
  k_scan_c<<<NB, 256, 0, stream>>>(row_ptr, bsum, cnt);
  k_scatter<<<(ETOT+255)/256, 256, 0, stream>>>(ei, cnt, col);

  if (full) {
    _Float16* xl1 = (_Float16*)wA;    // 20.5 MB
    _Float16* xr1 = (_Float16*)wB;
    float*    z1  = (float*)wC;       // 41 MB
    // layer-1 weight planes at start of region C (dead once z1 written in k_edge1)
    u16* wl1th = (u16*)wC;            u16* wl1tl = wl1th + 512*256;
    u16* wr1th = wl1tl + 512*256;     u16* wr1tl = wr1th + 512*256;
    // layer-2 + decoder weight planes at wA+16MB (xl1 dead after k_edge1; xl2 uses first 5.12 MB)
    u16* wl2th = (u16*)((char*)wA + (16u<<20));  u16* wl2tl = wl2th + 128*512;
    u16* wr2th = wl2tl + 128*512;                u16* wr2tl = wr2th + 128*512;
    u16* wdth  = wr2tl + 128*512;                u16* wdtl  = wdth  + 128*256;
    _Float16* xl2 = (_Float16*)wA;    // 5.12 MB
    _Float16* xr2 = (_Float16*)wB;
    float*    z2  = (float*)wC;       // z1 dead after mgemm2

    k_wsplit<<<(512*256+255)/256, 256, 0, stream>>>(Wl1, wl1th, wl1tl, INC, C1);
    k_wsplit<<<(512*256+255)/256, 256, 0, stream>>>(Wr1, wr1th, wr1tl, INC, C1);
    dim3 gm1((NN+127)/128, C1/128);
    k_mgemm<_Float16><<<gm1, 256, 0, stream>>>(x, wl1th, wl1tl, bl1, xl1, NN, C1, INC);
    k_mgemm<_Float16><<<gm1, 256, 0, stream>>>(x, wr1th, wr1tl, br1, xr1, NN, C1, INC);
    k_edge1<_Float16,float><<<NN/4, 256, 0, stream>>>(xl1, xr1, att1, bias1, row_ptr, col, z1);
    k_wsplit<<<(128*512+255)/256, 256, 0, stream>>>(Wl2, wl2th, wl2tl, C1, C2);
    k_wsplit<<<(128*512+255)/256, 256, 0, stream>>>(Wr2, wr2th, wr2tl, C1, C2);
    k_wsplit<<<(128*256+255)/256, 256, 0, stream>>>(Wd1, wdth, wdtl, 256, 128);
    dim3 gm2((NN+127)/128, C2/128);
    k_mgemm<_Float16><<<gm2, 256, 0, stream>>>(z1, wl2th, wl2tl, bl2, xl2, NN, C2, C1);
    k_mgemm<_Float16><<<gm2, 256, 0, stream>>>(z1, wr2th, wr2tl, br2, xr2, NN, C2, C1);
    k_edge2<_Float16><<<NN/4, 256, 0, stream>>>(xl2, xr2, att2, bias2, row_ptr, col, z2);
    k_dec3<<<(ELN+127)/128, 256, 0, stream>>>(z2, eli, wdth, wdtl, bd1, Wd2, bd2, out);
  } else {
    u16* xl1 = (u16*)wA;
    u16* xr1 = (u16*)wB;
    u16* z1  = (u16*)wC;
    float* xl2 = (float*)wA;
    float* xr2 = (float*)wB;
    float* z2  = (float*)wC;
    dim3 g1((NN+63)/64, C1/64);
    dim3 g2((NN+63)/64, C2/64);
    k_gemm<float,u16><<<g1, 256, 0, stream>>>(x, Wl1, bl1, xl1, NN, C1, INC);
    k_gemm<float,u16><<<g1, 256, 0, stream>>>(x, Wr1, br1, xr1, NN, C1, INC);
    k_edge1<u16,u16><<<NN/4, 256, 0, stream>>>(xl1, xr1, att1, bias1, row_ptr, col, z1);
    k_gemm<u16,float><<<g2, 256, 0, stream>>>(z1, Wl2, bl2, xl2, NN, C2, C1);
    k_gemm<u16,float><<<g2, 256, 0, stream>>>(z1, Wr2, br2, xr2, NN, C2, C1);
    k_edge2<float><<<NN/4, 256, 0, stream>>>(xl2, xr2, att2, bias2, row_ptr, col, z2);
    k_dec2<<<(ELN+63)/64, 256, 0, stream>>>(z2, eli, Wd1, bd1, Wd2, bd2, out);
  }
}

// Round 9
// 424.403 us; speedup vs baseline: 2.1048x; 1.1212x over previous
//
#include <hip/hip_runtime.h>
#include <hip/hip_bf16.h>
#include <math.h>
#include <stdint.h>

using bf16 = __hip_bfloat16;
typedef unsigned short u16;
typedef unsigned int   u32;
typedef __attribute__((ext_vector_type(8))) short short8;   // 8 bf16 bit patterns
typedef __attribute__((ext_vector_type(4))) float f32x4;

static constexpr int NN   = 20000;
static constexpr int EE   = 320000;
static constexpr int ELN  = 100000;
static constexpr int ETOT = EE + NN;
static constexpr int INC  = 256;
static constexpr int C1   = 512;
static constexpr int C2   = 128;
static constexpr int NB   = (NN + 255) / 256;   // scan blocks = 79

__device__ __forceinline__ float us2f(u16 u){ union{u32 i; float f;}x; x.i=((u32)u)<<16; return x.f; }
__device__ __forceinline__ u16  f2us(float f){ union{bf16 h; u16 u;}c; c.h=__float2bfloat16(f); return c.u; }
__device__ __forceinline__ float h2f(u16 u){ union{u16 u; _Float16 h;}c; c.u=u; return (float)c.h; }
// tanh-approx gelu via hw exp: tanh(t) = 1 - 2/(e^{2t}+1)
__device__ __forceinline__ float gelu_f(float x){
  float u = 1.5957691216057308f*(x + 0.044715f*x*x*x);
  float ex = __expf(u);
  float th = 1.f - 2.f/(ex + 1.f);
  return 0.5f*x*(1.f+th);
}
__device__ __forceinline__ void ld4v(const float* p, float* o){ float4 v=*(const float4*)p; o[0]=v.x;o[1]=v.y;o[2]=v.z;o[3]=v.w; }
__device__ __forceinline__ void ld4v(const u16* p, float* o){ uint2 v=*(const uint2*)p;
  o[0]=us2f(v.x&0xffff);o[1]=us2f(v.x>>16);o[2]=us2f(v.y&0xffff);o[3]=us2f(v.y>>16); }
__device__ __forceinline__ void ld4v(const _Float16* p, float* o){ uint2 v=*(const uint2*)p;
  o[0]=h2f(v.x&0xffff);o[1]=h2f(v.x>>16);o[2]=h2f(v.y&0xffff);o[3]=h2f(v.y>>16); }
__device__ __forceinline__ void ld8v(const float* p, float* o){ ld4v(p,o); ld4v(p+4,o+4); }
__device__ __forceinline__ void ld8v(const u16* p, float* o){ uint4 v=*(const uint4*)p;
  o[0]=us2f(v.x&0xffff);o[1]=us2f(v.x>>16);o[2]=us2f(v.y&0xffff);o[3]=us2f(v.y>>16);
  o[4]=us2f(v.z&0xffff);o[5]=us2f(v.z>>16);o[6]=us2f(v.w&0xffff);o[7]=us2f(v.w>>16); }
__device__ __forceinline__ void ld8v(const _Float16* p, float* o){ uint4 v=*(const uint4*)p;
  o[0]=h2f(v.x&0xffff);o[1]=h2f(v.x>>16);o[2]=h2f(v.y&0xffff);o[3]=h2f(v.y>>16);
  o[4]=h2f(v.z&0xffff);o[5]=h2f(v.z>>16);o[6]=h2f(v.w&0xffff);o[7]=h2f(v.w>>16); }
__device__ __forceinline__ void ld2v(const float* p, float* o){ float2 v=*(const float2*)p; o[0]=v.x;o[1]=v.y; }
__device__ __forceinline__ void ld2v(const _Float16* p, float* o){ u32 w=*(const u32*)p;
  o[0]=h2f(w&0xffff); o[1]=h2f(w>>16); }
__device__ __forceinline__ void st4v(float* p, const float* v){ *(float4*)p = make_float4(v[0],v[1],v[2],v[3]); }
__device__ __forceinline__ void st4v(u16* p, const float* v){ uint2 o;
  o.x=f2us(v[0])|((u32)f2us(v[1])<<16); o.y=f2us(v[2])|((u32)f2us(v[3])<<16); *(uint2*)p=o; }
__device__ __forceinline__ void st8v(float* p, const float* v){ st4v(p,v); st4v(p+4,v+4); }
__device__ __forceinline__ void st8v(u16* p, const float* v){ uint4 o;
  o.x=f2us(v[0])|((u32)f2us(v[1])<<16); o.y=f2us(v[2])|((u32)f2us(v[3])<<16);
  o.z=f2us(v[4])|((u32)f2us(v[5])<<16); o.w=f2us(v[6])|((u32)f2us(v[7])<<16); *(uint4*)p=o; }
__device__ __forceinline__ void st8v(_Float16* p, const float* v){
  union{ _Float16 h[8]; uint4 u; } c;
  #pragma unroll
  for (int j=0;j<8;++j) c.h[j] = (_Float16)v[j];
  *(uint4*)p = c.u; }

// ---------------- CSR ----------------
__global__ void k_hist(const int* __restrict__ ei, int* __restrict__ cnt) {
  int e = blockIdx.x*blockDim.x + threadIdx.x;
  if (e < ETOT) {
    int d = (e < EE) ? ei[EE + e] : (e - EE);
    if ((u32)d < (u32)NN) atomicAdd(&cnt[d], 1);
  }
}
__global__ void k_scan_a(const int* __restrict__ cnt, int* __restrict__ row_ptr,
                         int* __restrict__ bsum) {
  __shared__ int buf[256];
  int idx = blockIdx.x*256 + threadIdx.x;
  int v = (idx < NN) ? cnt[idx] : 0;
  buf[threadIdx.x] = v;
  __syncthreads();
  for (int off = 1; off < 256; off <<= 1) {
    int t = (threadIdx.x >= off) ? buf[threadIdx.x - off] : 0;
    __syncthreads();
    buf[threadIdx.x] += t;
    __syncthreads();
  }
  if (idx < NN) row_ptr[idx] = buf[threadIdx.x] - v;
  if (threadIdx.x == 255) bsum[blockIdx.x] = buf[255];
}
__global__ void k_scan_b(int* __restrict__ bsum, int* __restrict__ row_ptr) {
  __shared__ int buf[128];
  int v = (threadIdx.x < NB) ? bsum[threadIdx.x] : 0;
  buf[threadIdx.x] = v;
  __syncthreads();
  for (int off = 1; off < 128; off <<= 1) {
    int t = (threadIdx.x >= off) ? buf[threadIdx.x - off] : 0;
    __syncthreads();
    buf[threadIdx.x] += t;
    __syncthreads();
  }
  if (threadIdx.x < NB) bsum[threadIdx.x] = buf[threadIdx.x] - v;
  if (threadIdx.x == 127) row_ptr[NN] = buf[127];
}
__global__ void k_scan_c(int* __restrict__ row_ptr, const int* __restrict__ bsum,
                         int* __restrict__ cur) {
  int idx = blockIdx.x*256 + threadIdx.x;
  if (idx < NN) {
    int v = row_ptr[idx] + bsum[blockIdx.x];
    row_ptr[idx] = v;
    cur[idx] = v;
  }
}
__global__ void k_scatter(const int* __restrict__ ei, int* __restrict__ cur,
                          int* __restrict__ col) {
  int e = blockIdx.x*blockDim.x + threadIdx.x;
  if (e < ETOT) {
    int s, d;
    if (e < EE) { s = ei[e]; d = ei[EE + e]; } else { s = d = e - EE; }
    if ((u32)d >= (u32)NN) d = 0;
    int pos = atomicAdd(&cur[d], 1);
    if ((u32)pos < (u32)ETOT) col[pos] = s;
  }
}

// ---------------- batched weight transpose + hi/lo split ----------------
struct WsArgs { const float* src[5]; u16* th[5]; u16* tl[5]; int K[5]; int N[5]; };
__global__ __launch_bounds__(256) void k_wsplit_all(WsArgs a) {
  int seg = blockIdx.y;
  int K = a.K[seg], N = a.N[seg];
  int n = K * N;
  int idx = blockIdx.x*256 + threadIdx.x;
  if (idx >= n) return;
  int nn = idx / K, k = idx - nn*K;
  float v = a.src[seg][(size_t)k*N + nn];
  u16 h = f2us(v);
  a.th[seg][idx] = h;
  a.tl[seg][idx] = f2us(v - us2f(h));
}

// ---------------- MFMA GEMM: C[M,N] = A[M,K] @ B + bias ----------------
// D = Ah*Bh + Ah*Bl + Al*Bh. AT in {float,_Float16} (fp16 hi/lo split is exact); CT likewise.
template <typename AT, typename CT>
__global__ __launch_bounds__(256, 2)
void k_mgemm(const AT* __restrict__ A,
             const u16* __restrict__ Bth, const u16* __restrict__ Btl,
             const float* __restrict__ bias, CT* __restrict__ C,
             int M, int N, int K) {
  __shared__ __align__(16) u16 Ah[128][32], Al[128][32];
  __shared__ __align__(16) u16 Bh[128][32], Bl[128][32];
  int tid = threadIdx.x;
  int m0 = blockIdx.x * 128, n0 = blockIdx.y * 128;
  int wave = tid >> 6, lane = tid & 63;
  int wm = (wave & 1) * 64, wn = (wave >> 1) * 64;
  int l15 = lane & 15, quad = lane >> 4;
  f32x4 acc[4][4] = {};
  int ar = tid >> 3;
  int ak = (tid & 7) * 4;
  int bn = tid >> 2;
  int bc = (tid & 3) * 8;
  for (int k0 = 0; k0 < K; k0 += 32) {
    #pragma unroll
    for (int i = 0; i < 4; ++i) {
      int row = ar + 32*i;
      int gr = m0 + row;
      float hv[4] = {0.f, 0.f, 0.f, 0.f};
      if (gr < M) ld4v(&A[(size_t)gr*K + k0 + ak], hv);
      u16 hi[4], lo[4];
      #pragma unroll
      for (int j = 0; j < 4; ++j) {
        hi[j] = f2us(hv[j]);
        lo[j] = f2us(hv[j] - us2f(hi[j]));
      }
      *(uint2*)&Ah[row][ak] = make_uint2(hi[0]|((u32)hi[1]<<16), hi[2]|((u32)hi[3]<<16));
      *(uint2*)&Al[row][ak] = make_uint2(lo[0]|((u32)lo[1]<<16), lo[2]|((u32)lo[3]<<16));
    }
    #pragma unroll
    for (int i = 0; i < 2; ++i) {
      int n = bn + 64*i;
      *(uint4*)&Bh[n][bc] = *(const uint4*)&Bth[(size_t)(n0+n)*K + k0 + bc];
      *(uint4*)&Bl[n][bc] = *(const uint4*)&Btl[(size_t)(n0+n)*K + k0 + bc];
    }
    __syncthreads();
    short8 af_h[4], af_l[4], bf_h[4], bf_l[4];
    #pragma unroll
    for (int i = 0; i < 4; ++i) {
      af_h[i] = *(const short8*)&Ah[wm + i*16 + l15][quad*8];
      af_l[i] = *(const short8*)&Al[wm + i*16 + l15][quad*8];
      bf_h[i] = *(const short8*)&Bh[wn + i*16 + l15][quad*8];
      bf_l[i] = *(const short8*)&Bl[wn + i*16 + l15][quad*8];
    }
    #pragma unroll
    for (int i = 0; i < 4; ++i)
      #pragma unroll
      for (int j = 0; j < 4; ++j) {
        acc[i][j] = __builtin_amdgcn_mfma_f32_16x16x32_bf16(af_h[i], bf_l[j], acc[i][j], 0,0,0);
        acc[i][j] = __builtin_amdgcn_mfma_f32_16x16x32_bf16(af_l[i], bf_h[j], acc[i][j], 0,0,0);
        acc[i][j] = __builtin_amdgcn_mfma_f32_16x16x32_bf16(af_h[i], bf_h[j], acc[i][j], 0,0,0);
      }
    __syncthreads();
  }
  #pragma unroll
  for (int j = 0; j < 4; ++j) {
    int col = n0 + wn + j*16 + l15;
    float bv = bias[col];
    #pragma unroll
    for (int i = 0; i < 4; ++i) {
      int rbase = m0 + wm + i*16 + quad*4;
      #pragma unroll
      for (int r = 0; r < 4; ++r) {
        int row = rbase + r;
        if (row < M) C[(size_t)row*N + col] = (CT)(acc[i][j][r] + bv);
      }
    }
  }
}

// ---------------- MFMA decoder (z2 fp16) ----------------
__global__ __launch_bounds__(256, 2)
void k_dec3(const _Float16* __restrict__ z2,
            const int* __restrict__ eli,
            const u16* __restrict__ Wth, const u16* __restrict__ Wtl,
            const float* __restrict__ bd1,
            const float* __restrict__ Wd2, const float* __restrict__ bd2,
            float* __restrict__ out) {
  __shared__ __align__(16) u16 Ah[128][32], Al[128][32];
  __shared__ __align__(16) u16 Bh[128][32], Bl[128][32];
  __shared__ float pr[128][2];
  int tid = threadIdx.x;
  int e0 = blockIdx.x * 128;
  int wave = tid >> 6, lane = tid & 63;
  int wm = (wave & 1) * 64, wn = (wave >> 1) * 64;
  int l15 = lane & 15, quad = lane >> 4;
  int ar = tid >> 3;
  int ak = (tid & 7) * 4;
  int bn = tid >> 2;
  int bc = (tid & 3) * 8;
  int ia4[4], ib4[4];
  #pragma unroll
  for (int i = 0; i < 4; ++i) {
    int e = e0 + ar + 32*i;
    bool ev = e < ELN;
    int a = ev ? eli[e] : 0;      if ((u32)a >= (u32)NN) a = 0;
    int b = ev ? eli[ELN+e] : 0;  if ((u32)b >= (u32)NN) b = 0;
    ia4[i] = a; ib4[i] = b;
  }
  f32x4 acc[4][4] = {};
  for (int k0 = 0; k0 < 256; k0 += 32) {
    #pragma unroll
    for (int i = 0; i < 4; ++i) {
      int row = ar + 32*i;
      int kk = k0 + ak;
      const _Float16* src = (kk < 128) ? &z2[(size_t)ia4[i]*128 + kk]
                                       : &z2[(size_t)ib4[i]*128 + (kk - 128)];
      float hv[4];
      ld4v(src, hv);
      u16 hi[4], lo[4];
      #pragma unroll
      for (int j = 0; j < 4; ++j) {
        hi[j] = f2us(hv[j]);
        lo[j] = f2us(hv[j] - us2f(hi[j]));
      }
      *(uint2*)&Ah[row][ak] = make_uint2(hi[0]|((u32)hi[1]<<16), hi[2]|((u32)hi[3]<<16));
      *(uint2*)&Al[row][ak] = make_uint2(lo[0]|((u32)lo[1]<<16), lo[2]|((u32)lo[3]<<16));
    }
    #pragma unroll
    for (int i = 0; i < 2; ++i) {
      int n = bn + 64*i;
      *(uint4*)&Bh[n][bc] = *(const uint4*)&Wth[(size_t)n*256 + k0 + bc];
      *(uint4*)&Bl[n][bc] = *(const uint4*)&Wtl[(size_t)n*256 + k0 + bc];
    }
    __syncthreads();
    short8 af_h[4], af_l[4], bf_h[4], bf_l[4];
    #pragma unroll
    for (int i = 0; i < 4; ++i) {
      af_h[i] = *(const short8*)&Ah[wm + i*16 + l15][quad*8];
      af_l[i] = *(const short8*)&Al[wm + i*16 + l15][quad*8];
      bf_h[i] = *(const short8*)&Bh[wn + i*16 + l15][quad*8];
      bf_l[i] = *(const short8*)&Bl[wn + i*16 + l15][quad*8];
    }
    #pragma unroll
    for (int i = 0; i < 4; ++i)
      #pragma unroll
      for (int j = 0; j < 4; ++j) {
        acc[i][j] = __builtin_amdgcn_mfma_f32_16x16x32_bf16(af_h[i], bf_l[j], acc[i][j], 0,0,0);
        acc[i][j] = __builtin_amdgcn_mfma_f32_16x16x32_bf16(af_l[i], bf_h[j], acc[i][j], 0,0,0);
        acc[i][j] = __builtin_amdgcn_mfma_f32_16x16x32_bf16(af_h[i], bf_h[j], acc[i][j], 0,0,0);
      }
    __syncthreads();
  }
  float w2c[4], bbc[4];
  #pragma unroll
  for (int j = 0; j < 4; ++j) {
    int col = wn + j*16 + l15;
    w2c[j] = Wd2[col];
    bbc[j] = bd1[col];
  }
  #pragma unroll
  for (int i = 0; i < 4; ++i) {
    #pragma unroll
    for (int r = 0; r < 4; ++r) {
      float part = 0.f;
      #pragma unroll
      for (int j = 0; j < 4; ++j)
        part += gelu_f(acc[i][j][r] + bbc[j]) * w2c[j];
      part += __shfl_xor(part,1); part += __shfl_xor(part,2);
      part += __shfl_xor(part,4); part += __shfl_xor(part,8);
      if (l15 == 0) pr[wm + i*16 + quad*4 + r][wn>>6] = part;
    }
  }
  __syncthreads();
  if (tid < 128) {
    int e = e0 + tid;
    if (e < ELN) out[e] = pr[tid][0] + pr[tid][1] + bd2[0];
  }
}

// ---------------- fallback f32 GEMM (compact path only) ----------------
template <typename AT, typename CT>
__global__ __launch_bounds__(256) void k_gemm(const AT* __restrict__ A,
                                              const float* __restrict__ W,
                                              const float* __restrict__ bias,
                                              CT* __restrict__ C,
                                              int M, int Nc, int K) {
  __shared__ __align__(16) float As[16][64];
  __shared__ __align__(16) float Bs[16][64];
  int tid = threadIdx.x;
  int m0 = blockIdx.x*64, n0 = blockIdx.y*64;
  int ty = tid >> 4, tx = tid & 15;
  int lrow = tid >> 2;
  int lk   = (tid & 3)*4;
  int wk   = tid >> 4;
  int wn   = (tid & 15)*4;
  float acc[4][4] = {};
  for (int k0 = 0; k0 < K; k0 += 16) {
    int row = m0 + lrow;
    if (row < M) {
      float a4[4]; ld4v(&A[(size_t)row*K + k0 + lk], a4);
      As[lk+0][lrow]=a4[0]; As[lk+1][lrow]=a4[1]; As[lk+2][lrow]=a4[2]; As[lk+3][lrow]=a4[3];
    } else {
      #pragma unroll
      for (int j=0;j<4;++j) As[lk+j][lrow]=0.f;
    }
    {
      float4 bv4 = *(const float4*)&W[(size_t)(k0+wk)*Nc + n0 + wn];
      Bs[wk][wn+0]=bv4.x; Bs[wk][wn+1]=bv4.y; Bs[wk][wn+2]=bv4.z; Bs[wk][wn+3]=bv4.w;
    }
    __syncthreads();
    #pragma unroll
    for (int kk=0;kk<16;++kk) {
      float4 av = *(const float4*)&As[kk][ty*4];
      float4 bv = *(const float4*)&Bs[kk][tx*4];
      float a[4]={av.x,av.y,av.z,av.w}, b[4]={bv.x,bv.y,bv.z,bv.w};
      #pragma unroll
      for (int i=0;i<4;++i)
        #pragma unroll
        for (int j=0;j<4;++j)
          acc[i][j] += a[i]*b[j];
    }
    __syncthreads();
  }
  float bv[4];
  #pragma unroll
  for (int j=0;j<4;++j) bv[j] = bias[n0 + tx*4 + j];
  #pragma unroll
  for (int i=0;i<4;++i) {
    int row = m0 + ty*4 + i;
    if (row < M) {
      float o4[4] = {acc[i][0]+bv[0], acc[i][1]+bv[1], acc[i][2]+bv[2], acc[i][3]+bv[3]};
      st4v(&C[(size_t)row*Nc + n0 + tx*4], o4);
    }
  }
}

// ---------------- edge layer 1 (H=4, C=128), gelu fused, 2-edge unrolled ----------------
template <typename TI, typename TO>
__global__ __launch_bounds__(256) void k_edge1(const TI* __restrict__ xl,
                                               const TI* __restrict__ xr,
                                               const float* __restrict__ att,
                                               const float* __restrict__ bias,
                                               const int* __restrict__ row_ptr,
                                               const int* __restrict__ col,
                                               TO* __restrict__ z1) {
  int wid = (blockIdx.x*blockDim.x + threadIdx.x) >> 6;
  if (wid >= NN) return;
  int lane = threadIdx.x & 63;
  int c8 = lane*8;
  float xi[8], av[8], acc[8] = {};
  ld8v(&xr[(size_t)wid*C1 + c8], xi);
  #pragma unroll
  for (int j=0;j<8;++j) av[j] = att[c8+j];
  float m = -1e30f, s = 0.f;
  int e0 = row_ptr[wid], e1 = row_ptr[wid+1];
  int e = e0;
  if ((e1 - e0) & 1) {
    int sn = col[e]; if ((u32)sn >= (u32)NN) sn = 0;
    float xj[8];
    ld8v(&xl[(size_t)sn*C1 + c8], xj);
    float p = 0.f;
    #pragma unroll
    for (int j=0;j<8;++j) {
      float t = xi[j] + xj[j];
      t = fmaxf(t, 0.2f*t);          // leaky_relu 0.2
      p += t*av[j];
    }
    p += __shfl_xor(p,1); p += __shfl_xor(p,2);
    p += __shfl_xor(p,4); p += __shfl_xor(p,8);
    float mn = fmaxf(m, p);
    float f = __expf(m - mn), w = __expf(p - mn);
    s = s*f + w;
    #pragma unroll
    for (int j=0;j<8;++j) acc[j] = acc[j]*f + w*xj[j];
    m = mn;
    ++e;
  }
  for (; e < e1; e += 2) {
    int s1 = col[e];   if ((u32)s1 >= (u32)NN) s1 = 0;
    int s2 = col[e+1]; if ((u32)s2 >= (u32)NN) s2 = 0;
    float xj1[8], xj2[8];
    ld8v(&xl[(size_t)s1*C1 + c8], xj1);
    ld8v(&xl[(size_t)s2*C1 + c8], xj2);
    float p1 = 0.f, p2 = 0.f;
    #pragma unroll
    for (int j=0;j<8;++j) {
      float t1 = xi[j] + xj1[j]; t1 = fmaxf(t1, 0.2f*t1); p1 += t1*av[j];
      float t2 = xi[j] + xj2[j]; t2 = fmaxf(t2, 0.2f*t2); p2 += t2*av[j];
    }
    p1 += __shfl_xor(p1,1); p2 += __shfl_xor(p2,1);
    p1 += __shfl_xor(p1,2); p2 += __shfl_xor(p2,2);
    p1 += __shfl_xor(p1,4); p2 += __shfl_xor(p2,4);
    p1 += __shfl_xor(p1,8); p2 += __shfl_xor(p2,8);
    float mn = fmaxf(m, fmaxf(p1, p2));
    float f  = __expf(m - mn);
    float w1 = __expf(p1 - mn);
    float w2 = __expf(p2 - mn);
    s = s*f + w1 + w2;
    #pragma unroll
    for (int j=0;j<8;++j) acc[j] = acc[j]*f + (w1*xj1[j] + w2*xj2[j]);
    m = mn;
  }
  float inv = 1.f/s, o[8];
  #pragma unroll
  for (int j=0;j<8;++j) o[j] = gelu_f(acc[j]*inv + bias[c8+j]);
  st8v(&z1[(size_t)wid*C1 + c8], o);
}

// ---------------- edge layer 2 (H=1, C=128), 2-edge unrolled ----------------
template <typename TI, typename TO>
__global__ __launch_bounds__(256) void k_edge2(const TI* __restrict__ xl,
                                               const TI* __restrict__ xr,
                                               const float* __restrict__ att,
                                               const float* __restrict__ bias,
                                               const int* __restrict__ row_ptr,
                                               const int* __restrict__ col,
                                               TO* __restrict__ z2) {
  int wid = (blockIdx.x*blockDim.x + threadIdx.x) >> 6;
  if (wid >= NN) return;
  int lane = threadIdx.x & 63;
  int c2 = lane*2;
  float xiv[2];
  ld2v(&xr[(size_t)wid*C2 + c2], xiv);
  float a0 = att[c2], a1 = att[c2+1];
  float m = -1e30f, s = 0.f, ac0 = 0.f, ac1 = 0.f;
  int e0 = row_ptr[wid], e1 = row_ptr[wid+1];
  int e = e0;
  if ((e1 - e0) & 1) {
    int sn = col[e]; if ((u32)sn >= (u32)NN) sn = 0;
    float xj[2];
    ld2v(&xl[(size_t)sn*C2 + c2], xj);
    float t0 = xiv[0] + xj[0]; t0 = fmaxf(t0, 0.2f*t0);
    float t1 = xiv[1] + xj[1]; t1 = fmaxf(t1, 0.2f*t1);
    float p = t0*a0 + t1*a1;
    p += __shfl_xor(p,1);  p += __shfl_xor(p,2);
    p += __shfl_xor(p,4);  p += __shfl_xor(p,8);
    p += __shfl_xor(p,16); p += __shfl_xor(p,32);
    float mn = fmaxf(m, p);
    float f = __expf(m - mn), w = __expf(p - mn);
    s = s*f + w;
    ac0 = ac0*f + w*xj[0];
    ac1 = ac1*f + w*xj[1];
    m = mn;
    ++e;
  }
  for (; e < e1; e += 2) {
    int s1 = col[e];   if ((u32)s1 >= (u32)NN) s1 = 0;
    int s2 = col[e+1]; if ((u32)s2 >= (u32)NN) s2 = 0;
    float xj1[2], xj2[2];
    ld2v(&xl[(size_t)s1*C2 + c2], xj1);
    ld2v(&xl[(size_t)s2*C2 + c2], xj2);
    float u0 = xiv[0] + xj1[0]; u0 = fmaxf(u0, 0.2f*u0);
    float u1 = xiv[1] + xj1[1]; u1 = fmaxf(u1, 0.2f*u1);
    float v0 = xiv[0] + xj2[0]; v0 = fmaxf(v0, 0.2f*v0);
    float v1 = xiv[1] + xj2[1]; v1 = fmaxf(v1, 0.2f*v1);
    float p1 = u0*a0 + u1*a1;
    float p2 = v0*a0 + v1*a1;
    p1 += __shfl_xor(p1,1);  p2 += __shfl_xor(p2,1);
    p1 += __shfl_xor(p1,2);  p2 += __shfl_xor(p2,2);
    p1 += __shfl_xor(p1,4);  p2 += __shfl_xor(p2,4);
    p1 += __shfl_xor(p1,8);  p2 += __shfl_xor(p2,8);
    p1 += __shfl_xor(p1,16); p2 += __shfl_xor(p2,16);
    p1 += __shfl_xor(p1,32); p2 += __shfl_xor(p2,32);
    float mn = fmaxf(m, fmaxf(p1, p2));
    float f  = __expf(m - mn);
    float w1 = __expf(p1 - mn);
    float w2 = __expf(p2 - mn);
    s = s*f + w1 + w2;
    ac0 = ac0*f + (w1*xj1[0] + w2*xj2[0]);
    ac1 = ac1*f + (w1*xj1[1] + w2*xj2[1]);
    m = mn;
  }
  float inv = 1.f/s;
  z2[(size_t)wid*C2 + c2]   = (TO)(ac0*inv + bias[c2]);
  z2[(size_t)wid*C2 + c2+1] = (TO)(ac1*inv + bias[c2+1]);
}

// ---------------- f32 decoder (compact path fallback) ----------------
__global__ __launch_bounds__(256) void k_dec2(const float* __restrict__ z2,
                                              const int* __restrict__ eli,
                                              const float* __restrict__ Wd1,
                                              const float* __restrict__ bd1,
                                              const float* __restrict__ Wd2,
                                              const float* __restrict__ bd2,
                                              float* __restrict__ out) {
  __shared__ __align__(16) float As[16][64];
  __shared__ __align__(16) float Bs[16][128];
  int tid = threadIdx.x;
  int e0 = blockIdx.x * 64;
  int ty = tid >> 4, tx = tid & 15;
  int lrow = tid >> 2;
  int lk   = (tid & 3) * 4;
  int wk   = tid >> 4;
  int wn   = (tid & 15) * 8;
  int e = e0 + lrow;
  bool ev = e < ELN;
  int ia = ev ? eli[e] : 0;       if ((u32)ia >= (u32)NN) ia = 0;
  int ib = ev ? eli[ELN+e] : 0;   if ((u32)ib >= (u32)NN) ib = 0;
  float acc[4][8] = {};
  for (int k0 = 0; k0 < 256; k0 += 16) {
    int kk4 = k0 + lk;
    const float* src = (kk4 < 128) ? &z2[(size_t)ia*128 + kk4]
                                   : &z2[(size_t)ib*128 + (kk4 - 128)];
    float4 a4 = ev ? *(const float4*)src : make_float4(0.f,0.f,0.f,0.f);
    As[lk+0][lrow]=a4.x; As[lk+1][lrow]=a4.y; As[lk+2][lrow]=a4.z; As[lk+3][lrow]=a4.w;
    *(float4*)&Bs[wk][wn]   = *(const float4*)&Wd1[(size_t)(k0+wk)*128 + wn];
    *(float4*)&Bs[wk][wn+4] = *(const float4*)&Wd1[(size_t)(k0+wk)*128 + wn + 4];
    __syncthreads();
    #pragma unroll
    for (int kk = 0; kk < 16; ++kk) {
      float4 av = *(const float4*)&As[kk][ty*4];
      float a[4] = {av.x, av.y, av.z, av.w};
      float4 b0 = *(const float4*)&Bs[kk][tx*4];
      float4 b1 = *(const float4*)&Bs[kk][64 + tx*4];
      float b[8] = {b0.x,b0.y,b0.z,b0.w,b1.x,b1.y,b1.z,b1.w};
      #pragma unroll
      for (int i = 0; i < 4; ++i)
        #pragma unroll
        for (int j = 0; j < 8; ++j)
          acc[i][j] += a[i]*b[j];
    }
    __syncthreads();
  }
  float w2[8], bb[8];
  #pragma unroll
  for (int j = 0; j < 4; ++j) {
    w2[j]   = Wd2[tx*4+j];      bb[j]   = bd1[tx*4+j];
    w2[j+4] = Wd2[64+tx*4+j];   bb[j+4] = bd1[64+tx*4+j];
  }
  float b2 = bd2[0];
  #pragma unroll
  for (int i = 0; i < 4; ++i) {
    float part = 0.f;
    #pragma unroll
    for (int j = 0; j < 8; ++j)
      part += gelu_f(acc[i][j] + bb[j]) * w2[j];
    part += __shfl_xor(part,1); part += __shfl_xor(part,2);
    part += __shfl_xor(part,4); part += __shfl_xor(part,8);
    int row = e0 + ty*4 + i;
    if (tx == 0 && row < ELN) out[row] = part + b2;
  }
}

__global__ void k_tiny(float* out, float code) {
  if (threadIdx.x == 0) out[0] = code;
}

// ---------------- launch ----------------
extern "C" void kernel_launch(void* const* d_in, const int* in_sizes, int n_in,
                              void* d_out, int out_size, void* d_ws, size_t ws_size,
                              hipStream_t stream) {
  const float* x     = (const float*)d_in[0];
  const int*   ei    = (const int*)  d_in[1];
  const int*   eli   = (const int*)  d_in[2];
  const float* Wl1   = (const float*)d_in[3];
  const float* bl1   = (const float*)d_in[4];
  const float* Wr1   = (const float*)d_in[5];
  const float* br1   = (const float*)d_in[6];
  const float* att1  = (const float*)d_in[7];
  const float* bias1 = (const float*)d_in[8];
  const float* Wl2   = (const float*)d_in[9];
  const float* bl2   = (const float*)d_in[10];
  const float* Wr2   = (const float*)d_in[11];
  const float* br2   = (const float*)d_in[12];
  const float* att2  = (const float*)d_in[13];
  const float* bias2 = (const float*)d_in[14];
  const float* Wd1   = (const float*)d_in[15];
  const float* bd1   = (const float*)d_in[16];
  const float* Wd2   = (const float*)d_in[17];
  const float* bd2   = (const float*)d_in[18];
  float* out = (float*)d_out;

  constexpr size_t INTW = (size_t)(NN+1) + NN + ETOT;          // 380001 words
  constexpr size_t FULL_WORDS = 3ull*NN*C1 + INTW;             // ~124.4 MB (proven available)
  constexpr size_t CMP_WORDS  = 3ull*NN*C1/2 + INTW;           // ~63 MB

  bool full    = ws_size >= FULL_WORDS*4;
  bool compact = !full && ws_size >= CMP_WORDS*4;
  if (!full && !compact) {
    size_t mb = ws_size >> 20;
    k_tiny<<<1, 64, 0, stream>>>(out, 16384.f + (float)mb);
    return;
  }

  size_t regA = full ? (size_t)NN*C1 : (size_t)NN*C1/2;   // words per region
  char* base = (char*)d_ws;
  void* wA = base;
  void* wB = base + regA*4;
  void* wC = base + 2*regA*4;
  int* row_ptr = (int*)(base + 3*regA*4);
  int* cnt     = row_ptr + (NN + 1);
  int* col     = cnt + NN;
  int* bsum    = (int*)wA;   // scan scratch: wA dead during CSR phase

  // CSR over dst
  hipMemsetAsync(cnt, 0, NN*sizeof(int), stream);
  k_hist<<<(ETOT+255)/256, 256, 0, stream>>>(ei, cnt);
  k_scan_a<<<NB, 256, 0, stream>>>(cnt, row_ptr, bsum);
  k_scan_b<<<1, 128, 0, stream>>>(bsum, row_ptr);
  k_scan_c<<<NB, 256, 0, stream>>>(row_ptr, bsum, cnt);
  k_scatter<<<(ETOT+255)/256, 256, 0, stream>>>(ei, cnt, col);

  if (full) {
    _Float16* xl1 = (_Float16*)wA;    // 20.48 MB
    _Float16* xr1 = (_Float16*)wB;    // 20.48 MB
    _Float16* z1  = (_Float16*)wC;    // 20.48 MB
    _Float16* xl2 = (_Float16*)wA;    // 5.12 MB (xl1 dead)
    _Float16* xr2 = (_Float16*)wB;
    _Float16* z2  = (_Float16*)wC;    // 5.12 MB (z1 dead after mgemm2)
    // weight planes in wB slack (xr1 spans 20.48 MB; region is 40.96 MB)
    u16* wl1th = (u16*)((char*)wB + (21u<<20));
    u16* wl1tl = wl1th + 512*256;
    u16* wr1th = wl1tl + 512*256;
    u16* wr1tl = wr1th + 512*256;
    u16* wl2th = wr1tl + 512*256;
    u16* wl2tl = wl2th + 128*512;
    u16* wr2th = wl2tl + 128*512;
    u16* wr2tl = wr2th + 128*512;
    u16* wdth  = wr2tl + 128*512;
    u16* wdtl  = wdth  + 128*256;

    WsArgs wa;
    wa.src[0]=Wl1; wa.th[0]=wl1th; wa.tl[0]=wl1tl; wa.K[0]=INC; wa.N[0]=C1;
    wa.src[1]=Wr1; wa.th[1]=wr1th; wa.tl[1]=wr1tl; wa.K[1]=INC; wa.N[1]=C1;
    wa.src[2]=Wl2; wa.th[2]=wl2th; wa.tl[2]=wl2tl; wa.K[2]=C1;  wa.N[2]=C2;
    wa.src[3]=Wr2; wa.th[3]=wr2th; wa.tl[3]=wr2tl; wa.K[3]=C1;  wa.N[3]=C2;
    wa.src[4]=Wd1; wa.th[4]=wdth;  wa.tl[4]=wdtl;  wa.K[4]=256; wa.N[4]=C2;
    k_wsplit_all<<<dim3(512, 5), 256, 0, stream>>>(wa);

    dim3 gm1((NN+127)/128, C1/128);
    k_mgemm<float,_Float16><<<gm1, 256, 0, stream>>>(x, wl1th, wl1tl, bl1, xl1, NN, C1, INC);
    k_mgemm<float,_Float16><<<gm1, 256, 0, stream>>>(x, wr1th, wr1tl, br1, xr1, NN, C1, INC);
    k_edge1<_Float16,_Float16><<<NN/4, 256, 0, stream>>>(xl1, xr1, att1, bias1, row_ptr, col, z1);
    dim3 gm2((NN+127)/128, C2/128);
    k_mgemm<_Float16,_Float16><<<gm2, 256, 0, stream>>>(z1, wl2th, wl2tl, bl2, xl2, NN, C2, C1);
    k_mgemm<_Float16,_Float16><<<gm2, 256, 0, stream>>>(z1, wr2th, wr2tl, br2, xr2, NN, C2, C1);
    k_edge2<_Float16,_Float16><<<NN/4, 256, 0, stream>>>(xl2, xr2, att2, bias2, row_ptr, col, z2);
    k_dec3<<<(ELN+127)/128, 256, 0, stream>>>(z2, eli, wdth, wdtl, bd1, Wd2, bd2, out);
  } else {
    u16* xl1 = (u16*)wA;
    u16* xr1 = (u16*)wB;
    u16* z1  = (u16*)wC;
    float* xl2 = (float*)wA;
    float* xr2 = (float*)wB;
    float* z2  = (float*)wC;
    dim3 g1((NN+63)/64, C1/64);
    dim3 g2((NN+63)/64, C2/64);
    k_gemm<float,u16><<<g1, 256, 0, stream>>>(x, Wl1, bl1, xl1, NN, C1, INC);
    k_gemm<float,u16><<<g1, 256, 0, stream>>>(x, Wr1, br1, xr1, NN, C1, INC);
    k_edge1<u16,u16><<<NN/4, 256, 0, stream>>>(xl1, xr1, att1, bias1, row_ptr, col, z1);
    k_gemm<u16,float><<<g2, 256, 0, stream>>>(z1, Wl2, bl2, xl2, NN, C2, C1);
    k_gemm<u16,float><<<g2, 256, 0, stream>>>(z1, Wr2, br2, xr2, NN, C2, C1);
    k_edge2<float,float><<<NN/4, 256, 0, stream>>>(xl2, xr2, att2, bias2, row_ptr, col, z2);
    k_dec2<<<(ELN+63)/64, 256, 0, stream>>>(z2, eli, Wd1, bd1, Wd2, bd2, out);
  }
}

// Round 10
// 392.184 us; speedup vs baseline: 2.2777x; 1.0822x over previous
//
#include <hip/hip_runtime.h>
#include <hip/hip_bf16.h>
#include <math.h>
#include <stdint.h>

using bf16 = __hip_bfloat16;
typedef unsigned short u16;
typedef unsigned int   u32;
typedef __attribute__((ext_vector_type(8))) short short8;   // 8 bf16 bit patterns
typedef __attribute__((ext_vector_type(4))) float f32x4;

static constexpr int NN   = 20000;
static constexpr int EE   = 320000;
static constexpr int ELN  = 100000;
static constexpr int ETOT = EE + NN;
static constexpr int INC  = 256;
static constexpr int C1   = 512;
static constexpr int C2   = 128;
static constexpr int NB   = (NN + 255) / 256;   // scan blocks = 79

__device__ __forceinline__ float us2f(u16 u){ union{u32 i; float f;}x; x.i=((u32)u)<<16; return x.f; }
__device__ __forceinline__ u16  f2us(float f){ union{bf16 h; u16 u;}c; c.h=__float2bfloat16(f); return c.u; }
__device__ __forceinline__ float h2f(u16 u){ union{u16 u; _Float16 h;}c; c.u=u; return (float)c.h; }
// tanh-approx gelu via hw exp: tanh(t) = 1 - 2/(e^{2t}+1)
__device__ __forceinline__ float gelu_f(float x){
  float u = 1.5957691216057308f*(x + 0.044715f*x*x*x);
  float ex = __expf(u);
  float th = 1.f - 2.f/(ex + 1.f);
  return 0.5f*x*(1.f+th);
}
__device__ __forceinline__ void ld4v(const float* p, float* o){ float4 v=*(const float4*)p; o[0]=v.x;o[1]=v.y;o[2]=v.z;o[3]=v.w; }
__device__ __forceinline__ void ld4v(const u16* p, float* o){ uint2 v=*(const uint2*)p;
  o[0]=us2f(v.x&0xffff);o[1]=us2f(v.x>>16);o[2]=us2f(v.y&0xffff);o[3]=us2f(v.y>>16); }
__device__ __forceinline__ void ld4v(const _Float16* p, float* o){ uint2 v=*(const uint2*)p;
  o[0]=h2f(v.x&0xffff);o[1]=h2f(v.x>>16);o[2]=h2f(v.y&0xffff);o[3]=h2f(v.y>>16); }
__device__ __forceinline__ void ld8v(const float* p, float* o){ ld4v(p,o); ld4v(p+4,o+4); }
__device__ __forceinline__ void ld8v(const u16* p, float* o){ uint4 v=*(const uint4*)p;
  o[0]=us2f(v.x&0xffff);o[1]=us2f(v.x>>16);o[2]=us2f(v.y&0xffff);o[3]=us2f(v.y>>16);
  o[4]=us2f(v.z&0xffff);o[5]=us2f(v.z>>16);o[6]=us2f(v.w&0xffff);o[7]=us2f(v.w>>16); }
__device__ __forceinline__ void ld8v(const _Float16* p, float* o){ uint4 v=*(const uint4*)p;
  o[0]=h2f(v.x&0xffff);o[1]=h2f(v.x>>16);o[2]=h2f(v.y&0xffff);o[3]=h2f(v.y>>16);
  o[4]=h2f(v.z&0xffff);o[5]=h2f(v.z>>16);o[6]=h2f(v.w&0xffff);o[7]=h2f(v.w>>16); }
__device__ __forceinline__ void ld2v(const float* p, float* o){ float2 v=*(const float2*)p; o[0]=v.x;o[1]=v.y; }
__device__ __forceinline__ void ld2v(const _Float16* p, float* o){ u32 w=*(const u32*)p;
  o[0]=h2f(w&0xffff); o[1]=h2f(w>>16); }
__device__ __forceinline__ void st4v(float* p, const float* v){ *(float4*)p = make_float4(v[0],v[1],v[2],v[3]); }
__device__ __forceinline__ void st4v(u16* p, const float* v){ uint2 o;
  o.x=f2us(v[0])|((u32)f2us(v[1])<<16); o.y=f2us(v[2])|((u32)f2us(v[3])<<16); *(uint2*)p=o; }
__device__ __forceinline__ void st8v(float* p, const float* v){ st4v(p,v); st4v(p+4,v+4); }
__device__ __forceinline__ void st8v(u16* p, const float* v){ uint4 o;
  o.x=f2us(v[0])|((u32)f2us(v[1])<<16); o.y=f2us(v[2])|((u32)f2us(v[3])<<16);
  o.z=f2us(v[4])|((u32)f2us(v[5])<<16); o.w=f2us(v[6])|((u32)f2us(v[7])<<16); *(uint4*)p=o; }
__device__ __forceinline__ void st8v(_Float16* p, const float* v){
  union{ _Float16 h[8]; uint4 u; } c;
  #pragma unroll
  for (int j=0;j<8;++j) c.h[j] = (_Float16)v[j];
  *(uint4*)p = c.u; }

// ---------------- CSR ----------------
__global__ void k_hist(const int* __restrict__ ei, int* __restrict__ cnt) {
  int e = blockIdx.x*blockDim.x + threadIdx.x;
  if (e < ETOT) {
    int d = (e < EE) ? ei[EE + e] : (e - EE);
    if ((u32)d < (u32)NN) atomicAdd(&cnt[d], 1);
  }
}
__global__ void k_scan_a(const int* __restrict__ cnt, int* __restrict__ row_ptr,
                         int* __restrict__ bsum) {
  __shared__ int buf[256];
  int idx = blockIdx.x*256 + threadIdx.x;
  int v = (idx < NN) ? cnt[idx] : 0;
  buf[threadIdx.x] = v;
  __syncthreads();
  for (int off = 1; off < 256; off <<= 1) {
    int t = (threadIdx.x >= off) ? buf[threadIdx.x - off] : 0;
    __syncthreads();
    buf[threadIdx.x] += t;
    __syncthreads();
  }
  if (idx < NN) row_ptr[idx] = buf[threadIdx.x] - v;
  if (threadIdx.x == 255) bsum[blockIdx.x] = buf[255];
}
__global__ void k_scan_b(int* __restrict__ bsum, int* __restrict__ row_ptr) {
  __shared__ int buf[128];
  int v = (threadIdx.x < NB) ? bsum[threadIdx.x] : 0;
  buf[threadIdx.x] = v;
  __syncthreads();
  for (int off = 1; off < 128; off <<= 1) {
    int t = (threadIdx.x >= off) ? buf[threadIdx.x - off] : 0;
    __syncthreads();
    buf[threadIdx.x] += t;
    __syncthreads();
  }
  if (threadIdx.x < NB) bsum[threadIdx.x] = buf[threadIdx.x] - v;
  if (threadIdx.x == 127) row_ptr[NN] = buf[127];
}
__global__ void k_scan_c(int* __restrict__ row_ptr, const int* __restrict__ bsum,
                         int* __restrict__ cur) {
  int idx = blockIdx.x*256 + threadIdx.x;
  if (idx < NN) {
    int v = row_ptr[idx] + bsum[blockIdx.x];
    row_ptr[idx] = v;
    cur[idx] = v;
  }
}
__global__ void k_scatter(const int* __restrict__ ei, int* __restrict__ cur,
                          int* __restrict__ col) {
  int e = blockIdx.x*blockDim.x + threadIdx.x;
  if (e < ETOT) {
    int s, d;
    if (e < EE) { s = ei[e]; d = ei[EE + e]; } else { s = d = e - EE; }
    if ((u32)d >= (u32)NN) d = 0;
    int pos = atomicAdd(&cur[d], 1);
    if ((u32)pos < (u32)ETOT) col[pos] = s;
  }
}

// ---------------- x row-major hi/lo split: x f32 [M][K] -> Ath/Atl bf16 [M][K] ----------------
__global__ __launch_bounds__(256) void k_xsplit(const float* __restrict__ A,
                                                u16* __restrict__ Ath, u16* __restrict__ Atl,
                                                int n) {
  for (int i = blockIdx.x*256 + threadIdx.x; i < n; i += gridDim.x*256) {
    float v = A[i];
    u16 h = f2us(v);
    Ath[i] = h;
    Atl[i] = f2us(v - us2f(h));
  }
}

// ---------------- batched weight transpose + hi/lo split ----------------
struct WsArgs { const float* src[5]; u16* th[5]; u16* tl[5]; int K[5]; int N[5]; };
__global__ __launch_bounds__(256) void k_wsplit_all(WsArgs a) {
  int seg = blockIdx.y;
  int K = a.K[seg], N = a.N[seg];
  int n = K * N;
  int idx = blockIdx.x*256 + threadIdx.x;
  if (idx >= n) return;
  int nn = idx / K, k = idx - nn*K;
  float v = a.src[seg][(size_t)k*N + nn];
  u16 h = f2us(v);
  a.th[seg][idx] = h;
  a.tl[seg][idx] = f2us(v - us2f(h));
}

// ---------------- MFMA GEMM, pre-split A planes: C = A @ B + bias ----------------
// A as row-major bf16 planes Ath/Atl[M][K]; B as transposed planes Bt[N][K].
// bias col<ncut -> biasA[col], else biasB[col-ncut].
template <typename CT>
__global__ __launch_bounds__(256, 2)
void k_mgemm_p(const u16* __restrict__ Ath, const u16* __restrict__ Atl,
               const u16* __restrict__ Bth, const u16* __restrict__ Btl,
               const float* __restrict__ biasA, const float* __restrict__ biasB, int ncut,
               CT* __restrict__ C, int M, int N, int K) {
  __shared__ __align__(16) u16 Ah[128][32], Al[128][32];
  __shared__ __align__(16) u16 Bh[128][32], Bl[128][32];
  int tid = threadIdx.x;
  int m0 = blockIdx.x * 128, n0 = blockIdx.y * 128;
  int wave = tid >> 6, lane = tid & 63;
  int wm = (wave & 1) * 64, wn = (wave >> 1) * 64;
  int l15 = lane & 15, quad = lane >> 4;
  f32x4 acc[4][4] = {};
  int ar = tid >> 1;             // A staging: row 0..127
  int ac = (tid & 1) * 16;       // A staging: k offset 0/16
  int bn = tid >> 2;
  int bc = (tid & 3) * 8;
  uint4 z4 = make_uint4(0,0,0,0);
  for (int k0 = 0; k0 < K; k0 += 32) {
    int gr = m0 + ar;
    if (gr < M) {
      const u16* ph = &Ath[(size_t)gr*K + k0 + ac];
      const u16* pl = &Atl[(size_t)gr*K + k0 + ac];
      *(uint4*)&Ah[ar][ac]   = *(const uint4*)ph;
      *(uint4*)&Ah[ar][ac+8] = *(const uint4*)(ph+8);
      *(uint4*)&Al[ar][ac]   = *(const uint4*)pl;
      *(uint4*)&Al[ar][ac+8] = *(const uint4*)(pl+8);
    } else {
      *(uint4*)&Ah[ar][ac] = z4; *(uint4*)&Ah[ar][ac+8] = z4;
      *(uint4*)&Al[ar][ac] = z4; *(uint4*)&Al[ar][ac+8] = z4;
    }
    #pragma unroll
    for (int i = 0; i < 2; ++i) {
      int n = bn + 64*i;
      *(uint4*)&Bh[n][bc] = *(const uint4*)&Bth[(size_t)(n0+n)*K + k0 + bc];
      *(uint4*)&Bl[n][bc] = *(const uint4*)&Btl[(size_t)(n0+n)*K + k0 + bc];
    }
    __syncthreads();
    short8 af_h[4], af_l[4], bf_h[4], bf_l[4];
    #pragma unroll
    for (int i = 0; i < 4; ++i) {
      af_h[i] = *(const short8*)&Ah[wm + i*16 + l15][quad*8];
      af_l[i] = *(const short8*)&Al[wm + i*16 + l15][quad*8];
      bf_h[i] = *(const short8*)&Bh[wn + i*16 + l15][quad*8];
      bf_l[i] = *(const short8*)&Bl[wn + i*16 + l15][quad*8];
    }
    #pragma unroll
    for (int i = 0; i < 4; ++i)
      #pragma unroll
      for (int j = 0; j < 4; ++j) {
        acc[i][j] = __builtin_amdgcn_mfma_f32_16x16x32_bf16(af_h[i], bf_l[j], acc[i][j], 0,0,0);
        acc[i][j] = __builtin_amdgcn_mfma_f32_16x16x32_bf16(af_l[i], bf_h[j], acc[i][j], 0,0,0);
        acc[i][j] = __builtin_amdgcn_mfma_f32_16x16x32_bf16(af_h[i], bf_h[j], acc[i][j], 0,0,0);
      }
    __syncthreads();
  }
  #pragma unroll
  for (int j = 0; j < 4; ++j) {
    int col = n0 + wn + j*16 + l15;
    float bv = (col < ncut) ? biasA[col] : biasB[col - ncut];
    #pragma unroll
    for (int i = 0; i < 4; ++i) {
      int rbase = m0 + wm + i*16 + quad*4;
      #pragma unroll
      for (int r = 0; r < 4; ++r) {
        int row = rbase + r;
        if (row < M) C[(size_t)row*N + col] = (CT)(acc[i][j][r] + bv);
      }
    }
  }
}

// ---------------- MFMA GEMM, in-kernel split A (fp16): C = A @ B + bias ----------------
template <typename AT, typename CT>
__global__ __launch_bounds__(256, 2)
void k_mgemm(const AT* __restrict__ A,
             const u16* __restrict__ Bth, const u16* __restrict__ Btl,
             const float* __restrict__ biasA, const float* __restrict__ biasB, int ncut,
             CT* __restrict__ C, int M, int N, int K) {
  __shared__ __align__(16) u16 Ah[128][32], Al[128][32];
  __shared__ __align__(16) u16 Bh[128][32], Bl[128][32];
  int tid = threadIdx.x;
  int m0 = blockIdx.x * 128, n0 = blockIdx.y * 128;
  int wave = tid >> 6, lane = tid & 63;
  int wm = (wave & 1) * 64, wn = (wave >> 1) * 64;
  int l15 = lane & 15, quad = lane >> 4;
  f32x4 acc[4][4] = {};
  int ar = tid >> 3;
  int ak = (tid & 7) * 4;
  int bn = tid >> 2;
  int bc = (tid & 3) * 8;
  for (int k0 = 0; k0 < K; k0 += 32) {
    #pragma unroll
    for (int i = 0; i < 4; ++i) {
      int row = ar + 32*i;
      int gr = m0 + row;
      float hv[4] = {0.f, 0.f, 0.f, 0.f};
      if (gr < M) ld4v(&A[(size_t)gr*K + k0 + ak], hv);
      u16 hi[4], lo[4];
      #pragma unroll
      for (int j = 0; j < 4; ++j) {
        hi[j] = f2us(hv[j]);
        lo[j] = f2us(hv[j] - us2f(hi[j]));
      }
      *(uint2*)&Ah[row][ak] = make_uint2(hi[0]|((u32)hi[1]<<16), hi[2]|((u32)hi[3]<<16));
      *(uint2*)&Al[row][ak] = make_uint2(lo[0]|((u32)lo[1]<<16), lo[2]|((u32)lo[3]<<16));
    }
    #pragma unroll
    for (int i = 0; i < 2; ++i) {
      int n = bn + 64*i;
      *(uint4*)&Bh[n][bc] = *(const uint4*)&Bth[(size_t)(n0+n)*K + k0 + bc];
      *(uint4*)&Bl[n][bc] = *(const uint4*)&Btl[(size_t)(n0+n)*K + k0 + bc];
    }
    __syncthreads();
    short8 af_h[4], af_l[4], bf_h[4], bf_l[4];
    #pragma unroll
    for (int i = 0; i < 4; ++i) {
      af_h[i] = *(const short8*)&Ah[wm + i*16 + l15][quad*8];
      af_l[i] = *(const short8*)&Al[wm + i*16 + l15][quad*8];
      bf_h[i] = *(const short8*)&Bh[wn + i*16 + l15][quad*8];
      bf_l[i] = *(const short8*)&Bl[wn + i*16 + l15][quad*8];
    }
    #pragma unroll
    for (int i = 0; i < 4; ++i)
      #pragma unroll
      for (int j = 0; j < 4; ++j) {
        acc[i][j] = __builtin_amdgcn_mfma_f32_16x16x32_bf16(af_h[i], bf_l[j], acc[i][j], 0,0,0);
        acc[i][j] = __builtin_amdgcn_mfma_f32_16x16x32_bf16(af_l[i], bf_h[j], acc[i][j], 0,0,0);
        acc[i][j] = __builtin_amdgcn_mfma_f32_16x16x32_bf16(af_h[i], bf_h[j], acc[i][j], 0,0,0);
      }
    __syncthreads();
  }
  #pragma unroll
  for (int j = 0; j < 4; ++j) {
    int col = n0 + wn + j*16 + l15;
    float bv = (col < ncut) ? biasA[col] : biasB[col - ncut];
    #pragma unroll
    for (int i = 0; i < 4; ++i) {
      int rbase = m0 + wm + i*16 + quad*4;
      #pragma unroll
      for (int r = 0; r < 4; ++r) {
        int row = rbase + r;
        if (row < M) C[(size_t)row*N + col] = (CT)(acc[i][j][r] + bv);
      }
    }
  }
}

// ---------------- MFMA decoder (z2 fp16) ----------------
__global__ __launch_bounds__(256, 2)
void k_dec3(const _Float16* __restrict__ z2,
            const int* __restrict__ eli,
            const u16* __restrict__ Wth, const u16* __restrict__ Wtl,
            const float* __restrict__ bd1,
            const float* __restrict__ Wd2, const float* __restrict__ bd2,
            float* __restrict__ out) {
  __shared__ __align__(16) u16 Ah[128][32], Al[128][32];
  __shared__ __align__(16) u16 Bh[128][32], Bl[128][32];
  __shared__ float pr[128][2];
  int tid = threadIdx.x;
  int e0 = blockIdx.x * 128;
  int wave = tid >> 6, lane = tid & 63;
  int wm = (wave & 1) * 64, wn = (wave >> 1) * 64;
  int l15 = lane & 15, quad = lane >> 4;
  int ar = tid >> 3;
  int ak = (tid & 7) * 4;
  int bn = tid >> 2;
  int bc = (tid & 3) * 8;
  int ia4[4], ib4[4];
  #pragma unroll
  for (int i = 0; i < 4; ++i) {
    int e = e0 + ar + 32*i;
    bool ev = e < ELN;
    int a = ev ? eli[e] : 0;      if ((u32)a >= (u32)NN) a = 0;
    int b = ev ? eli[ELN+e] : 0;  if ((u32)b >= (u32)NN) b = 0;
    ia4[i] = a; ib4[i] = b;
  }
  f32x4 acc[4][4] = {};
  for (int k0 = 0; k0 < 256; k0 += 32) {
    #pragma unroll
    for (int i = 0; i < 4; ++i) {
      int row = ar + 32*i;
      int kk = k0 + ak;
      const _Float16* src = (kk < 128) ? &z2[(size_t)ia4[i]*128 + kk]
                                       : &z2[(size_t)ib4[i]*128 + (kk - 128)];
      float hv[4];
      ld4v(src, hv);
      u16 hi[4], lo[4];
      #pragma unroll
      for (int j = 0; j < 4; ++j) {
        hi[j] = f2us(hv[j]);
        lo[j] = f2us(hv[j] - us2f(hi[j]));
      }
      *(uint2*)&Ah[row][ak] = make_uint2(hi[0]|((u32)hi[1]<<16), hi[2]|((u32)hi[3]<<16));
      *(uint2*)&Al[row][ak] = make_uint2(lo[0]|((u32)lo[1]<<16), lo[2]|((u32)lo[3]<<16));
    }
    #pragma unroll
    for (int i = 0; i < 2; ++i) {
      int n = bn + 64*i;
      *(uint4*)&Bh[n][bc] = *(const uint4*)&Wth[(size_t)n*256 + k0 + bc];
      *(uint4*)&Bl[n][bc] = *(const uint4*)&Wtl[(size_t)n*256 + k0 + bc];
    }
    __syncthreads();
    short8 af_h[4], af_l[4], bf_h[4], bf_l[4];
    #pragma unroll
    for (int i = 0; i < 4; ++i) {
      af_h[i] = *(const short8*)&Ah[wm + i*16 + l15][quad*8];
      af_l[i] = *(const short8*)&Al[wm + i*16 + l15][quad*8];
      bf_h[i] = *(const short8*)&Bh[wn + i*16 + l15][quad*8];
      bf_l[i] = *(const short8*)&Bl[wn + i*16 + l15][quad*8];
    }
    #pragma unroll
    for (int i = 0; i < 4; ++i)
      #pragma unroll
      for (int j = 0; j < 4; ++j) {
        acc[i][j] = __builtin_amdgcn_mfma_f32_16x16x32_bf16(af_h[i], bf_l[j], acc[i][j], 0,0,0);
        acc[i][j] = __builtin_amdgcn_mfma_f32_16x16x32_bf16(af_l[i], bf_h[j], acc[i][j], 0,0,0);
        acc[i][j] = __builtin_amdgcn_mfma_f32_16x16x32_bf16(af_h[i], bf_h[j], acc[i][j], 0,0,0);
      }
    __syncthreads();
  }
  float w2c[4], bbc[4];
  #pragma unroll
  for (int j = 0; j < 4; ++j) {
    int col = wn + j*16 + l15;
    w2c[j] = Wd2[col];
    bbc[j] = bd1[col];
  }
  #pragma unroll
  for (int i = 0; i < 4; ++i) {
    #pragma unroll
    for (int r = 0; r < 4; ++r) {
      float part = 0.f;
      #pragma unroll
      for (int j = 0; j < 4; ++j)
        part += gelu_f(acc[i][j][r] + bbc[j]) * w2c[j];
      part += __shfl_xor(part,1); part += __shfl_xor(part,2);
      part += __shfl_xor(part,4); part += __shfl_xor(part,8);
      if (l15 == 0) pr[wm + i*16 + quad*4 + r][wn>>6] = part;
    }
  }
  __syncthreads();
  if (tid < 128) {
    int e = e0 + tid;
    if (e < ELN) out[e] = pr[tid][0] + pr[tid][1] + bd2[0];
  }
}

// ---------------- fallback f32 GEMM (compact path only) ----------------
template <typename AT, typename CT>
__global__ __launch_bounds__(256) void k_gemm(const AT* __restrict__ A,
                                              const float* __restrict__ W,
                                              const float* __restrict__ bias,
                                              CT* __restrict__ C,
                                              int M, int Nc, int K) {
  __shared__ __align__(16) float As[16][64];
  __shared__ __align__(16) float Bs[16][64];
  int tid = threadIdx.x;
  int m0 = blockIdx.x*64, n0 = blockIdx.y*64;
  int ty = tid >> 4, tx = tid & 15;
  int lrow = tid >> 2;
  int lk   = (tid & 3)*4;
  int wk   = tid >> 4;
  int wn   = (tid & 15)*4;
  float acc[4][4] = {};
  for (int k0 = 0; k0 < K; k0 += 16) {
    int row = m0 + lrow;
    if (row < M) {
      float a4[4]; ld4v(&A[(size_t)row*K + k0 + lk], a4);
      As[lk+0][lrow]=a4[0]; As[lk+1][lrow]=a4[1]; As[lk+2][lrow]=a4[2]; As[lk+3][lrow]=a4[3];
    } else {
      #pragma unroll
      for (int j=0;j<4;++j) As[lk+j][lrow]=0.f;
    }
    {
      float4 bv4 = *(const float4*)&W[(size_t)(k0+wk)*Nc + n0 + wn];
      Bs[wk][wn+0]=bv4.x; Bs[wk][wn+1]=bv4.y; Bs[wk][wn+2]=bv4.z; Bs[wk][wn+3]=bv4.w;
    }
    __syncthreads();
    #pragma unroll
    for (int kk=0;kk<16;++kk) {
      float4 av = *(const float4*)&As[kk][ty*4];
      float4 bv = *(const float4*)&Bs[kk][tx*4];
      float a[4]={av.x,av.y,av.z,av.w}, b[4]={bv.x,bv.y,bv.z,bv.w};
      #pragma unroll
      for (int i=0;i<4;++i)
        #pragma unroll
        for (int j=0;j<4;++j)
          acc[i][j] += a[i]*b[j];
    }
    __syncthreads();
  }
  float bv[4];
  #pragma unroll
  for (int j=0;j<4;++j) bv[j] = bias[n0 + tx*4 + j];
  #pragma unroll
  for (int i=0;i<4;++i) {
    int row = m0 + ty*4 + i;
    if (row < M) {
      float o4[4] = {acc[i][0]+bv[0], acc[i][1]+bv[1], acc[i][2]+bv[2], acc[i][3]+bv[3]};
      st4v(&C[(size_t)row*Nc + n0 + tx*4], o4);
    }
  }
}

// ---------------- edge layer 1 (H=4, C=128), gelu fused, no-max softmax ----------------
// xl/xr base pointers with row stride ld (supports interleaved [xl|xr] buffer).
template <typename TI, typename TO>
__global__ __launch_bounds__(256) void k_edge1(const TI* __restrict__ xl,
                                               const TI* __restrict__ xr, int ld,
                                               const float* __restrict__ att,
                                               const float* __restrict__ bias,
                                               const int* __restrict__ row_ptr,
                                               const int* __restrict__ col,
                                               TO* __restrict__ z1) {
  int wid = (blockIdx.x*blockDim.x + threadIdx.x) >> 6;
  if (wid >= NN) return;
  int lane = threadIdx.x & 63;
  int c8 = lane*8;
  float xi[8], av[8], acc[8] = {};
  ld8v(&xr[(size_t)wid*ld + c8], xi);
  #pragma unroll
  for (int j=0;j<8;++j) av[j] = att[c8+j];
  float s = 0.f;
  int e0 = row_ptr[wid], e1 = row_ptr[wid+1];
  int e = e0;
  if ((e1 - e0) & 1) {
    int sn = col[e]; if ((u32)sn >= (u32)NN) sn = 0;
    float xj[8];
    ld8v(&xl[(size_t)sn*ld + c8], xj);
    float p = 0.f;
    #pragma unroll
    for (int j=0;j<8;++j) {
      float t = xi[j] + xj[j];
      t = fmaxf(t, 0.2f*t);          // leaky_relu 0.2
      p += t*av[j];
    }
    p += __shfl_xor(p,1); p += __shfl_xor(p,2);
    p += __shfl_xor(p,4); p += __shfl_xor(p,8);
    float w = __expf(p);
    s += w;
    #pragma unroll
    for (int j=0;j<8;++j) acc[j] += w*xj[j];
    ++e;
  }
  for (; e < e1; e += 2) {
    int s1 = col[e];   if ((u32)s1 >= (u32)NN) s1 = 0;
    int s2 = col[e+1]; if ((u32)s2 >= (u32)NN) s2 = 0;
    float xj1[8], xj2[8];
    ld8v(&xl[(size_t)s1*ld + c8], xj1);
    ld8v(&xl[(size_t)s2*ld + c8], xj2);
    float p1 = 0.f, p2 = 0.f;
    #pragma unroll
    for (int j=0;j<8;++j) {
      float t1 = xi[j] + xj1[j]; t1 = fmaxf(t1, 0.2f*t1); p1 += t1*av[j];
      float t2 = xi[j] + xj2[j]; t2 = fmaxf(t2, 0.2f*t2); p2 += t2*av[j];
    }
    p1 += __shfl_xor(p1,1); p2 += __shfl_xor(p2,1);
    p1 += __shfl_xor(p1,2); p2 += __shfl_xor(p2,2);
    p1 += __shfl_xor(p1,4); p2 += __shfl_xor(p2,4);
    p1 += __shfl_xor(p1,8); p2 += __shfl_xor(p2,8);
    float w1 = __expf(p1);
    float w2 = __expf(p2);
    s += w1 + w2;
    #pragma unroll
    for (int j=0;j<8;++j) acc[j] += w1*xj1[j] + w2*xj2[j];
  }
  float inv = 1.f/s, o[8];
  #pragma unroll
  for (int j=0;j<8;++j) o[j] = gelu_f(acc[j]*inv + bias[c8+j]);
  st8v(&z1[(size_t)wid*C1 + c8], o);
}

// ---------------- edge layer 2 (H=1, C=128), no-max softmax ----------------
template <typename TI, typename TO>
__global__ __launch_bounds__(256) void k_edge2(const TI* __restrict__ xl,
                                               const TI* __restrict__ xr, int ld,
                                               const float* __restrict__ att,
                                               const float* __restrict__ bias,
                                               const int* __restrict__ row_ptr,
                                               const int* __restrict__ col,
                                               TO* __restrict__ z2) {
  int wid = (blockIdx.x*blockDim.x + threadIdx.x) >> 6;
  if (wid >= NN) return;
  int lane = threadIdx.x & 63;
  int c2 = lane*2;
  float xiv[2];
  ld2v(&xr[(size_t)wid*ld + c2], xiv);
  float a0 = att[c2], a1 = att[c2+1];
  float s = 0.f, ac0 = 0.f, ac1 = 0.f;
  int e0 = row_ptr[wid], e1 = row_ptr[wid+1];
  int e = e0;
  if ((e1 - e0) & 1) {
    int sn = col[e]; if ((u32)sn >= (u32)NN) sn = 0;
    float xj[2];
    ld2v(&xl[(size_t)sn*ld + c2], xj);
    float t0 = xiv[0] + xj[0]; t0 = fmaxf(t0, 0.2f*t0);
    float t1 = xiv[1] + xj[1]; t1 = fmaxf(t1, 0.2f*t1);
    float p = t0*a0 + t1*a1;
    p += __shfl_xor(p,1);  p += __shfl_xor(p,2);
    p += __shfl_xor(p,4);  p += __shfl_xor(p,8);
    p += __shfl_xor(p,16); p += __shfl_xor(p,32);
    float w = __expf(p);
    s += w;
    ac0 += w*xj[0];
    ac1 += w*xj[1];
    ++e;
  }
  for (; e < e1; e += 2) {
    int s1 = col[e];   if ((u32)s1 >= (u32)NN) s1 = 0;
    int s2 = col[e+1]; if ((u32)s2 >= (u32)NN) s2 = 0;
    float xj1[2], xj2[2];
    ld2v(&xl[(size_t)s1*ld + c2], xj1);
    ld2v(&xl[(size_t)s2*ld + c2], xj2);
    float u0 = xiv[0] + xj1[0]; u0 = fmaxf(u0, 0.2f*u0);
    float u1 = xiv[1] + xj1[1]; u1 = fmaxf(u1, 0.2f*u1);
    float v0 = xiv[0] + xj2[0]; v0 = fmaxf(v0, 0.2f*v0);
    float v1 = xiv[1] + xj2[1]; v1 = fmaxf(v1, 0.2f*v1);
    float p1 = u0*a0 + u1*a1;
    float p2 = v0*a0 + v1*a1;
    p1 += __shfl_xor(p1,1);  p2 += __shfl_xor(p2,1);
    p1 += __shfl_xor(p1,2);  p2 += __shfl_xor(p2,2);
    p1 += __shfl_xor(p1,4);  p2 += __shfl_xor(p2,4);
    p1 += __shfl_xor(p1,8);  p2 += __shfl_xor(p2,8);
    p1 += __shfl_xor(p1,16); p2 += __shfl_xor(p2,16);
    p1 += __shfl_xor(p1,32); p2 += __shfl_xor(p2,32);
    float w1 = __expf(p1);
    float w2 = __expf(p2);
    s += w1 + w2;
    ac0 += w1*xj1[0] + w2*xj2[0];
    ac1 += w1*xj1[1] + w2*xj2[1];
  }
  float inv = 1.f/s;
  z2[(size_t)wid*C2 + c2]   = (TO)(ac0*inv + bias[c2]);
  z2[(size_t)wid*C2 + c2+1] = (TO)(ac1*inv + bias[c2+1]);
}

// ---------------- f32 decoder (compact path fallback) ----------------
__global__ __launch_bounds__(256) void k_dec2(const float* __restrict__ z2,
                                              const int* __restrict__ eli,
                                              const float* __restrict__ Wd1,
                                              const float* __restrict__ bd1,
                                              const float* __restrict__ Wd2,
                                              const float* __restrict__ bd2,
                                              float* __restrict__ out) {
  __shared__ __align__(16) float As[16][64];
  __shared__ __align__(16) float Bs[16][128];
  int tid = threadIdx.x;
  int e0 = blockIdx.x * 64;
  int ty = tid >> 4, tx = tid & 15;
  int lrow = tid >> 2;
  int lk   = (tid & 3) * 4;
  int wk   = tid >> 4;
  int wn   = (tid & 15) * 8;
  int e = e0 + lrow;
  bool ev = e < ELN;
  int ia = ev ? eli[e] : 0;       if ((u32)ia >= (u32)NN) ia = 0;
  int ib = ev ? eli[ELN+e] : 0;   if ((u32)ib >= (u32)NN) ib = 0;
  float acc[4][8] = {};
  for (int k0 = 0; k0 < 256; k0 += 16) {
    int kk4 = k0 + lk;
    const float* src = (kk4 < 128) ? &z2[(size_t)ia*128 + kk4]
                                   : &z2[(size_t)ib*128 + (kk4 - 128)];
    float4 a4 = ev ? *(const float4*)src : make_float4(0.f,0.f,0.f,0.f);
    As[lk+0][lrow]=a4.x; As[lk+1][lrow]=a4.y; As[lk+2][lrow]=a4.z; As[lk+3][lrow]=a4.w;
    *(float4*)&Bs[wk][wn]   = *(const float4*)&Wd1[(size_t)(k0+wk)*128 + wn];
    *(float4*)&Bs[wk][wn+4] = *(const float4*)&Wd1[(size_t)(k0+wk)*128 + wn + 4];
    __syncthreads();
    #pragma unroll
    for (int kk = 0; kk < 16; ++kk) {
      float4 av = *(const float4*)&As[kk][ty*4];
      float a[4] = {av.x, av.y, av.z, av.w};
      float4 b0 = *(const float4*)&Bs[kk][tx*4];
      float4 b1 = *(const float4*)&Bs[kk][64 + tx*4];
      float b[8] = {b0.x,b0.y,b0.z,b0.w,b1.x,b1.y,b1.z,b1.w};
      #pragma unroll
      for (int i = 0; i < 4; ++i)
        #pragma unroll
        for (int j = 0; j < 8; ++j)
          acc[i][j] += a[i]*b[j];
    }
    __syncthreads();
  }
  float w2[8], bb[8];
  #pragma unroll
  for (int j = 0; j < 4; ++j) {
    w2[j]   = Wd2[tx*4+j];      bb[j]   = bd1[tx*4+j];
    w2[j+4] = Wd2[64+tx*4+j];   bb[j+4] = bd1[64+tx*4+j];
  }
  float b2 = bd2[0];
  #pragma unroll
  for (int i = 0; i < 4; ++i) {
    float part = 0.f;
    #pragma unroll
    for (int j = 0; j < 8; ++j)
      part += gelu_f(acc[i][j] + bb[j]) * w2[j];
    part += __shfl_xor(part,1); part += __shfl_xor(part,2);
    part += __shfl_xor(part,4); part += __shfl_xor(part,8);
    int row = e0 + ty*4 + i;
    if (tx == 0 && row < ELN) out[row] = part + b2;
  }
}

__global__ void k_tiny(float* out, float code) {
  if (threadIdx.x == 0) out[0] = code;
}

// ---------------- launch ----------------
extern "C" void kernel_launch(void* const* d_in, const int* in_sizes, int n_in,
                              void* d_out, int out_size, void* d_ws, size_t ws_size,
                              hipStream_t stream) {
  const float* x     = (const float*)d_in[0];
  const int*   ei    = (const int*)  d_in[1];
  const int*   eli   = (const int*)  d_in[2];
  const float* Wl1   = (const float*)d_in[3];
  const float* bl1   = (const float*)d_in[4];
  const float* Wr1   = (const float*)d_in[5];
  const float* br1   = (const float*)d_in[6];
  const float* att1  = (const float*)d_in[7];
  const float* bias1 = (const float*)d_in[8];
  const float* Wl2   = (const float*)d_in[9];
  const float* bl2   = (const float*)d_in[10];
  const float* Wr2   = (const float*)d_in[11];
  const float* br2   = (const float*)d_in[12];
  const float* att2  = (const float*)d_in[13];
  const float* bias2 = (const float*)d_in[14];
  const float* Wd1   = (const float*)d_in[15];
  const float* bd1   = (const float*)d_in[16];
  const float* Wd2   = (const float*)d_in[17];
  const float* bd2   = (const float*)d_in[18];
  float* out = (float*)d_out;

  constexpr size_t INTW = (size_t)(NN+1) + NN + ETOT;          // 380001 words
  constexpr size_t FULL_WORDS = 3ull*NN*C1 + INTW;             // ~124.4 MB (proven available)
  constexpr size_t CMP_WORDS  = 3ull*NN*C1/2 + INTW;           // ~63 MB

  bool full    = ws_size >= FULL_WORDS*4;
  bool compact = !full && ws_size >= CMP_WORDS*4;
  if (!full && !compact) {
    size_t mb = ws_size >> 20;
    k_tiny<<<1, 64, 0, stream>>>(out, 16384.f + (float)mb);
    return;
  }

  size_t regA = full ? (size_t)NN*C1 : (size_t)NN*C1/2;   // words per region
  char* base = (char*)d_ws;
  void* wA = base;
  void* wB = base + regA*4;
  void* wC = base + 2*regA*4;
  int* row_ptr = (int*)(base + 3*regA*4);
  int* cnt     = row_ptr + (NN + 1);
  int* col     = cnt + NN;
  int* bsum    = (int*)wA;   // scan scratch: wA dead during CSR phase

  // CSR over dst
  hipMemsetAsync(cnt, 0, NN*sizeof(int), stream);
  k_hist<<<(ETOT+255)/256, 256, 0, stream>>>(ei, cnt);
  k_scan_a<<<NB, 256, 0, stream>>>(cnt, row_ptr, bsum);
  k_scan_b<<<1, 128, 0, stream>>>(bsum, row_ptr);
  k_scan_c<<<NB, 256, 0, stream>>>(row_ptr, bsum, cnt);
  k_scatter<<<(ETOT+255)/256, 256, 0, stream>>>(ei, cnt, col);

  if (full) {
    // buffers
    _Float16* xlr1 = (_Float16*)wA;   // [20000][1024] fp16 = 41 MB (xl|xr interleaved)
    _Float16* z1   = (_Float16*)wC;   // [20000][512] fp16 = 20.5 MB
    _Float16* xlr2 = (_Float16*)wA;   // [20000][256] fp16 (xlr1 dead after edge1)
    _Float16* z2   = (_Float16*)wC;   // [20000][128] fp16 (z1 dead after mgemm2)
    // x hi/lo planes at wB start (20.5 MB), weight planes at wB+21MB
    u16* xth = (u16*)wB;
    u16* xtl = xth + (size_t)NN*INC;
    u16* wt1th = (u16*)((char*)wB + (21u<<20));   // combined [1024][256]
    u16* wt1tl = wt1th + 1024*256;
    u16* wt2th = wt1tl + 1024*256;                // combined [256][512]
    u16* wt2tl = wt2th + 256*512;
    u16* wdth  = wt2tl + 256*512;                 // [128][256]
    u16* wdtl  = wdth  + 128*256;

    k_xsplit<<<2048, 256, 0, stream>>>(x, xth, xtl, NN*INC);
    WsArgs wa;
    wa.src[0]=Wl1; wa.th[0]=wt1th;          wa.tl[0]=wt1tl;          wa.K[0]=INC; wa.N[0]=C1;
    wa.src[1]=Wr1; wa.th[1]=wt1th+512*256;  wa.tl[1]=wt1tl+512*256;  wa.K[1]=INC; wa.N[1]=C1;
    wa.src[2]=Wl2; wa.th[2]=wt2th;          wa.tl[2]=wt2tl;          wa.K[2]=C1;  wa.N[2]=C2;
    wa.src[3]=Wr2; wa.th[3]=wt2th+128*512;  wa.tl[3]=wt2tl+128*512;  wa.K[3]=C1;  wa.N[3]=C2;
    wa.src[4]=Wd1; wa.th[4]=wdth;           wa.tl[4]=wdtl;           wa.K[4]=256; wa.N[4]=C2;
    k_wsplit_all<<<dim3(512, 5), 256, 0, stream>>>(wa);

    // layer 1: one merged GEMM, N=1024 ([xl|xr])
    dim3 gm1((NN+127)/128, 1024/128);
    k_mgemm_p<_Float16><<<gm1, 256, 0, stream>>>(xth, xtl, wt1th, wt1tl,
                                                 bl1, br1, 512, xlr1, NN, 1024, INC);
    k_edge1<_Float16,_Float16><<<NN/4, 256, 0, stream>>>(xlr1, xlr1+512, 1024,
                                                         att1, bias1, row_ptr, col, z1);
    // layer 2: one merged GEMM, N=256 ([xl|xr])
    dim3 gm2((NN+127)/128, 256/128);
    k_mgemm<_Float16,_Float16><<<gm2, 256, 0, stream>>>(z1, wt2th, wt2tl,
                                                        bl2, br2, 128, xlr2, NN, 256, C1);
    k_edge2<_Float16,_Float16><<<NN/4, 256, 0, stream>>>(xlr2, xlr2+128, 256,
                                                         att2, bias2, row_ptr, col, z2);
    k_dec3<<<(ELN+127)/128, 256, 0, stream>>>(z2, eli, wdth, wdtl, bd1, Wd2, bd2, out);
  } else {
    u16* xl1 = (u16*)wA;
    u16* xr1 = (u16*)wB;
    u16* z1  = (u16*)wC;
    float* xl2 = (float*)wA;
    float* xr2 = (float*)wB;
    float* z2  = (float*)wC;
    dim3 g1((NN+63)/64, C1/64);
    dim3 g2((NN+63)/64, C2/64);
    k_gemm<float,u16><<<g1, 256, 0, stream>>>(x, Wl1, bl1, xl1, NN, C1, INC);
    k_gemm<float,u16><<<g1, 256, 0, stream>>>(x, Wr1, br1, xr1, NN, C1, INC);
    k_edge1<u16,u16><<<NN/4, 256, 0, stream>>>(xl1, xr1, C1, att1, bias1, row_ptr, col, z1);
    k_gemm<u16,float><<<g2, 256, 0, stream>>>(z1, Wl2, bl2, xl2, NN, C2, C1);
    k_gemm<u16,float><<<g2, 256, 0, stream>>>(z1, Wr2, br2, xr2, NN, C2, C1);
    k_edge2<float,float><<<NN/4, 256, 0, stream>>>(xl2, xr2, C2, att2, bias2, row_ptr, col, z2);
    k_dec2<<<(ELN+63)/64, 256, 0, stream>>>(z2, eli, Wd1, bd1, Wd2, bd2, out);
  }
}

// Round 11
// 389.048 us; speedup vs baseline: 2.2961x; 1.0081x over previous
//
#include <hip/hip_runtime.h>
#include <hip/hip_bf16.h>
#include <math.h>
#include <stdint.h>

using bf16 = __hip_bfloat16;
typedef unsigned short u16;
typedef unsigned int   u32;
typedef __attribute__((ext_vector_type(8))) short short8;   // 8 bf16 bit patterns
typedef __attribute__((ext_vector_type(4))) float f32x4;

static constexpr int NN   = 20000;
static constexpr int EE   = 320000;
static constexpr int ELN  = 100000;
static constexpr int ETOT = EE + NN;
static constexpr int INC  = 256;
static constexpr int C1   = 512;
static constexpr int C2   = 128;
static constexpr int NB   = (NN + 255) / 256;   // scan blocks = 79

__device__ __forceinline__ float us2f(u16 u){ union{u32 i; float f;}x; x.i=((u32)u)<<16; return x.f; }
__device__ __forceinline__ u16  f2us(float f){ union{bf16 h; u16 u;}c; c.h=__float2bfloat16(f); return c.u; }
__device__ __forceinline__ float h2f(u16 u){ union{u16 u; _Float16 h;}c; c.u=u; return (float)c.h; }
__device__ __forceinline__ float gelu_f(float x){
  float u = 1.5957691216057308f*(x + 0.044715f*x*x*x);
  float ex = __expf(u);
  float th = 1.f - 2.f/(ex + 1.f);
  return 0.5f*x*(1.f+th);
}
// async global->LDS, 16B per lane; lds dest = wave-uniform base + lane*16
__device__ __forceinline__ void gl_lds16(const u16* g, void* l) {
  __builtin_amdgcn_global_load_lds((const __attribute__((address_space(1))) void*)g,
                                   (__attribute__((address_space(3))) void*)l, 16, 0, 0);
}
__device__ __forceinline__ void ld4v(const float* p, float* o){ float4 v=*(const float4*)p; o[0]=v.x;o[1]=v.y;o[2]=v.z;o[3]=v.w; }
__device__ __forceinline__ void ld4v(const u16* p, float* o){ uint2 v=*(const uint2*)p;
  o[0]=us2f(v.x&0xffff);o[1]=us2f(v.x>>16);o[2]=us2f(v.y&0xffff);o[3]=us2f(v.y>>16); }
__device__ __forceinline__ void ld8v(const float* p, float* o){ ld4v(p,o); ld4v(p+4,o+4); }
__device__ __forceinline__ void ld8v(const u16* p, float* o){ uint4 v=*(const uint4*)p;
  o[0]=us2f(v.x&0xffff);o[1]=us2f(v.x>>16);o[2]=us2f(v.y&0xffff);o[3]=us2f(v.y>>16);
  o[4]=us2f(v.z&0xffff);o[5]=us2f(v.z>>16);o[6]=us2f(v.w&0xffff);o[7]=us2f(v.w>>16); }
__device__ __forceinline__ void ld8v(const _Float16* p, float* o){ uint4 v=*(const uint4*)p;
  o[0]=h2f(v.x&0xffff);o[1]=h2f(v.x>>16);o[2]=h2f(v.y&0xffff);o[3]=h2f(v.y>>16);
  o[4]=h2f(v.z&0xffff);o[5]=h2f(v.z>>16);o[6]=h2f(v.w&0xffff);o[7]=h2f(v.w>>16); }
__device__ __forceinline__ void ld2v(const float* p, float* o){ float2 v=*(const float2*)p; o[0]=v.x;o[1]=v.y; }
__device__ __forceinline__ void ld2v(const _Float16* p, float* o){ u32 w=*(const u32*)p;
  o[0]=h2f(w&0xffff); o[1]=h2f(w>>16); }
__device__ __forceinline__ void st4v(float* p, const float* v){ *(float4*)p = make_float4(v[0],v[1],v[2],v[3]); }
__device__ __forceinline__ void st4v(u16* p, const float* v){ uint2 o;
  o.x=f2us(v[0])|((u32)f2us(v[1])<<16); o.y=f2us(v[2])|((u32)f2us(v[3])<<16); *(uint2*)p=o; }
__device__ __forceinline__ void st8v(float* p, const float* v){ st4v(p,v); st4v(p+4,v+4); }
__device__ __forceinline__ void st8v(u16* p, const float* v){ uint4 o;
  o.x=f2us(v[0])|((u32)f2us(v[1])<<16); o.y=f2us(v[2])|((u32)f2us(v[3])<<16);
  o.z=f2us(v[4])|((u32)f2us(v[5])<<16); o.w=f2us(v[6])|((u32)f2us(v[7])<<16); *(uint4*)p=o; }

// ---------------- CSR ----------------
__global__ void k_hist(const int* __restrict__ ei, int* __restrict__ cnt) {
  int e = blockIdx.x*blockDim.x + threadIdx.x;
  if (e < ETOT) {
    int d = (e < EE) ? ei[EE + e] : (e - EE);
    if ((u32)d < (u32)NN) atomicAdd(&cnt[d], 1);
  }
}
__global__ void k_scan_a(const int* __restrict__ cnt, int* __restrict__ row_ptr,
                         int* __restrict__ bsum) {
  __shared__ int buf[256];
  int idx = blockIdx.x*256 + threadIdx.x;
  int v = (idx < NN) ? cnt[idx] : 0;
  buf[threadIdx.x] = v;
  __syncthreads();
  for (int off = 1; off < 256; off <<= 1) {
    int t = (threadIdx.x >= off) ? buf[threadIdx.x - off] : 0;
    __syncthreads();
    buf[threadIdx.x] += t;
    __syncthreads();
  }
  if (idx < NN) row_ptr[idx] = buf[threadIdx.x] - v;
  if (threadIdx.x == 255) bsum[blockIdx.x] = buf[255];
}
__global__ void k_scan_b(int* __restrict__ bsum, int* __restrict__ row_ptr) {
  __shared__ int buf[128];
  int v = (threadIdx.x < NB) ? bsum[threadIdx.x] : 0;
  buf[threadIdx.x] = v;
  __syncthreads();
  for (int off = 1; off < 128; off <<= 1) {
    int t = (threadIdx.x >= off) ? buf[threadIdx.x - off] : 0;
    __syncthreads();
    buf[threadIdx.x] += t;
    __syncthreads();
  }
  if (threadIdx.x < NB) bsum[threadIdx.x] = buf[threadIdx.x] - v;
  if (threadIdx.x == 127) row_ptr[NN] = buf[127];
}
__global__ void k_scan_c(int* __restrict__ row_ptr, const int* __restrict__ bsum,
                         int* __restrict__ cur) {
  int idx = blockIdx.x*256 + threadIdx.x;
  if (idx < NN) {
    int v = row_ptr[idx] + bsum[blockIdx.x];
    row_ptr[idx] = v;
    cur[idx] = v;
  }
}
__global__ void k_scatter(const int* __restrict__ ei, int* __restrict__ cur,
                          int* __restrict__ col) {
  int e = blockIdx.x*blockDim.x + threadIdx.x;
  if (e < ETOT) {
    int s, d;
    if (e < EE) { s = ei[e]; d = ei[EE + e]; } else { s = d = e - EE; }
    if ((u32)d >= (u32)NN) d = 0;
    int pos = atomicAdd(&cur[d], 1);
    if ((u32)pos < (u32)ETOT) col[pos] = s;
  }
}

// ---------------- x row-major hi/lo split ----------------
__global__ __launch_bounds__(256) void k_xsplit(const float* __restrict__ A,
                                                u16* __restrict__ Ath, u16* __restrict__ Atl,
                                                int n) {
  for (int i = blockIdx.x*256 + threadIdx.x; i < n; i += gridDim.x*256) {
    float v = A[i];
    u16 h = f2us(v);
    Ath[i] = h;
    Atl[i] = f2us(v - us2f(h));
  }
}

// ---------------- batched weight transpose + hi/lo split ----------------
struct WsArgs { const float* src[5]; u16* th[5]; u16* tl[5]; int K[5]; int N[5]; };
__global__ __launch_bounds__(256) void k_wsplit_all(WsArgs a) {
  int seg = blockIdx.y;
  int K = a.K[seg], N = a.N[seg];
  int n = K * N;
  int idx = blockIdx.x*256 + threadIdx.x;
  if (idx >= n) return;
  int nn = idx / K, k = idx - nn*K;
  float v = a.src[seg][(size_t)k*N + nn];
  u16 h = f2us(v);
  a.th[seg][idx] = h;
  a.tl[seg][idx] = f2us(v - us2f(h));
}

// ---------------- MFMA GEMM, async staging: C(fp16) = A @ B + bias ----------------
// A/B as bf16 hi/lo planes (A row-major [M][K], B transposed [N][K]).
// wave w stages plane w via global_load_lds (m97 structure). grid 1-D, y-fastest swizzle.
__global__ __launch_bounds__(256, 2)
void k_mgemm_a(const u16* __restrict__ Ath, const u16* __restrict__ Atl,
               const u16* __restrict__ Bth, const u16* __restrict__ Btl,
               const float* __restrict__ biasA, const float* __restrict__ biasB, int ncut,
               _Float16* __restrict__ C, int M, int N, int K, int nby) {
  __shared__ __align__(16) u16 sm[17408];   // staging 16384 u16 (4 planes x 4096); epilogue tile 128x136
  int tid = threadIdx.x;
  int bidy = blockIdx.x % nby, bidx = blockIdx.x / nby;
  int m0 = bidx * 128, n0 = bidy * 128;
  int wave = tid >> 6, lane = tid & 63;
  int wm = (wave & 1) * 64, wn = (wave >> 1) * 64;
  int l15 = lane & 15, quad = lane >> 4;
  const u16* pbase = (wave == 0) ? Ath : (wave == 1) ? Atl : (wave == 2) ? Bth : Btl;
  bool isA = wave < 2;
  int rbase = isA ? m0 : n0;
  int rseg = lane >> 2;           // row-within-16
  int kseg = (lane & 3) * 8;      // u16 offset (16B chunk)
  f32x4 acc[4][4] = {};
  for (int k0 = 0; k0 < K; k0 += 32) {
    #pragma unroll
    for (int i = 0; i < 8; ++i) {
      int r = rbase + i*16 + rseg;
      if (isA && r > M-1) r = M-1;     // clamp; rows >= M never written
      gl_lds16(&pbase[(size_t)r*K + k0 + kseg], (char*)sm + (wave<<13) + (i<<10));
    }
    __syncthreads();
    short8 af_h[4], af_l[4], bf_h[4], bf_l[4];
    #pragma unroll
    for (int i = 0; i < 4; ++i) {
      af_h[i] = *(const short8*)&sm[         (wm + i*16 + l15)*32 + quad*8];
      af_l[i] = *(const short8*)&sm[ 4096 +  (wm + i*16 + l15)*32 + quad*8];
      bf_h[i] = *(const short8*)&sm[ 8192 +  (wn + i*16 + l15)*32 + quad*8];
      bf_l[i] = *(const short8*)&sm[12288 +  (wn + i*16 + l15)*32 + quad*8];
    }
    #pragma unroll
    for (int i = 0; i < 4; ++i)
      #pragma unroll
      for (int j = 0; j < 4; ++j) {
        acc[i][j] = __builtin_amdgcn_mfma_f32_16x16x32_bf16(af_h[i], bf_l[j], acc[i][j], 0,0,0);
        acc[i][j] = __builtin_amdgcn_mfma_f32_16x16x32_bf16(af_l[i], bf_h[j], acc[i][j], 0,0,0);
        acc[i][j] = __builtin_amdgcn_mfma_f32_16x16x32_bf16(af_h[i], bf_h[j], acc[i][j], 0,0,0);
      }
    __syncthreads();
  }
  // epilogue: fp16 tile in LDS (stride 136: quad rows land on disjoint bank groups), coalesced out
  #pragma unroll
  for (int j = 0; j < 4; ++j) {
    int col = wn + j*16 + l15;
    int colg = n0 + col;
    float bv = (colg < ncut) ? biasA[colg] : biasB[colg - ncut];
    #pragma unroll
    for (int i = 0; i < 4; ++i) {
      int rowb = wm + i*16 + quad*4;
      #pragma unroll
      for (int r = 0; r < 4; ++r) {
        union { _Float16 h; u16 u; } cv;
        cv.h = (_Float16)(acc[i][j][r] + bv);
        sm[(rowb + r)*136 + col] = cv.u;
      }
    }
  }
  __syncthreads();
  int row = tid >> 1, half = (tid & 1) * 64;
  int gr = m0 + row;
  if (gr < M) {
    uint4* d = (uint4*)&C[(size_t)gr*N + n0 + half];
    const uint4* s = (const uint4*)&sm[row*136 + half];
    #pragma unroll
    for (int q = 0; q < 8; ++q) d[q] = s[q];
  }
}

// ---------------- MFMA decoder, async staging (z2 bf16 hi/lo planes) ----------------
__global__ __launch_bounds__(256, 2)
void k_dec4(const u16* __restrict__ z2h, const u16* __restrict__ z2l,
            const int* __restrict__ eli,
            const u16* __restrict__ Wth, const u16* __restrict__ Wtl,
            const float* __restrict__ bd1,
            const float* __restrict__ Wd2, const float* __restrict__ bd2,
            float* __restrict__ out) {
  __shared__ __align__(16) u16 sm[16384];
  __shared__ float pr[128][2];
  __shared__ int ias[128], ibs[128];
  int tid = threadIdx.x;
  int e0 = blockIdx.x * 128;
  if (tid < 128) {
    int e = e0 + tid;
    bool ev = e < ELN;
    int a = ev ? eli[e] : 0;      if ((u32)a >= (u32)NN) a = 0;
    int b = ev ? eli[ELN+e] : 0;  if ((u32)b >= (u32)NN) b = 0;
    ias[tid] = a; ibs[tid] = b;
  }
  __syncthreads();
  int wave = tid >> 6, lane = tid & 63;
  int wm = (wave & 1) * 64, wn = (wave >> 1) * 64;
  int l15 = lane & 15, quad = lane >> 4;
  const u16* pbase = (wave == 0) ? z2h : (wave == 1) ? z2l : (wave == 2) ? Wth : Wtl;
  bool isA = wave < 2;
  int rseg = lane >> 2;
  int kseg = (lane & 3) * 8;
  f32x4 acc[4][4] = {};
  for (int k0 = 0; k0 < 256; k0 += 32) {
    #pragma unroll
    for (int i = 0; i < 8; ++i) {
      int r = i*16 + rseg;
      const u16* g;
      if (isA) {
        int node = (k0 < 128) ? ias[r] : ibs[r];
        int kk   = (k0 < 128) ? k0 : (k0 - 128);
        g = &pbase[(size_t)node*128 + kk + kseg];
      } else {
        g = &pbase[(size_t)r*256 + k0 + kseg];
      }
      gl_lds16(g, (char*)sm + (wave<<13) + (i<<10));
    }
    __syncthreads();
    short8 af_h[4], af_l[4], bf_h[4], bf_l[4];
    #pragma unroll
    for (int i = 0; i < 4; ++i) {
      af_h[i] = *(const short8*)&sm[         (wm + i*16 + l15)*32 + quad*8];
      af_l[i] = *(const short8*)&sm[ 4096 +  (wm + i*16 + l15)*32 + quad*8];
      bf_h[i] = *(const short8*)&sm[ 8192 +  (wn + i*16 + l15)*32 + quad*8];
      bf_l[i] = *(const short8*)&sm[12288 +  (wn + i*16 + l15)*32 + quad*8];
    }
    #pragma unroll
    for (int i = 0; i < 4; ++i)
      #pragma unroll
      for (int j = 0; j < 4; ++j) {
        acc[i][j] = __builtin_amdgcn_mfma_f32_16x16x32_bf16(af_h[i], bf_l[j], acc[i][j], 0,0,0);
        acc[i][j] = __builtin_amdgcn_mfma_f32_16x16x32_bf16(af_l[i], bf_h[j], acc[i][j], 0,0,0);
        acc[i][j] = __builtin_amdgcn_mfma_f32_16x16x32_bf16(af_h[i], bf_h[j], acc[i][j], 0,0,0);
      }
    __syncthreads();
  }
  float w2c[4], bbc[4];
  #pragma unroll
  for (int j = 0; j < 4; ++j) {
    int col = wn + j*16 + l15;
    w2c[j] = Wd2[col];
    bbc[j] = bd1[col];
  }
  #pragma unroll
  for (int i = 0; i < 4; ++i) {
    #pragma unroll
    for (int r = 0; r < 4; ++r) {
      float part = 0.f;
      #pragma unroll
      for (int j = 0; j < 4; ++j)
        part += gelu_f(acc[i][j][r] + bbc[j]) * w2c[j];
      part += __shfl_xor(part,1); part += __shfl_xor(part,2);
      part += __shfl_xor(part,4); part += __shfl_xor(part,8);
      if (l15 == 0) pr[wm + i*16 + quad*4 + r][wn>>6] = part;
    }
  }
  __syncthreads();
  if (tid < 128) {
    int e = e0 + tid;
    if (e < ELN) out[e] = pr[tid][0] + pr[tid][1] + bd2[0];
  }
}

// ---------------- edge layer 1 (full path): fp16 in, bf16 hi/lo plane out ----------------
__global__ __launch_bounds__(256) void k_edge1p(const _Float16* __restrict__ xl,
                                                const _Float16* __restrict__ xr, int ld,
                                                const float* __restrict__ att,
                                                const float* __restrict__ bias,
                                                const int* __restrict__ row_ptr,
                                                const int* __restrict__ col,
                                                u16* __restrict__ z1h, u16* __restrict__ z1l) {
  int wid = (blockIdx.x*blockDim.x + threadIdx.x) >> 6;
  if (wid >= NN) return;
  int lane = threadIdx.x & 63;
  int c8 = lane*8;
  float xi[8], av[8], acc[8] = {};
  ld8v(&xr[(size_t)wid*ld + c8], xi);
  #pragma unroll
  for (int j=0;j<8;++j) av[j] = att[c8+j];
  float s = 0.f;
  int e0 = row_ptr[wid], e1 = row_ptr[wid+1];
  int e = e0;
  if ((e1 - e0) & 1) {
    int sn = col[e]; if ((u32)sn >= (u32)NN) sn = 0;
    float xj[8];
    ld8v(&xl[(size_t)sn*ld + c8], xj);
    float p = 0.f;
    #pragma unroll
    for (int j=0;j<8;++j) {
      float t = xi[j] + xj[j];
      t = fmaxf(t, 0.2f*t);
      p += t*av[j];
    }
    p += __shfl_xor(p,1); p += __shfl_xor(p,2);
    p += __shfl_xor(p,4); p += __shfl_xor(p,8);
    float w = __expf(p);
    s += w;
    #pragma unroll
    for (int j=0;j<8;++j) acc[j] += w*xj[j];
    ++e;
  }
  for (; e < e1; e += 2) {
    int s1 = col[e];   if ((u32)s1 >= (u32)NN) s1 = 0;
    int s2 = col[e+1]; if ((u32)s2 >= (u32)NN) s2 = 0;
    float xj1[8], xj2[8];
    ld8v(&xl[(size_t)s1*ld + c8], xj1);
    ld8v(&xl[(size_t)s2*ld + c8], xj2);
    float p1 = 0.f, p2 = 0.f;
    #pragma unroll
    for (int j=0;j<8;++j) {
      float t1 = xi[j] + xj1[j]; t1 = fmaxf(t1, 0.2f*t1); p1 += t1*av[j];
      float t2 = xi[j] + xj2[j]; t2 = fmaxf(t2, 0.2f*t2); p2 += t2*av[j];
    }
    p1 += __shfl_xor(p1,1); p2 += __shfl_xor(p2,1);
    p1 += __shfl_xor(p1,2); p2 += __shfl_xor(p2,2);
    p1 += __shfl_xor(p1,4); p2 += __shfl_xor(p2,4);
    p1 += __shfl_xor(p1,8); p2 += __shfl_xor(p2,8);
    float w1 = __expf(p1);
    float w2 = __expf(p2);
    s += w1 + w2;
    #pragma unroll
    for (int j=0;j<8;++j) acc[j] += w1*xj1[j] + w2*xj2[j];
  }
  float inv = 1.f/s;
  u16 hh[8], ll[8];
  #pragma unroll
  for (int j=0;j<8;++j) {
    float o = gelu_f(acc[j]*inv + bias[c8+j]);
    hh[j] = f2us(o);
    ll[j] = f2us(o - us2f(hh[j]));
  }
  uint4 H, L;
  H.x = hh[0]|((u32)hh[1]<<16); H.y = hh[2]|((u32)hh[3]<<16);
  H.z = hh[4]|((u32)hh[5]<<16); H.w = hh[6]|((u32)hh[7]<<16);
  L.x = ll[0]|((u32)ll[1]<<16); L.y = ll[2]|((u32)ll[3]<<16);
  L.z = ll[4]|((u32)ll[5]<<16); L.w = ll[6]|((u32)ll[7]<<16);
  *(uint4*)&z1h[(size_t)wid*C1 + c8] = H;
  *(uint4*)&z1l[(size_t)wid*C1 + c8] = L;
}

// ---------------- edge layer 2 (full path): fp16 in, bf16 hi/lo plane out ----------------
__global__ __launch_bounds__(256) void k_edge2p(const _Float16* __restrict__ xl,
                                                const _Float16* __restrict__ xr, int ld,
                                                const float* __restrict__ att,
                                                const float* __restrict__ bias,
                                                const int* __restrict__ row_ptr,
                                                const int* __restrict__ col,
                                                u16* __restrict__ z2h, u16* __restrict__ z2l) {
  int wid = (blockIdx.x*blockDim.x + threadIdx.x) >> 6;
  if (wid >= NN) return;
  int lane = threadIdx.x & 63;
  int c2 = lane*2;
  float xiv[2];
  ld2v(&xr[(size_t)wid*ld + c2], xiv);
  float a0 = att[c2], a1 = att[c2+1];
  float s = 0.f, ac0 = 0.f, ac1 = 0.f;
  int e0 = row_ptr[wid], e1 = row_ptr[wid+1];
  int e = e0;
  if ((e1 - e0) & 1) {
    int sn = col[e]; if ((u32)sn >= (u32)NN) sn = 0;
    float xj[2];
    ld2v(&xl[(size_t)sn*ld + c2], xj);
    float t0 = xiv[0] + xj[0]; t0 = fmaxf(t0, 0.2f*t0);
    float t1 = xiv[1] + xj[1]; t1 = fmaxf(t1, 0.2f*t1);
    float p = t0*a0 + t1*a1;
    p += __shfl_xor(p,1);  p += __shfl_xor(p,2);
    p += __shfl_xor(p,4);  p += __shfl_xor(p,8);
    p += __shfl_xor(p,16); p += __shfl_xor(p,32);
    float w = __expf(p);
    s += w;
    ac0 += w*xj[0];
    ac1 += w*xj[1];
    ++e;
  }
  for (; e < e1; e += 2) {
    int s1 = col[e];   if ((u32)s1 >= (u32)NN) s1 = 0;
    int s2 = col[e+1]; if ((u32)s2 >= (u32)NN) s2 = 0;
    float xj1[2], xj2[2];
    ld2v(&xl[(size_t)s1*ld + c2], xj1);
    ld2v(&xl[(size_t)s2*ld + c2], xj2);
    float u0 = xiv[0] + xj1[0]; u0 = fmaxf(u0, 0.2f*u0);
    float u1 = xiv[1] + xj1[1]; u1 = fmaxf(u1, 0.2f*u1);
    float v0 = xiv[0] + xj2[0]; v0 = fmaxf(v0, 0.2f*v0);
    float v1 = xiv[1] + xj2[1]; v1 = fmaxf(v1, 0.2f*v1);
    float p1 = u0*a0 + u1*a1;
    float p2 = v0*a0 + v1*a1;
    p1 += __shfl_xor(p1,1);  p2 += __shfl_xor(p2,1);
    p1 += __shfl_xor(p1,2);  p2 += __shfl_xor(p2,2);
    p1 += __shfl_xor(p1,4);  p2 += __shfl_xor(p2,4);
    p1 += __shfl_xor(p1,8);  p2 += __shfl_xor(p2,8);
    p1 += __shfl_xor(p1,16); p2 += __shfl_xor(p2,16);
    p1 += __shfl_xor(p1,32); p2 += __shfl_xor(p2,32);
    float w1 = __expf(p1);
    float w2 = __expf(p2);
    s += w1 + w2;
    ac0 += w1*xj1[0] + w2*xj2[0];
    ac1 += w1*xj1[1] + w2*xj2[1];
  }
  float inv = 1.f/s;
  float o0 = ac0*inv + bias[c2];
  float o1 = ac1*inv + bias[c2+1];
  u16 h0 = f2us(o0), h1 = f2us(o1);
  u16 l0 = f2us(o0 - us2f(h0)), l1v = f2us(o1 - us2f(h1));
  *(u32*)&z2h[(size_t)wid*C2 + c2] = h0 | ((u32)h1 << 16);
  *(u32*)&z2l[(size_t)wid*C2 + c2] = l0 | ((u32)l1v << 16);
}

// ================= compact-path fallback kernels (unchanged structure) =================
template <typename AT, typename CT>
__global__ __launch_bounds__(256) void k_gemm(const AT* __restrict__ A,
                                              const float* __restrict__ W,
                                              const float* __restrict__ bias,
                                              CT* __restrict__ C,
                                              int M, int Nc, int K) {
  __shared__ __align__(16) float As[16][64];
  __shared__ __align__(16) float Bs[16][64];
  int tid = threadIdx.x;
  int m0 = blockIdx.x*64, n0 = blockIdx.y*64;
  int ty = tid >> 4, tx = tid & 15;
  int lrow = tid >> 2;
  int lk   = (tid & 3)*4;
  int wk   = tid >> 4;
  int wn   = (tid & 15)*4;
  float acc[4][4] = {};
  for (int k0 = 0; k0 < K; k0 += 16) {
    int row = m0 + lrow;
    if (row < M) {
      float a4[4]; ld4v(&A[(size_t)row*K + k0 + lk], a4);
      As[lk+0][lrow]=a4[0]; As[lk+1][lrow]=a4[1]; As[lk+2][lrow]=a4[2]; As[lk+3][lrow]=a4[3];
    } else {
      #pragma unroll
      for (int j=0;j<4;++j) As[lk+j][lrow]=0.f;
    }
    {
      float4 bv4 = *(const float4*)&W[(size_t)(k0+wk)*Nc + n0 + wn];
      Bs[wk][wn+0]=bv4.x; Bs[wk][wn+1]=bv4.y; Bs[wk][wn+2]=bv4.z; Bs[wk][wn+3]=bv4.w;
    }
    __syncthreads();
    #pragma unroll
    for (int kk=0;kk<16;++kk) {
      float4 av = *(const float4*)&As[kk][ty*4];
      float4 bv = *(const float4*)&Bs[kk][tx*4];
      float a[4]={av.x,av.y,av.z,av.w}, b[4]={bv.x,bv.y,bv.z,bv.w};
      #pragma unroll
      for (int i=0;i<4;++i)
        #pragma unroll
        for (int j=0;j<4;++j)
          acc[i][j] += a[i]*b[j];
    }
    __syncthreads();
  }
  float bv[4];
  #pragma unroll
  for (int j=0;j<4;++j) bv[j] = bias[n0 + tx*4 + j];
  #pragma unroll
  for (int i=0;i<4;++i) {
    int row = m0 + ty*4 + i;
    if (row < M) {
      float o4[4] = {acc[i][0]+bv[0], acc[i][1]+bv[1], acc[i][2]+bv[2], acc[i][3]+bv[3]};
      st4v(&C[(size_t)row*Nc + n0 + tx*4], o4);
    }
  }
}

template <typename TI, typename TO>
__global__ __launch_bounds__(256) void k_edge1c(const TI* __restrict__ xl,
                                                const TI* __restrict__ xr, int ld,
                                                const float* __restrict__ att,
                                                const float* __restrict__ bias,
                                                const int* __restrict__ row_ptr,
                                                const int* __restrict__ col,
                                                TO* __restrict__ z1) {
  int wid = (blockIdx.x*blockDim.x + threadIdx.x) >> 6;
  if (wid >= NN) return;
  int lane = threadIdx.x & 63;
  int c8 = lane*8;
  float xi[8], av[8], acc[8] = {};
  ld8v(&xr[(size_t)wid*ld + c8], xi);
  #pragma unroll
  for (int j=0;j<8;++j) av[j] = att[c8+j];
  float s = 0.f;
  int e0 = row_ptr[wid], e1 = row_ptr[wid+1];
  for (int e = e0; e < e1; ++e) {
    int sn = col[e]; if ((u32)sn >= (u32)NN) sn = 0;
    float xj[8];
    ld8v(&xl[(size_t)sn*ld + c8], xj);
    float p = 0.f;
    #pragma unroll
    for (int j=0;j<8;++j) {
      float t = xi[j] + xj[j];
      t = fmaxf(t, 0.2f*t);
      p += t*av[j];
    }
    p += __shfl_xor(p,1); p += __shfl_xor(p,2);
    p += __shfl_xor(p,4); p += __shfl_xor(p,8);
    float w = __expf(p);
    s += w;
    #pragma unroll
    for (int j=0;j<8;++j) acc[j] += w*xj[j];
  }
  float inv = 1.f/s, o[8];
  #pragma unroll
  for (int j=0;j<8;++j) o[j] = gelu_f(acc[j]*inv + bias[c8+j]);
  st8v(&z1[(size_t)wid*C1 + c8], o);
}

template <typename TI, typename TO>
__global__ __launch_bounds__(256) void k_edge2c(const TI* __restrict__ xl,
                                                const TI* __restrict__ xr, int ld,
                                                const float* __restrict__ att,
                                                const float* __restrict__ bias,
                                                const int* __restrict__ row_ptr,
                                                const int* __restrict__ col,
                                                TO* __restrict__ z2) {
  int wid = (blockIdx.x*blockDim.x + threadIdx.x) >> 6;
  if (wid >= NN) return;
  int lane = threadIdx.x & 63;
  int c2 = lane*2;
  float xiv[2];
  ld2v(&xr[(size_t)wid*ld + c2], xiv);
  float a0 = att[c2], a1 = att[c2+1];
  float s = 0.f, ac0 = 0.f, ac1 = 0.f;
  int e0 = row_ptr[wid], e1 = row_ptr[wid+1];
  for (int e = e0; e < e1; ++e) {
    int sn = col[e]; if ((u32)sn >= (u32)NN) sn = 0;
    float xj[2];
    ld2v(&xl[(size_t)sn*ld + c2], xj);
    float t0 = xiv[0] + xj[0]; t0 = fmaxf(t0, 0.2f*t0);
    float t1 = xiv[1] + xj[1]; t1 = fmaxf(t1, 0.2f*t1);
    float p = t0*a0 + t1*a1;
    p += __shfl_xor(p,1);  p += __shfl_xor(p,2);
    p += __shfl_xor(p,4);  p += __shfl_xor(p,8);
    p += __shfl_xor(p,16); p += __shfl_xor(p,32);
    float w = __expf(p);
    s += w;
    ac0 += w*xj[0];
    ac1 += w*xj[1];
  }
  float inv = 1.f/s;
  z2[(size_t)wid*C2 + c2]   = (TO)(ac0*inv + bias[c2]);
  z2[(size_t)wid*C2 + c2+1] = (TO)(ac1*inv + bias[c2+1]);
}

__global__ __launch_bounds__(256) void k_dec2(const float* __restrict__ z2,
                                              const int* __restrict__ eli,
                                              const float* __restrict__ Wd1,
                                              const float* __restrict__ bd1,
                                              const float* __restrict__ Wd2,
                                              const float* __restrict__ bd2,
                                              float* __restrict__ out) {
  __shared__ __align__(16) float As[16][64];
  __shared__ __align__(16) float Bs[16][128];
  int tid = threadIdx.x;
  int e0 = blockIdx.x * 64;
  int ty = tid >> 4, tx = tid & 15;
  int lrow = tid >> 2;
  int lk   = (tid & 3) * 4;
  int wk   = tid >> 4;
  int wn   = (tid & 15) * 8;
  int e = e0 + lrow;
  bool ev = e < ELN;
  int ia = ev ? eli[e] : 0;       if ((u32)ia >= (u32)NN) ia = 0;
  int ib = ev ? eli[ELN+e] : 0;   if ((u32)ib >= (u32)NN) ib = 0;
  float acc[4][8] = {};
  for (int k0 = 0; k0 < 256; k0 += 16) {
    int kk4 = k0 + lk;
    const float* src = (kk4 < 128) ? &z2[(size_t)ia*128 + kk4]
                                   : &z2[(size_t)ib*128 + (kk4 - 128)];
    float4 a4 = ev ? *(const float4*)src : make_float4(0.f,0.f,0.f,0.f);
    As[lk+0][lrow]=a4.x; As[lk+1][lrow]=a4.y; As[lk+2][lrow]=a4.z; As[lk+3][lrow]=a4.w;
    *(float4*)&Bs[wk][wn]   = *(const float4*)&Wd1[(size_t)(k0+wk)*128 + wn];
    *(float4*)&Bs[wk][wn+4] = *(const float4*)&Wd1[(size_t)(k0+wk)*128 + wn + 4];
    __syncthreads();
    #pragma unroll
    for (int kk = 0; kk < 16; ++kk) {
      float4 av = *(const float4*)&As[kk][ty*4];
      float a[4] = {av.x, av.y, av.z, av.w};
      float4 b0 = *(const float4*)&Bs[kk][tx*4];
      float4 b1 = *(const float4*)&Bs[kk][64 + tx*4];
      float b[8] = {b0.x,b0.y,b0.z,b0.w,b1.x,b1.y,b1.z,b1.w};
      #pragma unroll
      for (int i = 0; i < 4; ++i)
        #pragma unroll
        for (int j = 0; j < 8; ++j)
          acc[i][j] += a[i]*b[j];
    }
    __syncthreads();
  }
  float w2[8], bb[8];
  #pragma unroll
  for (int j = 0; j < 4; ++j) {
    w2[j]   = Wd2[tx*4+j];      bb[j]   = bd1[tx*4+j];
    w2[j+4] = Wd2[64+tx*4+j];   bb[j+4] = bd1[64+tx*4+j];
  }
  float b2 = bd2[0];
  #pragma unroll
  for (int i = 0; i < 4; ++i) {
    float part = 0.f;
    #pragma unroll
    for (int j = 0; j < 8; ++j)
      part += gelu_f(acc[i][j] + bb[j]) * w2[j];
    part += __shfl_xor(part,1); part += __shfl_xor(part,2);
    part += __shfl_xor(part,4); part += __shfl_xor(part,8);
    int row = e0 + ty*4 + i;
    if (tx == 0 && row < ELN) out[row] = part + b2;
  }
}

__global__ void k_tiny(float* out, float code) {
  if (threadIdx.x == 0) out[0] = code;
}

// ---------------- launch ----------------
extern "C" void kernel_launch(void* const* d_in, const int* in_sizes, int n_in,
                              void* d_out, int out_size, void* d_ws, size_t ws_size,
                              hipStream_t stream) {
  const float* x     = (const float*)d_in[0];
  const int*   ei    = (const int*)  d_in[1];
  const int*   eli   = (const int*)  d_in[2];
  const float* Wl1   = (const float*)d_in[3];
  const float* bl1   = (const float*)d_in[4];
  const float* Wr1   = (const float*)d_in[5];
  const float* br1   = (const float*)d_in[6];
  const float* att1  = (const float*)d_in[7];
  const float* bias1 = (const float*)d_in[8];
  const float* Wl2   = (const float*)d_in[9];
  const float* bl2   = (const float*)d_in[10];
  const float* Wr2   = (const float*)d_in[11];
  const float* br2   = (const float*)d_in[12];
  const float* att2  = (const float*)d_in[13];
  const float* bias2 = (const float*)d_in[14];
  const float* Wd1   = (const float*)d_in[15];
  const float* bd1   = (const float*)d_in[16];
  const float* Wd2   = (const float*)d_in[17];
  const float* bd2   = (const float*)d_in[18];
  float* out = (float*)d_out;

  constexpr size_t INTW = (size_t)(NN+1) + NN + ETOT;          // 380001 words
  constexpr size_t FULL_WORDS = 3ull*NN*C1 + INTW;             // ~124.4 MB (proven available)
  constexpr size_t CMP_WORDS  = 3ull*NN*C1/2 + INTW;           // ~63 MB

  bool full    = ws_size >= FULL_WORDS*4;
  bool compact = !full && ws_size >= CMP_WORDS*4;
  if (!full && !compact) {
    size_t mb = ws_size >> 20;
    k_tiny<<<1, 64, 0, stream>>>(out, 16384.f + (float)mb);
    return;
  }

  size_t regA = full ? (size_t)NN*C1 : (size_t)NN*C1/2;   // words per region
  char* base = (char*)d_ws;
  void* wA = base;
  void* wB = base + regA*4;
  void* wC = base + 2*regA*4;
  int* row_ptr = (int*)(base + 3*regA*4);
  int* cnt     = row_ptr + (NN + 1);
  int* col     = cnt + NN;
  int* bsum    = (int*)wA;   // scan scratch: wA dead during CSR phase

  // CSR over dst
  hipMemsetAsync(cnt, 0, NN*sizeof(int), stream);
  k_hist<<<(ETOT+255)/256, 256, 0, stream>>>(ei, cnt);
  k_scan_a<<<NB, 256, 0, stream>>>(cnt, row_ptr, bsum);
  k_scan_b<<<1, 128, 0, stream>>>(bsum, row_ptr);
  k_scan_c<<<NB, 256, 0, stream>>>(row_ptr, bsum, cnt);
  k_scatter<<<(ETOT+255)/256, 256, 0, stream>>>(ei, cnt, col);

  if (full) {
    // wA: xlr1 fp16 [20000][1024] = 40.96 MB; later xlr2 fp16 [20000][256]
    _Float16* xlr1 = (_Float16*)wA;
    _Float16* xlr2 = (_Float16*)wA;
    // wB: x planes (20.48 MB) + weight planes at +21 MB
    u16* xth = (u16*)wB;
    u16* xtl = xth + (size_t)NN*INC;
    u16* wt1th = (u16*)((char*)wB + (21u<<20));   // [1024][256]
    u16* wt1tl = wt1th + 1024*256;
    u16* wt2th = wt1tl + 1024*256;                // [256][512]
    u16* wt2tl = wt2th + 256*512;
    u16* wdth  = wt2tl + 256*512;                 // [128][256]
    u16* wdtl  = wdth  + 128*256;
    // wC: z1 planes (2 x 20.48 MB); later z2 planes (2 x 2.56 MB)
    u16* z1h = (u16*)wC;
    u16* z1l = z1h + (size_t)NN*C1;
    u16* z2h = (u16*)wC;
    u16* z2l = z2h + (size_t)NN*C2;

    k_xsplit<<<2048, 256, 0, stream>>>(x, xth, xtl, NN*INC);
    WsArgs wa;
    wa.src[0]=Wl1; wa.th[0]=wt1th;          wa.tl[0]=wt1tl;          wa.K[0]=INC; wa.N[0]=C1;
    wa.src[1]=Wr1; wa.th[1]=wt1th+512*256;  wa.tl[1]=wt1tl+512*256;  wa.K[1]=INC; wa.N[1]=C1;
    wa.src[2]=Wl2; wa.th[2]=wt2th;          wa.tl[2]=wt2tl;          wa.K[2]=C1;  wa.N[2]=C2;
    wa.src[3]=Wr2; wa.th[3]=wt2th+128*512;  wa.tl[3]=wt2tl+128*512;  wa.K[3]=C1;  wa.N[3]=C2;
    wa.src[4]=Wd1; wa.th[4]=wdth;           wa.tl[4]=wdtl;           wa.K[4]=256; wa.N[4]=C2;
    k_wsplit_all<<<dim3(512, 5), 256, 0, stream>>>(wa);

    // layer 1: merged GEMM N=1024, async staging, y-fastest swizzle (nby=8)
    k_mgemm_a<<<157*8, 256, 0, stream>>>(xth, xtl, wt1th, wt1tl,
                                         bl1, br1, 512, xlr1, NN, 1024, INC, 8);
    k_edge1p<<<NN/4, 256, 0, stream>>>(xlr1, xlr1+512, 1024, att1, bias1, row_ptr, col, z1h, z1l);
    // layer 2: merged GEMM N=256, A = z1 planes (nby=2)
    k_mgemm_a<<<157*2, 256, 0, stream>>>(z1h, z1l, wt2th, wt2tl,
                                         bl2, br2, 128, xlr2, NN, 256, C1, 2);
    k_edge2p<<<NN/4, 256, 0, stream>>>(xlr2, xlr2+128, 256, att2, bias2, row_ptr, col, z2h, z2l);
    k_dec4<<<(ELN+127)/128, 256, 0, stream>>>(z2h, z2l, eli, wdth, wdtl, bd1, Wd2, bd2, out);
  } else {
    u16* xl1 = (u16*)wA;
    u16* xr1 = (u16*)wB;
    u16* z1  = (u16*)wC;
    float* xl2 = (float*)wA;
    float* xr2 = (float*)wB;
    float* z2  = (float*)wC;
    dim3 g1((NN+63)/64, C1/64);
    dim3 g2((NN+63)/64, C2/64);
    k_gemm<float,u16><<<g1, 256, 0, stream>>>(x, Wl1, bl1, xl1, NN, C1, INC);
    k_gemm<float,u16><<<g1, 256, 0, stream>>>(x, Wr1, br1, xr1, NN, C1, INC);
    k_edge1c<u16,u16><<<NN/4, 256, 0, stream>>>(xl1, xr1, C1, att1, bias1, row_ptr, col, z1);
    k_gemm<u16,float><<<g2, 256, 0, stream>>>(z1, Wl2, bl2, xl2, NN, C2, C1);
    k_gemm<u16,float><<<g2, 256, 0, stream>>>(z1, Wr2, br2, xr2, NN, C2, C1);
    k_edge2c<float,float><<<NN/4, 256, 0, stream>>>(xl2, xr2, C2, att2, bias2, row_ptr, col, z2);
    k_dec2<<<(ELN+63)/64, 256, 0, stream>>>(z2, eli, Wd1, bd1, Wd2, bd2, out);
  }
}

// Round 12
// 374.560 us; speedup vs baseline: 2.3849x; 1.0387x over previous
//
#include <hip/hip_runtime.h>
#include <hip/hip_bf16.h>
#include <math.h>
#include <stdint.h>

using bf16 = __hip_bfloat16;
typedef unsigned short u16;
typedef unsigned int   u32;
typedef __attribute__((ext_vector_type(8))) short short8;   // 8 bf16 bit patterns
typedef __attribute__((ext_vector_type(4))) float f32x4;
typedef _Float16 h2 __attribute__((ext_vector_type(2)));

static constexpr int NN   = 20000;
static constexpr int EE   = 320000;
static constexpr int ELN  = 100000;
static constexpr int ETOT = EE + NN;
static constexpr int INC  = 256;
static constexpr int C1   = 512;
static constexpr int C2   = 128;
static constexpr int NB   = (NN + 255) / 256;   // scan blocks = 79

__device__ __forceinline__ float us2f(u16 u){ union{u32 i; float f;}x; x.i=((u32)u)<<16; return x.f; }
__device__ __forceinline__ u16  f2us(float f){ union{bf16 h; u16 u;}c; c.h=__float2bfloat16(f); return c.u; }
__device__ __forceinline__ float h2f(u16 u){ union{u16 u; _Float16 h;}c; c.u=u; return (float)c.h; }
__device__ __forceinline__ float gelu_f(float x){
  float u = 1.5957691216057308f*(x + 0.044715f*x*x*x);
  float ex = __expf(u);
  float th = 1.f - 2.f/(ex + 1.f);
  return 0.5f*x*(1.f+th);
}
// async global->LDS, 16B per lane; lds dest = wave-uniform base + lane*16
__device__ __forceinline__ void gl_lds16(const u16* g, void* l) {
  __builtin_amdgcn_global_load_lds((const __attribute__((address_space(1))) void*)g,
                                   (__attribute__((address_space(3))) void*)l, 16, 0, 0);
}
__device__ __forceinline__ void ld4v(const float* p, float* o){ float4 v=*(const float4*)p; o[0]=v.x;o[1]=v.y;o[2]=v.z;o[3]=v.w; }
__device__ __forceinline__ void ld4v(const u16* p, float* o){ uint2 v=*(const uint2*)p;
  o[0]=us2f(v.x&0xffff);o[1]=us2f(v.x>>16);o[2]=us2f(v.y&0xffff);o[3]=us2f(v.y>>16); }
__device__ __forceinline__ void ld8v(const float* p, float* o){ ld4v(p,o); ld4v(p+4,o+4); }
__device__ __forceinline__ void ld8v(const u16* p, float* o){ uint4 v=*(const uint4*)p;
  o[0]=us2f(v.x&0xffff);o[1]=us2f(v.x>>16);o[2]=us2f(v.y&0xffff);o[3]=us2f(v.y>>16);
  o[4]=us2f(v.z&0xffff);o[5]=us2f(v.z>>16);o[6]=us2f(v.w&0xffff);o[7]=us2f(v.w>>16); }
__device__ __forceinline__ void ld8v(const _Float16* p, float* o){ uint4 v=*(const uint4*)p;
  o[0]=h2f(v.x&0xffff);o[1]=h2f(v.x>>16);o[2]=h2f(v.y&0xffff);o[3]=h2f(v.y>>16);
  o[4]=h2f(v.z&0xffff);o[5]=h2f(v.z>>16);o[6]=h2f(v.w&0xffff);o[7]=h2f(v.w>>16); }
__device__ __forceinline__ void ld2v(const float* p, float* o){ float2 v=*(const float2*)p; o[0]=v.x;o[1]=v.y; }
__device__ __forceinline__ void ld2v(const _Float16* p, float* o){ u32 w=*(const u32*)p;
  o[0]=h2f(w&0xffff); o[1]=h2f(w>>16); }
__device__ __forceinline__ void st4v(float* p, const float* v){ *(float4*)p = make_float4(v[0],v[1],v[2],v[3]); }
__device__ __forceinline__ void st4v(u16* p, const float* v){ uint2 o;
  o.x=f2us(v[0])|((u32)f2us(v[1])<<16); o.y=f2us(v[2])|((u32)f2us(v[3])<<16); *(uint2*)p=o; }
__device__ __forceinline__ void st8v(float* p, const float* v){ st4v(p,v); st4v(p+4,v+4); }
__device__ __forceinline__ void st8v(u16* p, const float* v){ uint4 o;
  o.x=f2us(v[0])|((u32)f2us(v[1])<<16); o.y=f2us(v[2])|((u32)f2us(v[3])<<16);
  o.z=f2us(v[4])|((u32)f2us(v[5])<<16); o.w=f2us(v[6])|((u32)f2us(v[7])<<16); *(uint4*)p=o; }

// ---------------- CSR ----------------
__global__ void k_hist(const int* __restrict__ ei, int* __restrict__ cnt) {
  int e = blockIdx.x*blockDim.x + threadIdx.x;
  if (e < ETOT) {
    int d = (e < EE) ? ei[EE + e] : (e - EE);
    if ((u32)d < (u32)NN) atomicAdd(&cnt[d], 1);
  }
}
__global__ void k_scan_a(const int* __restrict__ cnt, int* __restrict__ row_ptr,
                         int* __restrict__ bsum) {
  __shared__ int buf[256];
  int idx = blockIdx.x*256 + threadIdx.x;
  int v = (idx < NN) ? cnt[idx] : 0;
  buf[threadIdx.x] = v;
  __syncthreads();
  for (int off = 1; off < 256; off <<= 1) {
    int t = (threadIdx.x >= off) ? buf[threadIdx.x - off] : 0;
    __syncthreads();
    buf[threadIdx.x] += t;
    __syncthreads();
  }
  if (idx < NN) row_ptr[idx] = buf[threadIdx.x] - v;
  if (threadIdx.x == 255) bsum[blockIdx.x] = buf[255];
}
__global__ void k_scan_b(int* __restrict__ bsum, int* __restrict__ row_ptr) {
  __shared__ int buf[128];
  int v = (threadIdx.x < NB) ? bsum[threadIdx.x] : 0;
  buf[threadIdx.x] = v;
  __syncthreads();
  for (int off = 1; off < 128; off <<= 1) {
    int t = (threadIdx.x >= off) ? buf[threadIdx.x - off] : 0;
    __syncthreads();
    buf[threadIdx.x] += t;
    __syncthreads();
  }
  if (threadIdx.x < NB) bsum[threadIdx.x] = buf[threadIdx.x] - v;
  if (threadIdx.x == 127) row_ptr[NN] = buf[127];
}
__global__ void k_scan_c(int* __restrict__ row_ptr, const int* __restrict__ bsum,
                         int* __restrict__ cur) {
  int idx = blockIdx.x*256 + threadIdx.x;
  if (idx < NN) {
    int v = row_ptr[idx] + bsum[blockIdx.x];
    row_ptr[idx] = v;
    cur[idx] = v;
  }
}
__global__ void k_scatter(const int* __restrict__ ei, int* __restrict__ cur,
                          int* __restrict__ col) {
  int e = blockIdx.x*blockDim.x + threadIdx.x;
  if (e < ETOT) {
    int s, d;
    if (e < EE) { s = ei[e]; d = ei[EE + e]; } else { s = d = e - EE; }
    if ((u32)d >= (u32)NN) d = 0;
    int pos = atomicAdd(&cur[d], 1);
    if ((u32)pos < (u32)ETOT) col[pos] = s;
  }
}

// ---------------- x row-major hi/lo split ----------------
__global__ __launch_bounds__(256) void k_xsplit(const float* __restrict__ A,
                                                u16* __restrict__ Ath, u16* __restrict__ Atl,
                                                int n) {
  for (int i = blockIdx.x*256 + threadIdx.x; i < n; i += gridDim.x*256) {
    float v = A[i];
    u16 h = f2us(v);
    Ath[i] = h;
    Atl[i] = f2us(v - us2f(h));
  }
}

// ---------------- batched weight transpose + hi/lo split ----------------
struct WsArgs { const float* src[5]; u16* th[5]; u16* tl[5]; int K[5]; int N[5]; };
__global__ __launch_bounds__(256) void k_wsplit_all(WsArgs a) {
  int seg = blockIdx.y;
  int K = a.K[seg], N = a.N[seg];
  int n = K * N;
  int idx = blockIdx.x*256 + threadIdx.x;
  if (idx >= n) return;
  int nn = idx / K, k = idx - nn*K;
  float v = a.src[seg][(size_t)k*N + nn];
  u16 h = f2us(v);
  a.th[seg][idx] = h;
  a.tl[seg][idx] = f2us(v - us2f(h));
}

// ---------------- MFMA GEMM, async staging: C(fp16) = A @ B + bias ----------------
__global__ __launch_bounds__(256, 2)
void k_mgemm_a(const u16* __restrict__ Ath, const u16* __restrict__ Atl,
               const u16* __restrict__ Bth, const u16* __restrict__ Btl,
               const float* __restrict__ biasA, const float* __restrict__ biasB, int ncut,
               _Float16* __restrict__ C, int M, int N, int K, int nby) {
  __shared__ __align__(16) u16 sm[17408];
  int tid = threadIdx.x;
  int bidy = blockIdx.x % nby, bidx = blockIdx.x / nby;
  int m0 = bidx * 128, n0 = bidy * 128;
  int wave = tid >> 6, lane = tid & 63;
  int wm = (wave & 1) * 64, wn = (wave >> 1) * 64;
  int l15 = lane & 15, quad = lane >> 4;
  const u16* pbase = (wave == 0) ? Ath : (wave == 1) ? Atl : (wave == 2) ? Bth : Btl;
  bool isA = wave < 2;
  int rbase = isA ? m0 : n0;
  int rseg = lane >> 2;
  int kseg = (lane & 3) * 8;
  f32x4 acc[4][4] = {};
  for (int k0 = 0; k0 < K; k0 += 32) {
    #pragma unroll
    for (int i = 0; i < 8; ++i) {
      int r = rbase + i*16 + rseg;
      if (isA && r > M-1) r = M-1;
      gl_lds16(&pbase[(size_t)r*K + k0 + kseg], (char*)sm + (wave<<13) + (i<<10));
    }
    __syncthreads();
    short8 af_h[4], af_l[4], bf_h[4], bf_l[4];
    #pragma unroll
    for (int i = 0; i < 4; ++i) {
      af_h[i] = *(const short8*)&sm[         (wm + i*16 + l15)*32 + quad*8];
      af_l[i] = *(const short8*)&sm[ 4096 +  (wm + i*16 + l15)*32 + quad*8];
      bf_h[i] = *(const short8*)&sm[ 8192 +  (wn + i*16 + l15)*32 + quad*8];
      bf_l[i] = *(const short8*)&sm[12288 +  (wn + i*16 + l15)*32 + quad*8];
    }
    #pragma unroll
    for (int i = 0; i < 4; ++i)
      #pragma unroll
      for (int j = 0; j < 4; ++j) {
        acc[i][j] = __builtin_amdgcn_mfma_f32_16x16x32_bf16(af_h[i], bf_l[j], acc[i][j], 0,0,0);
        acc[i][j] = __builtin_amdgcn_mfma_f32_16x16x32_bf16(af_l[i], bf_h[j], acc[i][j], 0,0,0);
        acc[i][j] = __builtin_amdgcn_mfma_f32_16x16x32_bf16(af_h[i], bf_h[j], acc[i][j], 0,0,0);
      }
    __syncthreads();
  }
  #pragma unroll
  for (int j = 0; j < 4; ++j) {
    int col = wn + j*16 + l15;
    int colg = n0 + col;
    float bv = (colg < ncut) ? biasA[colg] : biasB[colg - ncut];
    #pragma unroll
    for (int i = 0; i < 4; ++i) {
      int rowb = wm + i*16 + quad*4;
      #pragma unroll
      for (int r = 0; r < 4; ++r) {
        union { _Float16 h; u16 u; } cv;
        cv.h = (_Float16)(acc[i][j][r] + bv);
        sm[(rowb + r)*136 + col] = cv.u;
      }
    }
  }
  __syncthreads();
  int row = tid >> 1, half = (tid & 1) * 64;
  int gr = m0 + row;
  if (gr < M) {
    uint4* d = (uint4*)&C[(size_t)gr*N + n0 + half];
    const uint4* s = (const uint4*)&sm[row*136 + half];
    #pragma unroll
    for (int q = 0; q < 8; ++q) d[q] = s[q];
  }
}

// ---------------- MFMA decoder, async staging (z2 bf16 hi/lo planes) ----------------
__global__ __launch_bounds__(256, 2)
void k_dec4(const u16* __restrict__ z2h, const u16* __restrict__ z2l,
            const int* __restrict__ eli,
            const u16* __restrict__ Wth, const u16* __restrict__ Wtl,
            const float* __restrict__ bd1,
            const float* __restrict__ Wd2, const float* __restrict__ bd2,
            float* __restrict__ out) {
  __shared__ __align__(16) u16 sm[16384];
  __shared__ float pr[128][2];
  __shared__ int ias[128], ibs[128];
  int tid = threadIdx.x;
  int e0 = blockIdx.x * 128;
  if (tid < 128) {
    int e = e0 + tid;
    bool ev = e < ELN;
    int a = ev ? eli[e] : 0;      if ((u32)a >= (u32)NN) a = 0;
    int b = ev ? eli[ELN+e] : 0;  if ((u32)b >= (u32)NN) b = 0;
    ias[tid] = a; ibs[tid] = b;
  }
  __syncthreads();
  int wave = tid >> 6, lane = tid & 63;
  int wm = (wave & 1) * 64, wn = (wave >> 1) * 64;
  int l15 = lane & 15, quad = lane >> 4;
  const u16* pbase = (wave == 0) ? z2h : (wave == 1) ? z2l : (wave == 2) ? Wth : Wtl;
  bool isA = wave < 2;
  int rseg = lane >> 2;
  int kseg = (lane & 3) * 8;
  f32x4 acc[4][4] = {};
  for (int k0 = 0; k0 < 256; k0 += 32) {
    #pragma unroll
    for (int i = 0; i < 8; ++i) {
      int r = i*16 + rseg;
      const u16* g;
      if (isA) {
        int node = (k0 < 128) ? ias[r] : ibs[r];
        int kk   = (k0 < 128) ? k0 : (k0 - 128);
        g = &pbase[(size_t)node*128 + kk + kseg];
      } else {
        g = &pbase[(size_t)r*256 + k0 + kseg];
      }
      gl_lds16(g, (char*)sm + (wave<<13) + (i<<10));
    }
    __syncthreads();
    short8 af_h[4], af_l[4], bf_h[4], bf_l[4];
    #pragma unroll
    for (int i = 0; i < 4; ++i) {
      af_h[i] = *(const short8*)&sm[         (wm + i*16 + l15)*32 + quad*8];
      af_l[i] = *(const short8*)&sm[ 4096 +  (wm + i*16 + l15)*32 + quad*8];
      bf_h[i] = *(const short8*)&sm[ 8192 +  (wn + i*16 + l15)*32 + quad*8];
      bf_l[i] = *(const short8*)&sm[12288 +  (wn + i*16 + l15)*32 + quad*8];
    }
    #pragma unroll
    for (int i = 0; i < 4; ++i)
      #pragma unroll
      for (int j = 0; j < 4; ++j) {
        acc[i][j] = __builtin_amdgcn_mfma_f32_16x16x32_bf16(af_h[i], bf_l[j], acc[i][j], 0,0,0);
        acc[i][j] = __builtin_amdgcn_mfma_f32_16x16x32_bf16(af_l[i], bf_h[j], acc[i][j], 0,0,0);
        acc[i][j] = __builtin_amdgcn_mfma_f32_16x16x32_bf16(af_h[i], bf_h[j], acc[i][j], 0,0,0);
      }
    __syncthreads();
  }
  float w2c[4], bbc[4];
  #pragma unroll
  for (int j = 0; j < 4; ++j) {
    int col = wn + j*16 + l15;
    w2c[j] = Wd2[col];
    bbc[j] = bd1[col];
  }
  #pragma unroll
  for (int i = 0; i < 4; ++i) {
    #pragma unroll
    for (int r = 0; r < 4; ++r) {
      float part = 0.f;
      #pragma unroll
      for (int j = 0; j < 4; ++j)
        part += gelu_f(acc[i][j][r] + bbc[j]) * w2c[j];
      part += __shfl_xor(part,1); part += __shfl_xor(part,2);
      part += __shfl_xor(part,4); part += __shfl_xor(part,8);
      if (l15 == 0) pr[wm + i*16 + quad*4 + r][wn>>6] = part;
    }
  }
  __syncthreads();
  if (tid < 128) {
    int e = e0 + tid;
    if (e < ELN) out[e] = pr[tid][0] + pr[tid][1] + bd2[0];
  }
}

// ---------------- edge layer 1: packed-fp16 math, scalar gather index ----------------
__global__ __launch_bounds__(256) void k_edge1p(const _Float16* __restrict__ xl,
                                                const _Float16* __restrict__ xr, int ld,
                                                const float* __restrict__ att,
                                                const float* __restrict__ bias,
                                                const int* __restrict__ row_ptr,
                                                const int* __restrict__ col,
                                                u16* __restrict__ z1h, u16* __restrict__ z1l) {
  int wid = (blockIdx.x*blockDim.x + threadIdx.x) >> 6;
  if (wid >= NN) return;
  int lane = threadIdx.x & 63;
  int c8 = lane*8;
  union Q { uint4 u; h2 h[4]; };
  Q XI; XI.u = *(const uint4*)&xr[(size_t)wid*ld + c8];
  h2 at[4];
  #pragma unroll
  for (int k=0;k<4;++k) { at[k][0] = (_Float16)att[c8+2*k]; at[k][1] = (_Float16)att[c8+2*k+1]; }
  const h2 k02 = {(_Float16)0.2f, (_Float16)0.2f};
  float acc[8] = {};
  float s = 0.f;
  int e0 = __builtin_amdgcn_readfirstlane(row_ptr[wid]);
  int e1 = __builtin_amdgcn_readfirstlane(row_ptr[wid+1]);
  int e = e0;
  if ((e1 - e0) & 1) {
    int sn = __builtin_amdgcn_readfirstlane(col[e]); if ((u32)sn >= (u32)NN) sn = 0;
    Q XJ; XJ.u = *(const uint4*)&xl[(size_t)sn*ld + c8];
    float p = 0.f;
    #pragma unroll
    for (int k=0;k<4;++k) {
      h2 t = XI.h[k] + XJ.h[k];
      t = __builtin_elementwise_max(t, t*k02);   // leaky_relu 0.2 (v_pk_max)
      p = __builtin_amdgcn_fdot2(t, at[k], p, false);
    }
    p += __shfl_xor(p,1); p += __shfl_xor(p,2);
    p += __shfl_xor(p,4); p += __shfl_xor(p,8);
    float w = __expf(p);
    s += w;
    #pragma unroll
    for (int k=0;k<4;++k) {
      acc[2*k]   += w*(float)XJ.h[k][0];
      acc[2*k+1] += w*(float)XJ.h[k][1];
    }
    ++e;
  }
  for (; e < e1; e += 2) {
    int s1 = __builtin_amdgcn_readfirstlane(col[e]);   if ((u32)s1 >= (u32)NN) s1 = 0;
    int s2 = __builtin_amdgcn_readfirstlane(col[e+1]); if ((u32)s2 >= (u32)NN) s2 = 0;
    Q X1, X2;
    X1.u = *(const uint4*)&xl[(size_t)s1*ld + c8];
    X2.u = *(const uint4*)&xl[(size_t)s2*ld + c8];
    float p1 = 0.f, p2 = 0.f;
    #pragma unroll
    for (int k=0;k<4;++k) {
      h2 t1 = XI.h[k] + X1.h[k];
      t1 = __builtin_elementwise_max(t1, t1*k02);
      p1 = __builtin_amdgcn_fdot2(t1, at[k], p1, false);
      h2 t2 = XI.h[k] + X2.h[k];
      t2 = __builtin_elementwise_max(t2, t2*k02);
      p2 = __builtin_amdgcn_fdot2(t2, at[k], p2, false);
    }
    p1 += __shfl_xor(p1,1); p2 += __shfl_xor(p2,1);
    p1 += __shfl_xor(p1,2); p2 += __shfl_xor(p2,2);
    p1 += __shfl_xor(p1,4); p2 += __shfl_xor(p2,4);
    p1 += __shfl_xor(p1,8); p2 += __shfl_xor(p2,8);
    float w1 = __expf(p1);
    float w2 = __expf(p2);
    s += w1 + w2;
    #pragma unroll
    for (int k=0;k<4;++k) {
      acc[2*k]   += w1*(float)X1.h[k][0] + w2*(float)X2.h[k][0];
      acc[2*k+1] += w1*(float)X1.h[k][1] + w2*(float)X2.h[k][1];
    }
  }
  float inv = 1.f/s;
  u16 hh[8], ll[8];
  #pragma unroll
  for (int j=0;j<8;++j) {
    float o = gelu_f(acc[j]*inv + bias[c8+j]);
    hh[j] = f2us(o);
    ll[j] = f2us(o - us2f(hh[j]));
  }
  uint4 H, L;
  H.x = hh[0]|((u32)hh[1]<<16); H.y = hh[2]|((u32)hh[3]<<16);
  H.z = hh[4]|((u32)hh[5]<<16); H.w = hh[6]|((u32)hh[7]<<16);
  L.x = ll[0]|((u32)ll[1]<<16); L.y = ll[2]|((u32)ll[3]<<16);
  L.z = ll[4]|((u32)ll[5]<<16); L.w = ll[6]|((u32)ll[7]<<16);
  *(uint4*)&z1h[(size_t)wid*C1 + c8] = H;
  *(uint4*)&z1l[(size_t)wid*C1 + c8] = L;
}

// ---------------- edge layer 2: packed-fp16 math, scalar gather index ----------------
__global__ __launch_bounds__(256) void k_edge2p(const _Float16* __restrict__ xl,
                                                const _Float16* __restrict__ xr, int ld,
                                                const float* __restrict__ att,
                                                const float* __restrict__ bias,
                                                const int* __restrict__ row_ptr,
                                                const int* __restrict__ col,
                                                u16* __restrict__ z2h, u16* __restrict__ z2l) {
  int wid = (blockIdx.x*blockDim.x + threadIdx.x) >> 6;
  if (wid >= NN) return;
  int lane = threadIdx.x & 63;
  int c2 = lane*2;
  union W { u32 u; h2 h; };
  W XI; XI.u = *(const u32*)&xr[(size_t)wid*ld + c2];
  h2 at; at[0] = (_Float16)att[c2]; at[1] = (_Float16)att[c2+1];
  const h2 k02 = {(_Float16)0.2f, (_Float16)0.2f};
  float s = 0.f, ac0 = 0.f, ac1 = 0.f;
  int e0 = __builtin_amdgcn_readfirstlane(row_ptr[wid]);
  int e1 = __builtin_amdgcn_readfirstlane(row_ptr[wid+1]);
  int e = e0;
  if ((e1 - e0) & 1) {
    int sn = __builtin_amdgcn_readfirstlane(col[e]); if ((u32)sn >= (u32)NN) sn = 0;
    W XJ; XJ.u = *(const u32*)&xl[(size_t)sn*ld + c2];
    h2 t = XI.h + XJ.h;
    t = __builtin_elementwise_max(t, t*k02);
    float p = __builtin_amdgcn_fdot2(t, at, 0.f, false);
    p += __shfl_xor(p,1);  p += __shfl_xor(p,2);
    p += __shfl_xor(p,4);  p += __shfl_xor(p,8);
    p += __shfl_xor(p,16); p += __shfl_xor(p,32);
    float w = __expf(p);
    s += w;
    ac0 += w*(float)XJ.h[0];
    ac1 += w*(float)XJ.h[1];
    ++e;
  }
  for (; e < e1; e += 2) {
    int s1 = __builtin_amdgcn_readfirstlane(col[e]);   if ((u32)s1 >= (u32)NN) s1 = 0;
    int s2 = __builtin_amdgcn_readfirstlane(col[e+1]); if ((u32)s2 >= (u32)NN) s2 = 0;
    W X1, X2;
    X1.u = *(const u32*)&xl[(size_t)s1*ld + c2];
    X2.u = *(const u32*)&xl[(size_t)s2*ld + c2];
    h2 t1 = XI.h + X1.h;
    t1 = __builtin_elementwise_max(t1, t1*k02);
    float p1 = __builtin_amdgcn_fdot2(t1, at, 0.f, false);
    h2 t2 = XI.h + X2.h;
    t2 = __builtin_elementwise_max(t2, t2*k02);
    float p2 = __builtin_amdgcn_fdot2(t2, at, 0.f, false);
    p1 += __shfl_xor(p1,1);  p2 += __shfl_xor(p2,1);
    p1 += __shfl_xor(p1,2);  p2 += __shfl_xor(p2,2);
    p1 += __shfl_xor(p1,4);  p2 += __shfl_xor(p2,4);
    p1 += __shfl_xor(p1,8);  p2 += __shfl_xor(p2,8);
    p1 += __shfl_xor(p1,16); p2 += __shfl_xor(p2,16);
    p1 += __shfl_xor(p1,32); p2 += __shfl_xor(p2,32);
    float w1 = __expf(p1);
    float w2 = __expf(p2);
    s += w1 + w2;
    ac0 += w1*(float)X1.h[0] + w2*(float)X2.h[0];
    ac1 += w1*(float)X1.h[1] + w2*(float)X2.h[1];
  }
  float inv = 1.f/s;
  float o0 = ac0*inv + bias[c2];
  float o1 = ac1*inv + bias[c2+1];
  u16 h0 = f2us(o0), h1 = f2us(o1);
  u16 l0 = f2us(o0 - us2f(h0)), l1v = f2us(o1 - us2f(h1));
  *(u32*)&z2h[(size_t)wid*C2 + c2] = h0 | ((u32)h1 << 16);
  *(u32*)&z2l[(size_t)wid*C2 + c2] = l0 | ((u32)l1v << 16);
}

// ================= compact-path fallback kernels =================
template <typename AT, typename CT>
__global__ __launch_bounds__(256) void k_gemm(const AT* __restrict__ A,
                                              const float* __restrict__ W,
                                              const float* __restrict__ bias,
                                              CT* __restrict__ C,
                                              int M, int Nc, int K) {
  __shared__ __align__(16) float As[16][64];
  __shared__ __align__(16) float Bs[16][64];
  int tid = threadIdx.x;
  int m0 = blockIdx.x*64, n0 = blockIdx.y*64;
  int ty = tid >> 4, tx = tid & 15;
  int lrow = tid >> 2;
  int lk   = (tid & 3)*4;
  int wk   = tid >> 4;
  int wn   = (tid & 15)*4;
  float acc[4][4] = {};
  for (int k0 = 0; k0 < K; k0 += 16) {
    int row = m0 + lrow;
    if (row < M) {
      float a4[4]; ld4v(&A[(size_t)row*K + k0 + lk], a4);
      As[lk+0][lrow]=a4[0]; As[lk+1][lrow]=a4[1]; As[lk+2][lrow]=a4[2]; As[lk+3][lrow]=a4[3];
    } else {
      #pragma unroll
      for (int j=0;j<4;++j) As[lk+j][lrow]=0.f;
    }
    {
      float4 bv4 = *(const float4*)&W[(size_t)(k0+wk)*Nc + n0 + wn];
      Bs[wk][wn+0]=bv4.x; Bs[wk][wn+1]=bv4.y; Bs[wk][wn+2]=bv4.z; Bs[wk][wn+3]=bv4.w;
    }
    __syncthreads();
    #pragma unroll
    for (int kk=0;kk<16;++kk) {
      float4 av = *(const float4*)&As[kk][ty*4];
      float4 bv = *(const float4*)&Bs[kk][tx*4];
      float a[4]={av.x,av.y,av.z,av.w}, b[4]={bv.x,bv.y,bv.z,bv.w};
      #pragma unroll
      for (int i=0;i<4;++i)
        #pragma unroll
        for (int j=0;j<4;++j)
          acc[i][j] += a[i]*b[j];
    }
    __syncthreads();
  }
  float bv[4];
  #pragma unroll
  for (int j=0;j<4;++j) bv[j] = bias[n0 + tx*4 + j];
  #pragma unroll
  for (int i=0;i<4;++i) {
    int row = m0 + ty*4 + i;
    if (row < M) {
      float o4[4] = {acc[i][0]+bv[0], acc[i][1]+bv[1], acc[i][2]+bv[2], acc[i][3]+bv[3]};
      st4v(&C[(size_t)row*Nc + n0 + tx*4], o4);
    }
  }
}

template <typename TI, typename TO>
__global__ __launch_bounds__(256) void k_edge1c(const TI* __restrict__ xl,
                                                const TI* __restrict__ xr, int ld,
                                                const float* __restrict__ att,
                                                const float* __restrict__ bias,
                                                const int* __restrict__ row_ptr,
                                                const int* __restrict__ col,
                                                TO* __restrict__ z1) {
  int wid = (blockIdx.x*blockDim.x + threadIdx.x) >> 6;
  if (wid >= NN) return;
  int lane = threadIdx.x & 63;
  int c8 = lane*8;
  float xi[8], av[8], acc[8] = {};
  ld8v(&xr[(size_t)wid*ld + c8], xi);
  #pragma unroll
  for (int j=0;j<8;++j) av[j] = att[c8+j];
  float s = 0.f;
  int e0 = row_ptr[wid], e1 = row_ptr[wid+1];
  for (int e = e0; e < e1; ++e) {
    int sn = col[e]; if ((u32)sn >= (u32)NN) sn = 0;
    float xj[8];
    ld8v(&xl[(size_t)sn*ld + c8], xj);
    float p = 0.f;
    #pragma unroll
    for (int j=0;j<8;++j) {
      float t = xi[j] + xj[j];
      t = fmaxf(t, 0.2f*t);
      p += t*av[j];
    }
    p += __shfl_xor(p,1); p += __shfl_xor(p,2);
    p += __shfl_xor(p,4); p += __shfl_xor(p,8);
    float w = __expf(p);
    s += w;
    #pragma unroll
    for (int j=0;j<8;++j) acc[j] += w*xj[j];
  }
  float inv = 1.f/s, o[8];
  #pragma unroll
  for (int j=0;j<8;++j) o[j] = gelu_f(acc[j]*inv + bias[c8+j]);
  st8v(&z1[(size_t)wid*C1 + c8], o);
}

template <typename TI, typename TO>
__global__ __launch_bounds__(256) void k_edge2c(const TI* __restrict__ xl,
                                                const TI* __restrict__ xr, int ld,
                                                const float* __restrict__ att,
                                                const float* __restrict__ bias,
                                                const int* __restrict__ row_ptr,
                                                const int* __restrict__ col,
                                                TO* __restrict__ z2) {
  int wid = (blockIdx.x*blockDim.x + threadIdx.x) >> 6;
  if (wid >= NN) return;
  int lane = threadIdx.x & 63;
  int c2 = lane*2;
  float xiv[2];
  ld2v(&xr[(size_t)wid*ld + c2], xiv);
  float a0 = att[c2], a1 = att[c2+1];
  float s = 0.f, ac0 = 0.f, ac1 = 0.f;
  int e0 = row_ptr[wid], e1 = row_ptr[wid+1];
  for (int e = e0; e < e1; ++e) {
    int sn = col[e]; if ((u32)sn >= (u32)NN) sn = 0;
    float xj[2];
    ld2v(&xl[(size_t)sn*ld + c2], xj);
    float t0 = xiv[0] + xj[0]; t0 = fmaxf(t0, 0.2f*t0);
    float t1 = xiv[1] + xj[1]; t1 = fmaxf(t1, 0.2f*t1);
    float p = t0*a0 + t1*a1;
    p += __shfl_xor(p,1);  p += __shfl_xor(p,2);
    p += __shfl_xor(p,4);  p += __shfl_xor(p,8);
    p += __shfl_xor(p,16); p += __shfl_xor(p,32);
    float w = __expf(p);
    s += w;
    ac0 += w*xj[0];
    ac1 += w*xj[1];
  }
  float inv = 1.f/s;
  z2[(size_t)wid*C2 + c2]   = (TO)(ac0*inv + bias[c2]);
  z2[(size_t)wid*C2 + c2+1] = (TO)(ac1*inv + bias[c2+1]);
}

__global__ __launch_bounds__(256) void k_dec2(const float* __restrict__ z2,
                                              const int* __restrict__ eli,
                                              const float* __restrict__ Wd1,
                                              const float* __restrict__ bd1,
                                              const float* __restrict__ Wd2,
                                              const float* __restrict__ bd2,
                                              float* __restrict__ out) {
  __shared__ __align__(16) float As[16][64];
  __shared__ __align__(16) float Bs[16][128];
  int tid = threadIdx.x;
  int e0 = blockIdx.x * 64;
  int ty = tid >> 4, tx = tid & 15;
  int lrow = tid >> 2;
  int lk   = (tid & 3) * 4;
  int wk   = tid >> 4;
  int wn   = (tid & 15) * 8;
  int e = e0 + lrow;
  bool ev = e < ELN;
  int ia = ev ? eli[e] : 0;       if ((u32)ia >= (u32)NN) ia = 0;
  int ib = ev ? eli[ELN+e] : 0;   if ((u32)ib >= (u32)NN) ib = 0;
  float acc[4][8] = {};
  for (int k0 = 0; k0 < 256; k0 += 16) {
    int kk4 = k0 + lk;
    const float* src = (kk4 < 128) ? &z2[(size_t)ia*128 + kk4]
                                   : &z2[(size_t)ib*128 + (kk4 - 128)];
    float4 a4 = ev ? *(const float4*)src : make_float4(0.f,0.f,0.f,0.f);
    As[lk+0][lrow]=a4.x; As[lk+1][lrow]=a4.y; As[lk+2][lrow]=a4.z; As[lk+3][lrow]=a4.w;
    *(float4*)&Bs[wk][wn]   = *(const float4*)&Wd1[(size_t)(k0+wk)*128 + wn];
    *(float4*)&Bs[wk][wn+4] = *(const float4*)&Wd1[(size_t)(k0+wk)*128 + wn + 4];
    __syncthreads();
    #pragma unroll
    for (int kk = 0; kk < 16; ++kk) {
      float4 av = *(const float4*)&As[kk][ty*4];
      float a[4] = {av.x, av.y, av.z, av.w};
      float4 b0 = *(const float4*)&Bs[kk][tx*4];
      float4 b1 = *(const float4*)&Bs[kk][64 + tx*4];
      float b[8] = {b0.x,b0.y,b0.z,b0.w,b1.x,b1.y,b1.z,b1.w};
      #pragma unroll
      for (int i = 0; i < 4; ++i)
        #pragma unroll
        for (int j = 0; j < 8; ++j)
          acc[i][j] += a[i]*b[j];
    }
    __syncthreads();
  }
  float w2[8], bb[8];
  #pragma unroll
  for (int j = 0; j < 4; ++j) {
    w2[j]   = Wd2[tx*4+j];      bb[j]   = bd1[tx*4+j];
    w2[j+4] = Wd2[64+tx*4+j];   bb[j+4] = bd1[64+tx*4+j];
  }
  float b2 = bd2[0];
  #pragma unroll
  for (int i = 0; i < 4; ++i) {
    float part = 0.f;
    #pragma unroll
    for (int j = 0; j < 8; ++j)
      part += gelu_f(acc[i][j] + bb[j]) * w2[j];
    part += __shfl_xor(part,1); part += __shfl_xor(part,2);
    part += __shfl_xor(part,4); part += __shfl_xor(part,8);
    int row = e0 + ty*4 + i;
    if (tx == 0 && row < ELN) out[row] = part + b2;
  }
}

__global__ void k_tiny(float* out, float code) {
  if (threadIdx.x == 0) out[0] = code;
}

// ---------------- launch ----------------
extern "C" void kernel_launch(void* const* d_in, const int* in_sizes, int n_in,
                              void* d_out, int out_size, void* d_ws, size_t ws_size,
                              hipStream_t stream) {
  const float* x     = (const float*)d_in[0];
  const int*   ei    = (const int*)  d_in[1];
  const int*   eli   = (const int*)  d_in[2];
  const float* Wl1   = (const float*)d_in[3];
  const float* bl1   = (const float*)d_in[4];
  const float* Wr1   = (const float*)d_in[5];
  const float* br1   = (const float*)d_in[6];
  const float* att1  = (const float*)d_in[7];
  const float* bias1 = (const float*)d_in[8];
  const float* Wl2   = (const float*)d_in[9];
  const float* bl2   = (const float*)d_in[10];
  const float* Wr2   = (const float*)d_in[11];
  const float* br2   = (const float*)d_in[12];
  const float* att2  = (const float*)d_in[13];
  const float* bias2 = (const float*)d_in[14];
  const float* Wd1   = (const float*)d_in[15];
  const float* bd1   = (const float*)d_in[16];
  const float* Wd2   = (const float*)d_in[17];
  const float* bd2   = (const float*)d_in[18];
  float* out = (float*)d_out;

  constexpr size_t INTW = (size_t)(NN+1) + NN + ETOT;          // 380001 words
  constexpr size_t FULL_WORDS = 3ull*NN*C1 + INTW;             // ~124.4 MB (proven available)
  constexpr size_t CMP_WORDS  = 3ull*NN*C1/2 + INTW;           // ~63 MB

  bool full    = ws_size >= FULL_WORDS*4;
  bool compact = !full && ws_size >= CMP_WORDS*4;
  if (!full && !compact) {
    size_t mb = ws_size >> 20;
    k_tiny<<<1, 64, 0, stream>>>(out, 16384.f + (float)mb);
    return;
  }

  size_t regA = full ? (size_t)NN*C1 : (size_t)NN*C1/2;   // words per region
  char* base = (char*)d_ws;
  void* wA = base;
  void* wB = base + regA*4;
  void* wC = base + 2*regA*4;
  int* row_ptr = (int*)(base + 3*regA*4);
  int* cnt     = row_ptr + (NN + 1);
  int* col     = cnt + NN;
  int* bsum    = (int*)wA;   // scan scratch: wA dead during CSR phase

  // CSR over dst
  hipMemsetAsync(cnt, 0, NN*sizeof(int), stream);
  k_hist<<<(ETOT+255)/256, 256, 0, stream>>>(ei, cnt);
  k_scan_a<<<NB, 256, 0, stream>>>(cnt, row_ptr, bsum);
  k_scan_b<<<1, 128, 0, stream>>>(bsum, row_ptr);
  k_scan_c<<<NB, 256, 0, stream>>>(row_ptr, bsum, cnt);
  k_scatter<<<(ETOT+255)/256, 256, 0, stream>>>(ei, cnt, col);

  if (full) {
    _Float16* xlr1 = (_Float16*)wA;
    _Float16* xlr2 = (_Float16*)wA;
    u16* xth = (u16*)wB;
    u16* xtl = xth + (size_t)NN*INC;
    u16* wt1th = (u16*)((char*)wB + (21u<<20));   // [1024][256]
    u16* wt1tl = wt1th + 1024*256;
    u16* wt2th = wt1tl + 1024*256;                // [256][512]
    u16* wt2tl = wt2th + 256*512;
    u16* wdth  = wt2tl + 256*512;                 // [128][256]
    u16* wdtl  = wdth  + 128*256;
    u16* z1h = (u16*)wC;
    u16* z1l = z1h + (size_t)NN*C1;
    u16* z2h = (u16*)wC;
    u16* z2l = z2h + (size_t)NN*C2;

    k_xsplit<<<2048, 256, 0, stream>>>(x, xth, xtl, NN*INC);
    WsArgs wa;
    wa.src[0]=Wl1; wa.th[0]=wt1th;          wa.tl[0]=wt1tl;          wa.K[0]=INC; wa.N[0]=C1;
    wa.src[1]=Wr1; wa.th[1]=wt1th+512*256;  wa.tl[1]=wt1tl+512*256;  wa.K[1]=INC; wa.N[1]=C1;
    wa.src[2]=Wl2; wa.th[2]=wt2th;          wa.tl[2]=wt2tl;          wa.K[2]=C1;  wa.N[2]=C2;
    wa.src[3]=Wr2; wa.th[3]=wt2th+128*512;  wa.tl[3]=wt2tl+128*512;  wa.K[3]=C1;  wa.N[3]=C2;
    wa.src[4]=Wd1; wa.th[4]=wdth;           wa.tl[4]=wdtl;           wa.K[4]=256; wa.N[4]=C2;
    k_wsplit_all<<<dim3(512, 5), 256, 0, stream>>>(wa);

    k_mgemm_a<<<157*8, 256, 0, stream>>>(xth, xtl, wt1th, wt1tl,
                                         bl1, br1, 512, xlr1, NN, 1024, INC, 8);
    k_edge1p<<<NN/4, 256, 0, stream>>>(xlr1, xlr1+512, 1024, att1, bias1, row_ptr, col, z1h, z1l);
    k_mgemm_a<<<157*2, 256, 0, stream>>>(z1h, z1l, wt2th, wt2tl,
                                         bl2, br2, 128, xlr2, NN, 256, C1, 2);
    k_edge2p<<<NN/4, 256, 0, stream>>>(xlr2, xlr2+128, 256, att2, bias2, row_ptr, col, z2h, z2l);
    k_dec4<<<(ELN+127)/128, 256, 0, stream>>>(z2h, z2l, eli, wdth, wdtl, bd1, Wd2, bd2, out);
  } else {
    u16* xl1 = (u16*)wA;
    u16* xr1 = (u16*)wB;
    u16* z1  = (u16*)wC;
    float* xl2 = (float*)wA;
    float* xr2 = (float*)wB;
    float* z2  = (float*)wC;
    dim3 g1((NN+63)/64, C1/64);
    dim3 g2((NN+63)/64, C2/64);
    k_gemm<float,u16><<<g1, 256, 0, stream>>>(x, Wl1, bl1, xl1, NN, C1, INC);
    k_gemm<float,u16><<<g1, 256, 0, stream>>>(x, Wr1, br1, xr1, NN, C1, INC);
    k_edge1c<u16,u16><<<NN/4, 256, 0, stream>>>(xl1, xr1, C1, att1, bias1, row_ptr, col, z1);
    k_gemm<u16,float><<<g2, 256, 0, stream>>>(z1, Wl2, bl2, xl2, NN, C2, C1);
    k_gemm<u16,float><<<g2, 256, 0, stream>>>(z1, Wr2, br2, xr2, NN, C2, C1);
    k_edge2c<float,float><<<NN/4, 256, 0, stream>>>(xl2, xr2, C2, att2, bias2, row_ptr, col, z2);
    k_dec2<<<(ELN+63)/64, 256, 0, stream>>>(z2, eli, Wd1, bd1, Wd2, bd2, out);
  }
}

// Round 13
// 359.238 us; speedup vs baseline: 2.4866x; 1.0427x over previous
//
#include <hip/hip_runtime.h>
#include <hip/hip_bf16.h>
#include <math.h>
#include <stdint.h>

using bf16 = __hip_bfloat16;
typedef unsigned short u16;
typedef unsigned int   u32;
typedef __attribute__((ext_vector_type(8))) short short8;   // 8 bf16 bit patterns
typedef __attribute__((ext_vector_type(4))) float f32x4;
typedef _Float16 h2 __attribute__((ext_vector_type(2)));

static constexpr int NN   = 20000;
static constexpr int EE   = 320000;
static constexpr int ELN  = 100000;
static constexpr int ETOT = EE + NN;
static constexpr int INC  = 256;
static constexpr int C1   = 512;
static constexpr int C2   = 128;
static constexpr int NB   = (NN + 255) / 256;   // scan blocks = 79

__device__ __forceinline__ float us2f(u16 u){ union{u32 i; float f;}x; x.i=((u32)u)<<16; return x.f; }
__device__ __forceinline__ u16  f2us(float f){ union{bf16 h; u16 u;}c; c.h=__float2bfloat16(f); return c.u; }
__device__ __forceinline__ float h2f(u16 u){ union{u16 u; _Float16 h;}c; c.u=u; return (float)c.h; }
__device__ __forceinline__ float gelu_f(float x){
  float u = 1.5957691216057308f*(x + 0.044715f*x*x*x);
  float ex = __expf(u);
  float th = 1.f - 2.f/(ex + 1.f);
  return 0.5f*x*(1.f+th);
}
// async global->LDS, 16B per lane; lds dest = wave-uniform base + lane*16
__device__ __forceinline__ void gl_lds16(const u16* g, void* l) {
  __builtin_amdgcn_global_load_lds((const __attribute__((address_space(1))) void*)g,
                                   (__attribute__((address_space(3))) void*)l, 16, 0, 0);
}
__device__ __forceinline__ void ld4v(const float* p, float* o){ float4 v=*(const float4*)p; o[0]=v.x;o[1]=v.y;o[2]=v.z;o[3]=v.w; }
__device__ __forceinline__ void ld4v(const u16* p, float* o){ uint2 v=*(const uint2*)p;
  o[0]=us2f(v.x&0xffff);o[1]=us2f(v.x>>16);o[2]=us2f(v.y&0xffff);o[3]=us2f(v.y>>16); }
__device__ __forceinline__ void ld4v(const _Float16* p, float* o){ uint2 v=*(const uint2*)p;
  o[0]=h2f(v.x&0xffff);o[1]=h2f(v.x>>16);o[2]=h2f(v.y&0xffff);o[3]=h2f(v.y>>16); }
__device__ __forceinline__ void ld8v(const float* p, float* o){ ld4v(p,o); ld4v(p+4,o+4); }
__device__ __forceinline__ void ld8v(const u16* p, float* o){ uint4 v=*(const uint4*)p;
  o[0]=us2f(v.x&0xffff);o[1]=us2f(v.x>>16);o[2]=us2f(v.y&0xffff);o[3]=us2f(v.y>>16);
  o[4]=us2f(v.z&0xffff);o[5]=us2f(v.z>>16);o[6]=us2f(v.w&0xffff);o[7]=us2f(v.w>>16); }
__device__ __forceinline__ void ld8v(const _Float16* p, float* o){ uint4 v=*(const uint4*)p;
  o[0]=h2f(v.x&0xffff);o[1]=h2f(v.x>>16);o[2]=h2f(v.y&0xffff);o[3]=h2f(v.y>>16);
  o[4]=h2f(v.z&0xffff);o[5]=h2f(v.z>>16);o[6]=h2f(v.w&0xffff);o[7]=h2f(v.w>>16); }
__device__ __forceinline__ void ld2v(const float* p, float* o){ float2 v=*(const float2*)p; o[0]=v.x;o[1]=v.y; }
__device__ __forceinline__ void ld2v(const _Float16* p, float* o){ u32 w=*(const u32*)p;
  o[0]=h2f(w&0xffff); o[1]=h2f(w>>16); }
__device__ __forceinline__ void st4v(float* p, const float* v){ *(float4*)p = make_float4(v[0],v[1],v[2],v[3]); }
__device__ __forceinline__ void st4v(u16* p, const float* v){ uint2 o;
  o.x=f2us(v[0])|((u32)f2us(v[1])<<16); o.y=f2us(v[2])|((u32)f2us(v[3])<<16); *(uint2*)p=o; }
__device__ __forceinline__ void st8v(float* p, const float* v){ st4v(p,v); st4v(p+4,v+4); }
__device__ __forceinline__ void st8v(u16* p, const float* v){ uint4 o;
  o.x=f2us(v[0])|((u32)f2us(v[1])<<16); o.y=f2us(v[2])|((u32)f2us(v[3])<<16);
  o.z=f2us(v[4])|((u32)f2us(v[5])<<16); o.w=f2us(v[6])|((u32)f2us(v[7])<<16); *(uint4*)p=o; }

// ---------------- CSR ----------------
__global__ void k_hist(const int* __restrict__ ei, int* __restrict__ cnt) {
  int e = blockIdx.x*blockDim.x + threadIdx.x;
  if (e < ETOT) {
    int d = (e < EE) ? ei[EE + e] : (e - EE);
    if ((u32)d < (u32)NN) atomicAdd(&cnt[d], 1);
  }
}
__global__ void k_scan_a(const int* __restrict__ cnt, int* __restrict__ row_ptr,
                         int* __restrict__ bsum) {
  __shared__ int buf[256];
  int idx = blockIdx.x*256 + threadIdx.x;
  int v = (idx < NN) ? cnt[idx] : 0;
  buf[threadIdx.x] = v;
  __syncthreads();
  for (int off = 1; off < 256; off <<= 1) {
    int t = (threadIdx.x >= off) ? buf[threadIdx.x - off] : 0;
    __syncthreads();
    buf[threadIdx.x] += t;
    __syncthreads();
  }
  if (idx < NN) row_ptr[idx] = buf[threadIdx.x] - v;
  if (threadIdx.x == 255) bsum[blockIdx.x] = buf[255];
}
__global__ void k_scan_b(int* __restrict__ bsum, int* __restrict__ row_ptr) {
  __shared__ int buf[128];
  int v = (threadIdx.x < NB) ? bsum[threadIdx.x] : 0;
  buf[threadIdx.x] = v;
  __syncthreads();
  for (int off = 1; off < 128; off <<= 1) {
    int t = (threadIdx.x >= off) ? buf[threadIdx.x - off] : 0;
    __syncthreads();
    buf[threadIdx.x] += t;
    __syncthreads();
  }
  if (threadIdx.x < NB) bsum[threadIdx.x] = buf[threadIdx.x] - v;
  if (threadIdx.x == 127) row_ptr[NN] = buf[127];
}
__global__ void k_scan_c(int* __restrict__ row_ptr, const int* __restrict__ bsum,
                         int* __restrict__ cur) {
  int idx = blockIdx.x*256 + threadIdx.x;
  if (idx < NN) {
    int v = row_ptr[idx] + bsum[blockIdx.x];
    row_ptr[idx] = v;
    cur[idx] = v;
  }
}
__global__ void k_scatter(const int* __restrict__ ei, int* __restrict__ cur,
                          int* __restrict__ col) {
  int e = blockIdx.x*blockDim.x + threadIdx.x;
  if (e < ETOT) {
    int s, d;
    if (e < EE) { s = ei[e]; d = ei[EE + e]; } else { s = d = e - EE; }
    if ((u32)d >= (u32)NN) d = 0;
    int pos = atomicAdd(&cur[d], 1);
    if ((u32)pos < (u32)ETOT) col[pos] = s;
  }
}

// ---------------- x row-major hi/lo split ----------------
__global__ __launch_bounds__(256) void k_xsplit(const float* __restrict__ A,
                                                u16* __restrict__ Ath, u16* __restrict__ Atl,
                                                int n) {
  for (int i = blockIdx.x*256 + threadIdx.x; i < n; i += gridDim.x*256) {
    float v = A[i];
    u16 h = f2us(v);
    Ath[i] = h;
    Atl[i] = f2us(v - us2f(h));
  }
}

// ---------------- batched weight transpose + hi/lo split ----------------
struct WsArgs { const float* src[5]; u16* th[5]; u16* tl[5]; int K[5]; int N[5]; };
__global__ __launch_bounds__(256) void k_wsplit_all(WsArgs a) {
  int seg = blockIdx.y;
  int K = a.K[seg], N = a.N[seg];
  int n = K * N;
  int idx = blockIdx.x*256 + threadIdx.x;
  if (idx >= n) return;
  int nn = idx / K, k = idx - nn*K;
  float v = a.src[seg][(size_t)k*N + nn];
  u16 h = f2us(v);
  a.th[seg][idx] = h;
  a.tl[seg][idx] = f2us(v - us2f(h));
}

// ---------------- MFMA GEMM, async staging: C(fp16) = A @ B + bias ----------------
__global__ __launch_bounds__(256, 3)
void k_mgemm_a(const u16* __restrict__ Ath, const u16* __restrict__ Atl,
               const u16* __restrict__ Bth, const u16* __restrict__ Btl,
               const float* __restrict__ biasA, const float* __restrict__ biasB, int ncut,
               _Float16* __restrict__ C, int M, int N, int K, int nby) {
  __shared__ __align__(16) u16 sm[17408];
  int tid = threadIdx.x;
  int bidy = blockIdx.x % nby, bidx = blockIdx.x / nby;
  int m0 = bidx * 128, n0 = bidy * 128;
  int wave = tid >> 6, lane = tid & 63;
  int wm = (wave & 1) * 64, wn = (wave >> 1) * 64;
  int l15 = lane & 15, quad = lane >> 4;
  const u16* pbase = (wave == 0) ? Ath : (wave == 1) ? Atl : (wave == 2) ? Bth : Btl;
  bool isA = wave < 2;
  int rbase = isA ? m0 : n0;
  int rseg = lane >> 2;
  int kseg = (lane & 3) * 8;
  f32x4 acc[4][4] = {};
  for (int k0 = 0; k0 < K; k0 += 32) {
    #pragma unroll
    for (int i = 0; i < 8; ++i) {
      int r = rbase + i*16 + rseg;
      if (isA && r > M-1) r = M-1;
      gl_lds16(&pbase[(size_t)r*K + k0 + kseg], (char*)sm + (wave<<13) + (i<<10));
    }
    __syncthreads();
    short8 af_h[4], af_l[4], bf_h[4], bf_l[4];
    #pragma unroll
    for (int i = 0; i < 4; ++i) {
      af_h[i] = *(const short8*)&sm[         (wm + i*16 + l15)*32 + quad*8];
      af_l[i] = *(const short8*)&sm[ 4096 +  (wm + i*16 + l15)*32 + quad*8];
      bf_h[i] = *(const short8*)&sm[ 8192 +  (wn + i*16 + l15)*32 + quad*8];
      bf_l[i] = *(const short8*)&sm[12288 +  (wn + i*16 + l15)*32 + quad*8];
    }
    #pragma unroll
    for (int i = 0; i < 4; ++i)
      #pragma unroll
      for (int j = 0; j < 4; ++j) {
        acc[i][j] = __builtin_amdgcn_mfma_f32_16x16x32_bf16(af_h[i], bf_l[j], acc[i][j], 0,0,0);
        acc[i][j] = __builtin_amdgcn_mfma_f32_16x16x32_bf16(af_l[i], bf_h[j], acc[i][j], 0,0,0);
        acc[i][j] = __builtin_amdgcn_mfma_f32_16x16x32_bf16(af_h[i], bf_h[j], acc[i][j], 0,0,0);
      }
    __syncthreads();
  }
  #pragma unroll
  for (int j = 0; j < 4; ++j) {
    int col = wn + j*16 + l15;
    int colg = n0 + col;
    float bv = (colg < ncut) ? biasA[colg] : biasB[colg - ncut];
    #pragma unroll
    for (int i = 0; i < 4; ++i) {
      int rowb = wm + i*16 + quad*4;
      #pragma unroll
      for (int r = 0; r < 4; ++r) {
        union { _Float16 h; u16 u; } cv;
        cv.h = (_Float16)(acc[i][j][r] + bv);
        sm[(rowb + r)*136 + col] = cv.u;
      }
    }
  }
  __syncthreads();
  int row = tid >> 1, half = (tid & 1) * 64;
  int gr = m0 + row;
  if (gr < M) {
    uint4* d = (uint4*)&C[(size_t)gr*N + n0 + half];
    const uint4* s = (const uint4*)&sm[row*136 + half];
    #pragma unroll
    for (int q = 0; q < 8; ++q) d[q] = s[q];
  }
}

// ---------------- MFMA decoder (z2 fp16, regular loads, in-kernel split) ----------------
__global__ __launch_bounds__(256, 2)
void k_dec3(const _Float16* __restrict__ z2,
            const int* __restrict__ eli,
            const u16* __restrict__ Wth, const u16* __restrict__ Wtl,
            const float* __restrict__ bd1,
            const float* __restrict__ Wd2, const float* __restrict__ bd2,
            float* __restrict__ out) {
  __shared__ __align__(16) u16 Ah[128][32], Al[128][32];
  __shared__ __align__(16) u16 Bh[128][32], Bl[128][32];
  __shared__ float pr[128][2];
  int tid = threadIdx.x;
  int e0 = blockIdx.x * 128;
  int wave = tid >> 6, lane = tid & 63;
  int wm = (wave & 1) * 64, wn = (wave >> 1) * 64;
  int l15 = lane & 15, quad = lane >> 4;
  int ar = tid >> 3;
  int ak = (tid & 7) * 4;
  int bn = tid >> 2;
  int bc = (tid & 3) * 8;
  int ia4[4], ib4[4];
  #pragma unroll
  for (int i = 0; i < 4; ++i) {
    int e = e0 + ar + 32*i;
    bool ev = e < ELN;
    int a = ev ? eli[e] : 0;      if ((u32)a >= (u32)NN) a = 0;
    int b = ev ? eli[ELN+e] : 0;  if ((u32)b >= (u32)NN) b = 0;
    ia4[i] = a; ib4[i] = b;
  }
  f32x4 acc[4][4] = {};
  for (int k0 = 0; k0 < 256; k0 += 32) {
    #pragma unroll
    for (int i = 0; i < 4; ++i) {
      int row = ar + 32*i;
      int kk = k0 + ak;
      const _Float16* src = (kk < 128) ? &z2[(size_t)ia4[i]*128 + kk]
                                       : &z2[(size_t)ib4[i]*128 + (kk - 128)];
      float hv[4];
      ld4v(src, hv);
      u16 hi[4], lo[4];
      #pragma unroll
      for (int j = 0; j < 4; ++j) {
        hi[j] = f2us(hv[j]);
        lo[j] = f2us(hv[j] - us2f(hi[j]));
      }
      *(uint2*)&Ah[row][ak] = make_uint2(hi[0]|((u32)hi[1]<<16), hi[2]|((u32)hi[3]<<16));
      *(uint2*)&Al[row][ak] = make_uint2(lo[0]|((u32)lo[1]<<16), lo[2]|((u32)lo[3]<<16));
    }
    #pragma unroll
    for (int i = 0; i < 2; ++i) {
      int n = bn + 64*i;
      *(uint4*)&Bh[n][bc] = *(const uint4*)&Wth[(size_t)n*256 + k0 + bc];
      *(uint4*)&Bl[n][bc] = *(const uint4*)&Wtl[(size_t)n*256 + k0 + bc];
    }
    __syncthreads();
    short8 af_h[4], af_l[4], bf_h[4], bf_l[4];
    #pragma unroll
    for (int i = 0; i < 4; ++i) {
      af_h[i] = *(const short8*)&Ah[wm + i*16 + l15][quad*8];
      af_l[i] = *(const short8*)&Al[wm + i*16 + l15][quad*8];
      bf_h[i] = *(const short8*)&Bh[wn + i*16 + l15][quad*8];
      bf_l[i] = *(const short8*)&Bl[wn + i*16 + l15][quad*8];
    }
    #pragma unroll
    for (int i = 0; i < 4; ++i)
      #pragma unroll
      for (int j = 0; j < 4; ++j) {
        acc[i][j] = __builtin_amdgcn_mfma_f32_16x16x32_bf16(af_h[i], bf_l[j], acc[i][j], 0,0,0);
        acc[i][j] = __builtin_amdgcn_mfma_f32_16x16x32_bf16(af_l[i], bf_h[j], acc[i][j], 0,0,0);
        acc[i][j] = __builtin_amdgcn_mfma_f32_16x16x32_bf16(af_h[i], bf_h[j], acc[i][j], 0,0,0);
      }
    __syncthreads();
  }
  float w2c[4], bbc[4];
  #pragma unroll
  for (int j = 0; j < 4; ++j) {
    int col = wn + j*16 + l15;
    w2c[j] = Wd2[col];
    bbc[j] = bd1[col];
  }
  #pragma unroll
  for (int i = 0; i < 4; ++i) {
    #pragma unroll
    for (int r = 0; r < 4; ++r) {
      float part = 0.f;
      #pragma unroll
      for (int j = 0; j < 4; ++j)
        part += gelu_f(acc[i][j][r] + bbc[j]) * w2c[j];
      part += __shfl_xor(part,1); part += __shfl_xor(part,2);
      part += __shfl_xor(part,4); part += __shfl_xor(part,8);
      if (l15 == 0) pr[wm + i*16 + quad*4 + r][wn>>6] = part;
    }
  }
  __syncthreads();
  if (tid < 128) {
    int e = e0 + tid;
    if (e < ELN) out[e] = pr[tid][0] + pr[tid][1] + bd2[0];
  }
}

// ---------------- edge layer 1: packed-fp16 math, scalar gather index ----------------
__global__ __launch_bounds__(256) void k_edge1p(const _Float16* __restrict__ xl,
                                                const _Float16* __restrict__ xr, int ld,
                                                const float* __restrict__ att,
                                                const float* __restrict__ bias,
                                                const int* __restrict__ row_ptr,
                                                const int* __restrict__ col,
                                                u16* __restrict__ z1h, u16* __restrict__ z1l) {
  int wid = (blockIdx.x*blockDim.x + threadIdx.x) >> 6;
  if (wid >= NN) return;
  int lane = threadIdx.x & 63;
  int c8 = lane*8;
  union Q { uint4 u; h2 h[4]; };
  Q XI; XI.u = *(const uint4*)&xr[(size_t)wid*ld + c8];
  h2 at[4];
  #pragma unroll
  for (int k=0;k<4;++k) { at[k][0] = (_Float16)att[c8+2*k]; at[k][1] = (_Float16)att[c8+2*k+1]; }
  const h2 k02 = {(_Float16)0.2f, (_Float16)0.2f};
  float acc[8] = {};
  float s = 0.f;
  int e0 = __builtin_amdgcn_readfirstlane(row_ptr[wid]);
  int e1 = __builtin_amdgcn_readfirstlane(row_ptr[wid+1]);
  int e = e0;
  if ((e1 - e0) & 1) {
    int sn = __builtin_amdgcn_readfirstlane(col[e]); if ((u32)sn >= (u32)NN) sn = 0;
    Q XJ; XJ.u = *(const uint4*)&xl[(size_t)sn*ld + c8];
    float p = 0.f;
    #pragma unroll
    for (int k=0;k<4;++k) {
      h2 t = XI.h[k] + XJ.h[k];
      t = __builtin_elementwise_max(t, t*k02);
      p = __builtin_amdgcn_fdot2(t, at[k], p, false);
    }
    p += __shfl_xor(p,1); p += __shfl_xor(p,2);
    p += __shfl_xor(p,4); p += __shfl_xor(p,8);
    float w = __expf(p);
    s += w;
    #pragma unroll
    for (int k=0;k<4;++k) {
      acc[2*k]   += w*(float)XJ.h[k][0];
      acc[2*k+1] += w*(float)XJ.h[k][1];
    }
    ++e;
  }
  for (; e < e1; e += 2) {
    int s1 = __builtin_amdgcn_readfirstlane(col[e]);   if ((u32)s1 >= (u32)NN) s1 = 0;
    int s2 = __builtin_amdgcn_readfirstlane(col[e+1]); if ((u32)s2 >= (u32)NN) s2 = 0;
    Q X1, X2;
    X1.u = *(const uint4*)&xl[(size_t)s1*ld + c8];
    X2.u = *(const uint4*)&xl[(size_t)s2*ld + c8];
    float p1 = 0.f, p2 = 0.f;
    #pragma unroll
    for (int k=0;k<4;++k) {
      h2 t1 = XI.h[k] + X1.h[k];
      t1 = __builtin_elementwise_max(t1, t1*k02);
      p1 = __builtin_amdgcn_fdot2(t1, at[k], p1, false);
      h2 t2 = XI.h[k] + X2.h[k];
      t2 = __builtin_elementwise_max(t2, t2*k02);
      p2 = __builtin_amdgcn_fdot2(t2, at[k], p2, false);
    }
    p1 += __shfl_xor(p1,1); p2 += __shfl_xor(p2,1);
    p1 += __shfl_xor(p1,2); p2 += __shfl_xor(p2,2);
    p1 += __shfl_xor(p1,4); p2 += __shfl_xor(p2,4);
    p1 += __shfl_xor(p1,8); p2 += __shfl_xor(p2,8);
    float w1 = __expf(p1);
    float w2 = __expf(p2);
    s += w1 + w2;
    #pragma unroll
    for (int k=0;k<4;++k) {
      acc[2*k]   += w1*(float)X1.h[k][0] + w2*(float)X2.h[k][0];
      acc[2*k+1] += w1*(float)X1.h[k][1] + w2*(float)X2.h[k][1];
    }
  }
  float inv = 1.f/s;
  u16 hh[8], ll[8];
  #pragma unroll
  for (int j=0;j<8;++j) {
    float o = gelu_f(acc[j]*inv + bias[c8+j]);
    hh[j] = f2us(o);
    ll[j] = f2us(o - us2f(hh[j]));
  }
  uint4 H, L;
  H.x = hh[0]|((u32)hh[1]<<16); H.y = hh[2]|((u32)hh[3]<<16);
  H.z = hh[4]|((u32)hh[5]<<16); H.w = hh[6]|((u32)hh[7]<<16);
  L.x = ll[0]|((u32)ll[1]<<16); L.y = ll[2]|((u32)ll[3]<<16);
  L.z = ll[4]|((u32)ll[5]<<16); L.w = ll[6]|((u32)ll[7]<<16);
  *(uint4*)&z1h[(size_t)wid*C1 + c8] = H;
  *(uint4*)&z1l[(size_t)wid*C1 + c8] = L;
}

// ---------------- edge layer 2: packed-fp16 math, fp16 z2 out ----------------
__global__ __launch_bounds__(256) void k_edge2p(const _Float16* __restrict__ xl,
                                                const _Float16* __restrict__ xr, int ld,
                                                const float* __restrict__ att,
                                                const float* __restrict__ bias,
                                                const int* __restrict__ row_ptr,
                                                const int* __restrict__ col,
                                                _Float16* __restrict__ z2) {
  int wid = (blockIdx.x*blockDim.x + threadIdx.x) >> 6;
  if (wid >= NN) return;
  int lane = threadIdx.x & 63;
  int c2 = lane*2;
  union W { u32 u; h2 h; };
  W XI; XI.u = *(const u32*)&xr[(size_t)wid*ld + c2];
  h2 at; at[0] = (_Float16)att[c2]; at[1] = (_Float16)att[c2+1];
  const h2 k02 = {(_Float16)0.2f, (_Float16)0.2f};
  float s = 0.f, ac0 = 0.f, ac1 = 0.f;
  int e0 = __builtin_amdgcn_readfirstlane(row_ptr[wid]);
  int e1 = __builtin_amdgcn_readfirstlane(row_ptr[wid+1]);
  int e = e0;
  if ((e1 - e0) & 1) {
    int sn = __builtin_amdgcn_readfirstlane(col[e]); if ((u32)sn >= (u32)NN) sn = 0;
    W XJ; XJ.u = *(const u32*)&xl[(size_t)sn*ld + c2];
    h2 t = XI.h + XJ.h;
    t = __builtin_elementwise_max(t, t*k02);
    float p = __builtin_amdgcn_fdot2(t, at, 0.f, false);
    p += __shfl_xor(p,1);  p += __shfl_xor(p,2);
    p += __shfl_xor(p,4);  p += __shfl_xor(p,8);
    p += __shfl_xor(p,16); p += __shfl_xor(p,32);
    float w = __expf(p);
    s += w;
    ac0 += w*(float)XJ.h[0];
    ac1 += w*(float)XJ.h[1];
    ++e;
  }
  for (; e < e1; e += 2) {
    int s1 = __builtin_amdgcn_readfirstlane(col[e]);   if ((u32)s1 >= (u32)NN) s1 = 0;
    int s2 = __builtin_amdgcn_readfirstlane(col[e+1]); if ((u32)s2 >= (u32)NN) s2 = 0;
    W X1, X2;
    X1.u = *(const u32*)&xl[(size_t)s1*ld + c2];
    X2.u = *(const u32*)&xl[(size_t)s2*ld + c2];
    h2 t1 = XI.h + X1.h;
    t1 = __builtin_elementwise_max(t1, t1*k02);
    float p1 = __builtin_amdgcn_fdot2(t1, at, 0.f, false);
    h2 t2 = XI.h + X2.h;
    t2 = __builtin_elementwise_max(t2, t2*k02);
    float p2 = __builtin_amdgcn_fdot2(t2, at, 0.f, false);
    p1 += __shfl_xor(p1,1);  p2 += __shfl_xor(p2,1);
    p1 += __shfl_xor(p1,2);  p2 += __shfl_xor(p2,2);
    p1 += __shfl_xor(p1,4);  p2 += __shfl_xor(p2,4);
    p1 += __shfl_xor(p1,8);  p2 += __shfl_xor(p2,8);
    p1 += __shfl_xor(p1,16); p2 += __shfl_xor(p2,16);
    p1 += __shfl_xor(p1,32); p2 += __shfl_xor(p2,32);
    float w1 = __expf(p1);
    float w2 = __expf(p2);
    s += w1 + w2;
    ac0 += w1*(float)X1.h[0] + w2*(float)X2.h[0];
    ac1 += w1*(float)X1.h[1] + w2*(float)X2.h[1];
  }
  float inv = 1.f/s;
  union { h2 h; u32 u; } o;
  o.h[0] = (_Float16)(ac0*inv + bias[c2]);
  o.h[1] = (_Float16)(ac1*inv + bias[c2+1]);
  *(u32*)&z2[(size_t)wid*C2 + c2] = o.u;
}

// ================= compact-path fallback kernels =================
template <typename AT, typename CT>
__global__ __launch_bounds__(256) void k_gemm(const AT* __restrict__ A,
                                              const float* __restrict__ W,
                                              const float* __restrict__ bias,
                                              CT* __restrict__ C,
                                              int M, int Nc, int K) {
  __shared__ __align__(16) float As[16][64];
  __shared__ __align__(16) float Bs[16][64];
  int tid = threadIdx.x;
  int m0 = blockIdx.x*64, n0 = blockIdx.y*64;
  int ty = tid >> 4, tx = tid & 15;
  int lrow = tid >> 2;
  int lk   = (tid & 3)*4;
  int wk   = tid >> 4;
  int wn   = (tid & 15)*4;
  float acc[4][4] = {};
  for (int k0 = 0; k0 < K; k0 += 16) {
    int row = m0 + lrow;
    if (row < M) {
      float a4[4]; ld4v(&A[(size_t)row*K + k0 + lk], a4);
      As[lk+0][lrow]=a4[0]; As[lk+1][lrow]=a4[1]; As[lk+2][lrow]=a4[2]; As[lk+3][lrow]=a4[3];
    } else {
      #pragma unroll
      for (int j=0;j<4;++j) As[lk+j][lrow]=0.f;
    }
    {
      float4 bv4 = *(const float4*)&W[(size_t)(k0+wk)*Nc + n0 + wn];
      Bs[wk][wn+0]=bv4.x; Bs[wk][wn+1]=bv4.y; Bs[wk][wn+2]=bv4.z; Bs[wk][wn+3]=bv4.w;
    }
    __syncthreads();
    #pragma unroll
    for (int kk=0;kk<16;++kk) {
      float4 av = *(const float4*)&As[kk][ty*4];
      float4 bv = *(const float4*)&Bs[kk][tx*4];
      float a[4]={av.x,av.y,av.z,av.w}, b[4]={bv.x,bv.y,bv.z,bv.w};
      #pragma unroll
      for (int i=0;i<4;++i)
        #pragma unroll
        for (int j=0;j<4;++j)
          acc[i][j] += a[i]*b[j];
    }
    __syncthreads();
  }
  float bv[4];
  #pragma unroll
  for (int j=0;j<4;++j) bv[j] = bias[n0 + tx*4 + j];
  #pragma unroll
  for (int i=0;i<4;++i) {
    int row = m0 + ty*4 + i;
    if (row < M) {
      float o4[4] = {acc[i][0]+bv[0], acc[i][1]+bv[1], acc[i][2]+bv[2], acc[i][3]+bv[3]};
      st4v(&C[(size_t)row*Nc + n0 + tx*4], o4);
    }
  }
}

template <typename TI, typename TO>
__global__ __launch_bounds__(256) void k_edge1c(const TI* __restrict__ xl,
                                                const TI* __restrict__ xr, int ld,
                                                const float* __restrict__ att,
                                                const float* __restrict__ bias,
                                                const int* __restrict__ row_ptr,
                                                const int* __restrict__ col,
                                                TO* __restrict__ z1) {
  int wid = (blockIdx.x*blockDim.x + threadIdx.x) >> 6;
  if (wid >= NN) return;
  int lane = threadIdx.x & 63;
  int c8 = lane*8;
  float xi[8], av[8], acc[8] = {};
  ld8v(&xr[(size_t)wid*ld + c8], xi);
  #pragma unroll
  for (int j=0;j<8;++j) av[j] = att[c8+j];
  float s = 0.f;
  int e0 = row_ptr[wid], e1 = row_ptr[wid+1];
  for (int e = e0; e < e1; ++e) {
    int sn = col[e]; if ((u32)sn >= (u32)NN) sn = 0;
    float xj[8];
    ld8v(&xl[(size_t)sn*ld + c8], xj);
    float p = 0.f;
    #pragma unroll
    for (int j=0;j<8;++j) {
      float t = xi[j] + xj[j];
      t = fmaxf(t, 0.2f*t);
      p += t*av[j];
    }
    p += __shfl_xor(p,1); p += __shfl_xor(p,2);
    p += __shfl_xor(p,4); p += __shfl_xor(p,8);
    float w = __expf(p);
    s += w;
    #pragma unroll
    for (int j=0;j<8;++j) acc[j] += w*xj[j];
  }
  float inv = 1.f/s, o[8];
  #pragma unroll
  for (int j=0;j<8;++j) o[j] = gelu_f(acc[j]*inv + bias[c8+j]);
  st8v(&z1[(size_t)wid*C1 + c8], o);
}

template <typename TI, typename TO>
__global__ __launch_bounds__(256) void k_edge2c(const TI* __restrict__ xl,
                                                const TI* __restrict__ xr, int ld,
                                                const float* __restrict__ att,
                                                const float* __restrict__ bias,
                                                const int* __restrict__ row_ptr,
                                                const int* __restrict__ col,
                                                TO* __restrict__ z2) {
  int wid = (blockIdx.x*blockDim.x + threadIdx.x) >> 6;
  if (wid >= NN) return;
  int lane = threadIdx.x & 63;
  int c2 = lane*2;
  float xiv[2];
  ld2v(&xr[(size_t)wid*ld + c2], xiv);
  float a0 = att[c2], a1 = att[c2+1];
  float s = 0.f, ac0 = 0.f, ac1 = 0.f;
  int e0 = row_ptr[wid], e1 = row_ptr[wid+1];
  for (int e = e0; e < e1; ++e) {
    int sn = col[e]; if ((u32)sn >= (u32)NN) sn = 0;
    float xj[2];
    ld2v(&xl[(size_t)sn*ld + c2], xj);
    float t0 = xiv[0] + xj[0]; t0 = fmaxf(t0, 0.2f*t0);
    float t1 = xiv[1] + xj[1]; t1 = fmaxf(t1, 0.2f*t1);
    float p = t0*a0 + t1*a1;
    p += __shfl_xor(p,1);  p += __shfl_xor(p,2);
    p += __shfl_xor(p,4);  p += __shfl_xor(p,8);
    p += __shfl_xor(p,16); p += __shfl_xor(p,32);
    float w = __expf(p);
    s += w;
    ac0 += w*xj[0];
    ac1 += w*xj[1];
  }
  float inv = 1.f/s;
  z2[(size_t)wid*C2 + c2]   = (TO)(ac0*inv + bias[c2]);
  z2[(size_t)wid*C2 + c2+1] = (TO)(ac1*inv + bias[c2+1]);
}

__global__ __launch_bounds__(256) void k_dec2(const float* __restrict__ z2,
                                              const int* __restrict__ eli,
                                              const float* __restrict__ Wd1,
                                              const float* __restrict__ bd1,
                                              const float* __restrict__ Wd2,
                                              const float* __restrict__ bd2,
                                              float* __restrict__ out) {
  __shared__ __align__(16) float As[16][64];
  __shared__ __align__(16) float Bs[16][128];
  int tid = threadIdx.x;
  int e0 = blockIdx.x * 64;
  int ty = tid >> 4, tx = tid & 15;
  int lrow = tid >> 2;
  int lk   = (tid & 3) * 4;
  int wk   = tid >> 4;
  int wn   = (tid & 15) * 8;
  int e = e0 + lrow;
  bool ev = e < ELN;
  int ia = ev ? eli[e] : 0;       if ((u32)ia >= (u32)NN) ia = 0;
  int ib = ev ? eli[ELN+e] : 0;   if ((u32)ib >= (u32)NN) ib = 0;
  float acc[4][8] = {};
  for (int k0 = 0; k0 < 256; k0 += 16) {
    int kk4 = k0 + lk;
    const float* src = (kk4 < 128) ? &z2[(size_t)ia*128 + kk4]
                                   : &z2[(size_t)ib*128 + (kk4 - 128)];
    float4 a4 = ev ? *(const float4*)src : make_float4(0.f,0.f,0.f,0.f);
    As[lk+0][lrow]=a4.x; As[lk+1][lrow]=a4.y; As[lk+2][lrow]=a4.z; As[lk+3][lrow]=a4.w;
    *(float4*)&Bs[wk][wn]   = *(const float4*)&Wd1[(size_t)(k0+wk)*128 + wn];
    *(float4*)&Bs[wk][wn+4] = *(const float4*)&Wd1[(size_t)(k0+wk)*128 + wn + 4];
    __syncthreads();
    #pragma unroll
    for (int kk = 0; kk < 16; ++kk) {
      float4 av = *(const float4*)&As[kk][ty*4];
      float a[4] = {av.x, av.y, av.z, av.w};
      float4 b0 = *(const float4*)&Bs[kk][tx*4];
      float4 b1 = *(const float4*)&Bs[kk][64 + tx*4];
      float b[8] = {b0.x,b0.y,b0.z,b0.w,b1.x,b1.y,b1.z,b1.w};
      #pragma unroll
      for (int i = 0; i < 4; ++i)
        #pragma unroll
        for (int j = 0; j < 8; ++j)
          acc[i][j] += a[i]*b[j];
    }
    __syncthreads();
  }
  float w2[8], bb[8];
  #pragma unroll
  for (int j = 0; j < 4; ++j) {
    w2[j]   = Wd2[tx*4+j];      bb[j]   = bd1[tx*4+j];
    w2[j+4] = Wd2[64+tx*4+j];   bb[j+4] = bd1[64+tx*4+j];
  }
  float b2 = bd2[0];
  #pragma unroll
  for (int i = 0; i < 4; ++i) {
    float part = 0.f;
    #pragma unroll
    for (int j = 0; j < 8; ++j)
      part += gelu_f(acc[i][j] + bb[j]) * w2[j];
    part += __shfl_xor(part,1); part += __shfl_xor(part,2);
    part += __shfl_xor(part,4); part += __shfl_xor(part,8);
    int row = e0 + ty*4 + i;
    if (tx == 0 && row < ELN) out[row] = part + b2;
  }
}

__global__ void k_tiny(float* out, float code) {
  if (threadIdx.x == 0) out[0] = code;
}

// ---------------- launch ----------------
extern "C" void kernel_launch(void* const* d_in, const int* in_sizes, int n_in,
                              void* d_out, int out_size, void* d_ws, size_t ws_size,
                              hipStream_t stream) {
  const float* x     = (const float*)d_in[0];
  const int*   ei    = (const int*)  d_in[1];
  const int*   eli   = (const int*)  d_in[2];
  const float* Wl1   = (const float*)d_in[3];
  const float* bl1   = (const float*)d_in[4];
  const float* Wr1   = (const float*)d_in[5];
  const float* br1   = (const float*)d_in[6];
  const float* att1  = (const float*)d_in[7];
  const float* bias1 = (const float*)d_in[8];
  const float* Wl2   = (const float*)d_in[9];
  const float* bl2   = (const float*)d_in[10];
  const float* Wr2   = (const float*)d_in[11];
  const float* br2   = (const float*)d_in[12];
  const float* att2  = (const float*)d_in[13];
  const float* bias2 = (const float*)d_in[14];
  const float* Wd1   = (const float*)d_in[15];
  const float* bd1   = (const float*)d_in[16];
  const float* Wd2   = (const float*)d_in[17];
  const float* bd2   = (const float*)d_in[18];
  float* out = (float*)d_out;

  constexpr size_t INTW = (size_t)(NN+1) + NN + ETOT;          // 380001 words
  constexpr size_t FULL_WORDS = 3ull*NN*C1 + INTW;             // ~124.4 MB (proven available)
  constexpr size_t CMP_WORDS  = 3ull*NN*C1/2 + INTW;           // ~63 MB

  bool full    = ws_size >= FULL_WORDS*4;
  bool compact = !full && ws_size >= CMP_WORDS*4;
  if (!full && !compact) {
    size_t mb = ws_size >> 20;
    k_tiny<<<1, 64, 0, stream>>>(out, 16384.f + (float)mb);
    return;
  }

  size_t regA = full ? (size_t)NN*C1 : (size_t)NN*C1/2;   // words per region
  char* base = (char*)d_ws;
  void* wA = base;
  void* wB = base + regA*4;
  void* wC = base + 2*regA*4;
  int* row_ptr = (int*)(base + 3*regA*4);
  int* cnt     = row_ptr + (NN + 1);
  int* col     = cnt + NN;
  int* bsum    = (int*)wA;   // scan scratch: wA dead during CSR phase

  // CSR over dst
  hipMemsetAsync(cnt, 0, NN*sizeof(int), stream);
  k_hist<<<(ETOT+255)/256, 256, 0, stream>>>(ei, cnt);
  k_scan_a<<<NB, 256, 0, stream>>>(cnt, row_ptr, bsum);
  k_scan_b<<<1, 128, 0, stream>>>(bsum, row_ptr);
  k_scan_c<<<NB, 256, 0, stream>>>(row_ptr, bsum, cnt);
  k_scatter<<<(ETOT+255)/256, 256, 0, stream>>>(ei, cnt, col);

  if (full) {
    _Float16* xlr1 = (_Float16*)wA;
    _Float16* xlr2 = (_Float16*)wA;
    u16* xth = (u16*)wB;
    u16* xtl = xth + (size_t)NN*INC;
    u16* wt1th = (u16*)((char*)wB + (21u<<20));   // [1024][256]
    u16* wt1tl = wt1th + 1024*256;
    u16* wt2th = wt1tl + 1024*256;                // [256][512]
    u16* wt2tl = wt2th + 256*512;
    u16* wdth  = wt2tl + 256*512;                 // [128][256]
    u16* wdtl  = wdth  + 128*256;
    u16* z1h = (u16*)wC;
    u16* z1l = z1h + (size_t)NN*C1;
    _Float16* z2 = (_Float16*)wC;                 // z1 planes dead after mgemm2

    k_xsplit<<<2048, 256, 0, stream>>>(x, xth, xtl, NN*INC);
    WsArgs wa;
    wa.src[0]=Wl1; wa.th[0]=wt1th;          wa.tl[0]=wt1tl;          wa.K[0]=INC; wa.N[0]=C1;
    wa.src[1]=Wr1; wa.th[1]=wt1th+512*256;  wa.tl[1]=wt1tl+512*256;  wa.K[1]=INC; wa.N[1]=C1;
    wa.src[2]=Wl2; wa.th[2]=wt2th;          wa.tl[2]=wt2tl;          wa.K[2]=C1;  wa.N[2]=C2;
    wa.src[3]=Wr2; wa.th[3]=wt2th+128*512;  wa.tl[3]=wt2tl+128*512;  wa.K[3]=C1;  wa.N[3]=C2;
    wa.src[4]=Wd1; wa.th[4]=wdth;           wa.tl[4]=wdtl;           wa.K[4]=256; wa.N[4]=C2;
    k_wsplit_all<<<dim3(512, 5), 256, 0, stream>>>(wa);

    k_mgemm_a<<<157*8, 256, 0, stream>>>(xth, xtl, wt1th, wt1tl,
                                         bl1, br1, 512, xlr1, NN, 1024, INC, 8);
    k_edge1p<<<NN/4, 256, 0, stream>>>(xlr1, xlr1+512, 1024, att1, bias1, row_ptr, col, z1h, z1l);
    k_mgemm_a<<<157*2, 256, 0, stream>>>(z1h, z1l, wt2th, wt2tl,
                                         bl2, br2, 128, xlr2, NN, 256, C1, 2);
    k_edge2p<<<NN/4, 256, 0, stream>>>(xlr2, xlr2+128, 256, att2, bias2, row_ptr, col, z2);
    k_dec3<<<(ELN+127)/128, 256, 0, stream>>>(z2, eli, wdth, wdtl, bd1, Wd2, bd2, out);
  } else {
    u16* xl1 = (u16*)wA;
    u16* xr1 = (u16*)wB;
    u16* z1  = (u16*)wC;
    float* xl2 = (float*)wA;
    float* xr2 = (float*)wB;
    float* z2  = (float*)wC;
    dim3 g1((NN+63)/64, C1/64);
    dim3 g2((NN+63)/64, C2/64);
    k_gemm<float,u16><<<g1, 256, 0, stream>>>(x, Wl1, bl1, xl1, NN, C1, INC);
    k_gemm<float,u16><<<g1, 256, 0, stream>>>(x, Wr1, br1, xr1, NN, C1, INC);
    k_edge1c<u16,u16><<<NN/4, 256, 0, stream>>>(xl1, xr1, C1, att1, bias1, row_ptr, col, z1);
    k_gemm<u16,float><<<g2, 256, 0, stream>>>(z1, Wl2, bl2, xl2, NN, C2, C1);
    k_gemm<u16,float><<<g2, 256, 0, stream>>>(z1, Wr2, br2, xr2, NN, C2, C1);
    k_edge2c<float,float><<<NN/4, 256, 0, stream>>>(xl2, xr2, C2, att2, bias2, row_ptr, col, z2);
    k_dec2<<<(ELN+63)/64, 256, 0, stream>>>(z2, eli, Wd1, bd1, Wd2, bd2, out);
  }
}

// Round 14
// 344.663 us; speedup vs baseline: 2.5918x; 1.0423x over previous
//
#include <hip/hip_runtime.h>
#include <hip/hip_bf16.h>
#include <math.h>
#include <stdint.h>

using bf16 = __hip_bfloat16;
typedef unsigned short u16;
typedef unsigned int   u32;
typedef __attribute__((ext_vector_type(8))) short short8;   // 8 bf16 bit patterns
typedef __attribute__((ext_vector_type(4))) float f32x4;
typedef _Float16 h2 __attribute__((ext_vector_type(2)));

static constexpr int NN   = 20000;
static constexpr int EE   = 320000;
static constexpr int ELN  = 100000;
static constexpr int ETOT = EE + NN;
static constexpr int INC  = 256;
static constexpr int C1   = 512;
static constexpr int C2   = 128;
static constexpr int NB   = (NN + 255) / 256;   // scan blocks = 79

__device__ __forceinline__ float us2f(u16 u){ union{u32 i; float f;}x; x.i=((u32)u)<<16; return x.f; }
__device__ __forceinline__ u16  f2us(float f){ union{bf16 h; u16 u;}c; c.h=__float2bfloat16(f); return c.u; }
__device__ __forceinline__ float h2f(u16 u){ union{u16 u; _Float16 h;}c; c.u=u; return (float)c.h; }
__device__ __forceinline__ float gelu_f(float x){
  float u = 1.5957691216057308f*(x + 0.044715f*x*x*x);
  float ex = __expf(u);
  float th = 1.f - 2.f/(ex + 1.f);
  return 0.5f*x*(1.f+th);
}
__device__ __forceinline__ void gl_lds16(const u16* g, void* l) {
  __builtin_amdgcn_global_load_lds((const __attribute__((address_space(1))) void*)g,
                                   (__attribute__((address_space(3))) void*)l, 16, 0, 0);
}
__device__ __forceinline__ void ld4v(const float* p, float* o){ float4 v=*(const float4*)p; o[0]=v.x;o[1]=v.y;o[2]=v.z;o[3]=v.w; }
__device__ __forceinline__ void ld4v(const u16* p, float* o){ uint2 v=*(const uint2*)p;
  o[0]=us2f(v.x&0xffff);o[1]=us2f(v.x>>16);o[2]=us2f(v.y&0xffff);o[3]=us2f(v.y>>16); }
__device__ __forceinline__ void ld4v(const _Float16* p, float* o){ uint2 v=*(const uint2*)p;
  o[0]=h2f(v.x&0xffff);o[1]=h2f(v.x>>16);o[2]=h2f(v.y&0xffff);o[3]=h2f(v.y>>16); }
__device__ __forceinline__ void ld8v(const float* p, float* o){ ld4v(p,o); ld4v(p+4,o+4); }
__device__ __forceinline__ void ld8v(const u16* p, float* o){ uint4 v=*(const uint4*)p;
  o[0]=us2f(v.x&0xffff);o[1]=us2f(v.x>>16);o[2]=us2f(v.y&0xffff);o[3]=us2f(v.y>>16);
  o[4]=us2f(v.z&0xffff);o[5]=us2f(v.z>>16);o[6]=us2f(v.w&0xffff);o[7]=us2f(v.w>>16); }
__device__ __forceinline__ void ld8v(const _Float16* p, float* o){ uint4 v=*(const uint4*)p;
  o[0]=h2f(v.x&0xffff);o[1]=h2f(v.x>>16);o[2]=h2f(v.y&0xffff);o[3]=h2f(v.y>>16);
  o[4]=h2f(v.z&0xffff);o[5]=h2f(v.z>>16);o[6]=h2f(v.w&0xffff);o[7]=h2f(v.w>>16); }
__device__ __forceinline__ void ld2v(const float* p, float* o){ float2 v=*(const float2*)p; o[0]=v.x;o[1]=v.y; }
__device__ __forceinline__ void ld2v(const _Float16* p, float* o){ u32 w=*(const u32*)p;
  o[0]=h2f(w&0xffff); o[1]=h2f(w>>16); }
__device__ __forceinline__ void st4v(float* p, const float* v){ *(float4*)p = make_float4(v[0],v[1],v[2],v[3]); }
__device__ __forceinline__ void st4v(u16* p, const float* v){ uint2 o;
  o.x=f2us(v[0])|((u32)f2us(v[1])<<16); o.y=f2us(v[2])|((u32)f2us(v[3])<<16); *(uint2*)p=o; }
__device__ __forceinline__ void st8v(float* p, const float* v){ st4v(p,v); st4v(p+4,v+4); }
__device__ __forceinline__ void st8v(u16* p, const float* v){ uint4 o;
  o.x=f2us(v[0])|((u32)f2us(v[1])<<16); o.y=f2us(v[2])|((u32)f2us(v[3])<<16);
  o.z=f2us(v[4])|((u32)f2us(v[5])<<16); o.w=f2us(v[6])|((u32)f2us(v[7])<<16); *(uint4*)p=o; }

// ---------------- fused preprocessing: xsplit + weight transpose/split + hist ----------------
struct PrepArgs {
  const float* x; u16* xth; u16* xtl; int nx;
  const float* wsrc[5]; u16* wth[5]; u16* wtl[5]; int wK[5]; int wN[5];
  const int* ei; int* cnt;
};
__global__ __launch_bounds__(256) void k_prep(PrepArgs a) {
  int seg = blockIdx.y;
  int tid = blockIdx.x*256 + threadIdx.x;
  int stride = gridDim.x*256;
  if (seg == 0) {
    for (int i = tid; i < a.nx; i += stride) {
      float v = a.x[i];
      u16 h = f2us(v);
      a.xth[i] = h;
      a.xtl[i] = f2us(v - us2f(h));
    }
  } else if (seg <= 5) {
    int s = seg - 1;
    int K = a.wK[s], N = a.wN[s];
    int n = K * N;
    for (int i = tid; i < n; i += stride) {
      int nn = i / K, k = i - nn*K;
      float v = a.wsrc[s][(size_t)k*N + nn];
      u16 h = f2us(v);
      a.wth[s][i] = h;
      a.wtl[s][i] = f2us(v - us2f(h));
    }
  } else {
    for (int e = tid; e < ETOT; e += stride) {
      int d = (e < EE) ? a.ei[EE + e] : (e - EE);
      if ((u32)d < (u32)NN) atomicAdd(&a.cnt[d], 1);
    }
  }
}

// ---------------- CSR scan/scatter ----------------
__global__ void k_scan_a(const int* __restrict__ cnt, int* __restrict__ row_ptr,
                         int* __restrict__ bsum) {
  __shared__ int buf[256];
  int idx = blockIdx.x*256 + threadIdx.x;
  int v = (idx < NN) ? cnt[idx] : 0;
  buf[threadIdx.x] = v;
  __syncthreads();
  for (int off = 1; off < 256; off <<= 1) {
    int t = (threadIdx.x >= off) ? buf[threadIdx.x - off] : 0;
    __syncthreads();
    buf[threadIdx.x] += t;
    __syncthreads();
  }
  if (idx < NN) row_ptr[idx] = buf[threadIdx.x] - v;
  if (threadIdx.x == 255) bsum[blockIdx.x] = buf[255];
}
__global__ void k_scan_b(int* __restrict__ bsum, int* __restrict__ row_ptr) {
  __shared__ int buf[128];
  int v = (threadIdx.x < NB) ? bsum[threadIdx.x] : 0;
  buf[threadIdx.x] = v;
  __syncthreads();
  for (int off = 1; off < 128; off <<= 1) {
    int t = (threadIdx.x >= off) ? buf[threadIdx.x - off] : 0;
    __syncthreads();
    buf[threadIdx.x] += t;
    __syncthreads();
  }
  if (threadIdx.x < NB) bsum[threadIdx.x] = buf[threadIdx.x] - v;
  if (threadIdx.x == 127) row_ptr[NN] = buf[127];
}
__global__ void k_scan_c(int* __restrict__ row_ptr, const int* __restrict__ bsum,
                         int* __restrict__ cur) {
  int idx = blockIdx.x*256 + threadIdx.x;
  if (idx < NN) {
    int v = row_ptr[idx] + bsum[blockIdx.x];
    row_ptr[idx] = v;
    cur[idx] = v;
  }
}
__global__ void k_scatter(const int* __restrict__ ei, int* __restrict__ cur,
                          int* __restrict__ col) {
  int e = blockIdx.x*blockDim.x + threadIdx.x;
  if (e < ETOT) {
    int s, d;
    if (e < EE) { s = ei[e]; d = ei[EE + e]; } else { s = d = e - EE; }
    if ((u32)d >= (u32)NN) d = 0;
    int pos = atomicAdd(&cur[d], 1);
    if ((u32)pos < (u32)ETOT) col[pos] = s;
  }
}

// ---------------- MFMA GEMM, async staging: C(fp16) = A @ B + bias ----------------
__global__ __launch_bounds__(256, 3)
void k_mgemm_a(const u16* __restrict__ Ath, const u16* __restrict__ Atl,
               const u16* __restrict__ Bth, const u16* __restrict__ Btl,
               const float* __restrict__ biasA, const float* __restrict__ biasB, int ncut,
               _Float16* __restrict__ C, int M, int N, int K, int nby) {
  __shared__ __align__(16) u16 sm[17408];
  int tid = threadIdx.x;
  int bidy = blockIdx.x % nby, bidx = blockIdx.x / nby;
  int m0 = bidx * 128, n0 = bidy * 128;
  int wave = tid >> 6, lane = tid & 63;
  int wm = (wave & 1) * 64, wn = (wave >> 1) * 64;
  int l15 = lane & 15, quad = lane >> 4;
  const u16* pbase = (wave == 0) ? Ath : (wave == 1) ? Atl : (wave == 2) ? Bth : Btl;
  bool isA = wave < 2;
  int rbase = isA ? m0 : n0;
  int rseg = lane >> 2;
  int kseg = (lane & 3) * 8;
  f32x4 acc[4][4] = {};
  for (int k0 = 0; k0 < K; k0 += 32) {
    #pragma unroll
    for (int i = 0; i < 8; ++i) {
      int r = rbase + i*16 + rseg;
      if (isA && r > M-1) r = M-1;
      gl_lds16(&pbase[(size_t)r*K + k0 + kseg], (char*)sm + (wave<<13) + (i<<10));
    }
    __syncthreads();
    short8 af_h[4], af_l[4], bf_h[4], bf_l[4];
    #pragma unroll
    for (int i = 0; i < 4; ++i) {
      af_h[i] = *(const short8*)&sm[         (wm + i*16 + l15)*32 + quad*8];
      af_l[i] = *(const short8*)&sm[ 4096 +  (wm + i*16 + l15)*32 + quad*8];
      bf_h[i] = *(const short8*)&sm[ 8192 +  (wn + i*16 + l15)*32 + quad*8];
      bf_l[i] = *(const short8*)&sm[12288 +  (wn + i*16 + l15)*32 + quad*8];
    }
    #pragma unroll
    for (int i = 0; i < 4; ++i)
      #pragma unroll
      for (int j = 0; j < 4; ++j) {
        acc[i][j] = __builtin_amdgcn_mfma_f32_16x16x32_bf16(af_h[i], bf_l[j], acc[i][j], 0,0,0);
        acc[i][j] = __builtin_amdgcn_mfma_f32_16x16x32_bf16(af_l[i], bf_h[j], acc[i][j], 0,0,0);
        acc[i][j] = __builtin_amdgcn_mfma_f32_16x16x32_bf16(af_h[i], bf_h[j], acc[i][j], 0,0,0);
      }
    __syncthreads();
  }
  #pragma unroll
  for (int j = 0; j < 4; ++j) {
    int col = wn + j*16 + l15;
    int colg = n0 + col;
    float bv = (colg < ncut) ? biasA[colg] : biasB[colg - ncut];
    #pragma unroll
    for (int i = 0; i < 4; ++i) {
      int rowb = wm + i*16 + quad*4;
      #pragma unroll
      for (int r = 0; r < 4; ++r) {
        union { _Float16 h; u16 u; } cv;
        cv.h = (_Float16)(acc[i][j][r] + bv);
        sm[(rowb + r)*136 + col] = cv.u;
      }
    }
  }
  __syncthreads();
  int row = tid >> 1, half = (tid & 1) * 64;
  int gr = m0 + row;
  if (gr < M) {
    uint4* d = (uint4*)&C[(size_t)gr*N + n0 + half];
    const uint4* s = (const uint4*)&sm[row*136 + half];
    #pragma unroll
    for (int q = 0; q < 8; ++q) d[q] = s[q];
  }
}

// ---------------- MFMA decoder (z2 fp16, regular loads, in-kernel split) ----------------
__global__ __launch_bounds__(256, 3)
void k_dec3(const _Float16* __restrict__ z2,
            const int* __restrict__ eli,
            const u16* __restrict__ Wth, const u16* __restrict__ Wtl,
            const float* __restrict__ bd1,
            const float* __restrict__ Wd2, const float* __restrict__ bd2,
            float* __restrict__ out) {
  __shared__ __align__(16) u16 Ah[128][32], Al[128][32];
  __shared__ __align__(16) u16 Bh[128][32], Bl[128][32];
  __shared__ float pr[128][2];
  int tid = threadIdx.x;
  int e0 = blockIdx.x * 128;
  int wave = tid >> 6, lane = tid & 63;
  int wm = (wave & 1) * 64, wn = (wave >> 1) * 64;
  int l15 = lane & 15, quad = lane >> 4;
  int ar = tid >> 3;
  int ak = (tid & 7) * 4;
  int bn = tid >> 2;
  int bc = (tid & 3) * 8;
  int ia4[4], ib4[4];
  #pragma unroll
  for (int i = 0; i < 4; ++i) {
    int e = e0 + ar + 32*i;
    bool ev = e < ELN;
    int a = ev ? eli[e] : 0;      if ((u32)a >= (u32)NN) a = 0;
    int b = ev ? eli[ELN+e] : 0;  if ((u32)b >= (u32)NN) b = 0;
    ia4[i] = a; ib4[i] = b;
  }
  f32x4 acc[4][4] = {};
  for (int k0 = 0; k0 < 256; k0 += 32) {
    #pragma unroll
    for (int i = 0; i < 4; ++i) {
      int row = ar + 32*i;
      int kk = k0 + ak;
      const _Float16* src = (kk < 128) ? &z2[(size_t)ia4[i]*128 + kk]
                                       : &z2[(size_t)ib4[i]*128 + (kk - 128)];
      float hv[4];
      ld4v(src, hv);
      u16 hi[4], lo[4];
      #pragma unroll
      for (int j = 0; j < 4; ++j) {
        hi[j] = f2us(hv[j]);
        lo[j] = f2us(hv[j] - us2f(hi[j]));
      }
      *(uint2*)&Ah[row][ak] = make_uint2(hi[0]|((u32)hi[1]<<16), hi[2]|((u32)hi[3]<<16));
      *(uint2*)&Al[row][ak] = make_uint2(lo[0]|((u32)lo[1]<<16), lo[2]|((u32)lo[3]<<16));
    }
    #pragma unroll
    for (int i = 0; i < 2; ++i) {
      int n = bn + 64*i;
      *(uint4*)&Bh[n][bc] = *(const uint4*)&Wth[(size_t)n*256 + k0 + bc];
      *(uint4*)&Bl[n][bc] = *(const uint4*)&Wtl[(size_t)n*256 + k0 + bc];
    }
    __syncthreads();
    short8 af_h[4], af_l[4], bf_h[4], bf_l[4];
    #pragma unroll
    for (int i = 0; i < 4; ++i) {
      af_h[i] = *(const short8*)&Ah[wm + i*16 + l15][quad*8];
      af_l[i] = *(const short8*)&Al[wm + i*16 + l15][quad*8];
      bf_h[i] = *(const short8*)&Bh[wn + i*16 + l15][quad*8];
      bf_l[i] = *(const short8*)&Bl[wn + i*16 + l15][quad*8];
    }
    #pragma unroll
    for (int i = 0; i < 4; ++i)
      #pragma unroll
      for (int j = 0; j < 4; ++j) {
        acc[i][j] = __builtin_amdgcn_mfma_f32_16x16x32_bf16(af_h[i], bf_l[j], acc[i][j], 0,0,0);
        acc[i][j] = __builtin_amdgcn_mfma_f32_16x16x32_bf16(af_l[i], bf_h[j], acc[i][j], 0,0,0);
        acc[i][j] = __builtin_amdgcn_mfma_f32_16x16x32_bf16(af_h[i], bf_h[j], acc[i][j], 0,0,0);
      }
    __syncthreads();
  }
  float w2c[4], bbc[4];
  #pragma unroll
  for (int j = 0; j < 4; ++j) {
    int col = wn + j*16 + l15;
    w2c[j] = Wd2[col];
    bbc[j] = bd1[col];
  }
  #pragma unroll
  for (int i = 0; i < 4; ++i) {
    #pragma unroll
    for (int r = 0; r < 4; ++r) {
      float part = 0.f;
      #pragma unroll
      for (int j = 0; j < 4; ++j)
        part += gelu_f(acc[i][j][r] + bbc[j]) * w2c[j];
      part += __shfl_xor(part,1); part += __shfl_xor(part,2);
      part += __shfl_xor(part,4); part += __shfl_xor(part,8);
      if (l15 == 0) pr[wm + i*16 + quad*4 + r][wn>>6] = part;
    }
  }
  __syncthreads();
  if (tid < 128) {
    int e = e0 + tid;
    if (e < ELN) out[e] = pr[tid][0] + pr[tid][1] + bd2[0];
  }
}

// ---------------- edge layer 1: packed-fp16 math, 4-edge unroll ----------------
__global__ __launch_bounds__(256) void k_edge1p(const _Float16* __restrict__ xl,
                                                const _Float16* __restrict__ xr, int ld,
                                                const float* __restrict__ att,
                                                const float* __restrict__ bias,
                                                const int* __restrict__ row_ptr,
                                                const int* __restrict__ col,
                                                u16* __restrict__ z1h, u16* __restrict__ z1l) {
  int wid = (blockIdx.x*blockDim.x + threadIdx.x) >> 6;
  if (wid >= NN) return;
  int lane = threadIdx.x & 63;
  int c8 = lane*8;
  union Q { uint4 u; h2 h[4]; };
  Q XI; XI.u = *(const uint4*)&xr[(size_t)wid*ld + c8];
  h2 at[4];
  #pragma unroll
  for (int k=0;k<4;++k) { at[k][0] = (_Float16)att[c8+2*k]; at[k][1] = (_Float16)att[c8+2*k+1]; }
  const h2 k02 = {(_Float16)0.2f, (_Float16)0.2f};
  float acc[8] = {};
  float s = 0.f;
  int e0 = __builtin_amdgcn_readfirstlane(row_ptr[wid]);
  int e1 = __builtin_amdgcn_readfirstlane(row_ptr[wid+1]);
  int e = e0;
  for (; e + 4 <= e1; e += 4) {
    int s1 = __builtin_amdgcn_readfirstlane(col[e]);   if ((u32)s1 >= (u32)NN) s1 = 0;
    int s2 = __builtin_amdgcn_readfirstlane(col[e+1]); if ((u32)s2 >= (u32)NN) s2 = 0;
    int s3 = __builtin_amdgcn_readfirstlane(col[e+2]); if ((u32)s3 >= (u32)NN) s3 = 0;
    int s4 = __builtin_amdgcn_readfirstlane(col[e+3]); if ((u32)s4 >= (u32)NN) s4 = 0;
    Q X1, X2, X3, X4;
    X1.u = *(const uint4*)&xl[(size_t)s1*ld + c8];
    X2.u = *(const uint4*)&xl[(size_t)s2*ld + c8];
    X3.u = *(const uint4*)&xl[(size_t)s3*ld + c8];
    X4.u = *(const uint4*)&xl[(size_t)s4*ld + c8];
    float p1 = 0.f, p2 = 0.f, p3 = 0.f, p4 = 0.f;
    #pragma unroll
    for (int k=0;k<4;++k) {
      h2 t1 = XI.h[k] + X1.h[k]; t1 = __builtin_elementwise_max(t1, t1*k02);
      p1 = __builtin_amdgcn_fdot2(t1, at[k], p1, false);
      h2 t2 = XI.h[k] + X2.h[k]; t2 = __builtin_elementwise_max(t2, t2*k02);
      p2 = __builtin_amdgcn_fdot2(t2, at[k], p2, false);
      h2 t3 = XI.h[k] + X3.h[k]; t3 = __builtin_elementwise_max(t3, t3*k02);
      p3 = __builtin_amdgcn_fdot2(t3, at[k], p3, false);
      h2 t4 = XI.h[k] + X4.h[k]; t4 = __builtin_elementwise_max(t4, t4*k02);
      p4 = __builtin_amdgcn_fdot2(t4, at[k], p4, false);
    }
    p1 += __shfl_xor(p1,1); p2 += __shfl_xor(p2,1); p3 += __shfl_xor(p3,1); p4 += __shfl_xor(p4,1);
    p1 += __shfl_xor(p1,2); p2 += __shfl_xor(p2,2); p3 += __shfl_xor(p3,2); p4 += __shfl_xor(p4,2);
    p1 += __shfl_xor(p1,4); p2 += __shfl_xor(p2,4); p3 += __shfl_xor(p3,4); p4 += __shfl_xor(p4,4);
    p1 += __shfl_xor(p1,8); p2 += __shfl_xor(p2,8); p3 += __shfl_xor(p3,8); p4 += __shfl_xor(p4,8);
    float w1 = __expf(p1), w2 = __expf(p2), w3 = __expf(p3), w4 = __expf(p4);
    s += (w1 + w2) + (w3 + w4);
    #pragma unroll
    for (int k=0;k<4;++k) {
      acc[2*k]   += (w1*(float)X1.h[k][0] + w2*(float)X2.h[k][0])
                  + (w3*(float)X3.h[k][0] + w4*(float)X4.h[k][0]);
      acc[2*k+1] += (w1*(float)X1.h[k][1] + w2*(float)X2.h[k][1])
                  + (w3*(float)X3.h[k][1] + w4*(float)X4.h[k][1]);
    }
  }
  for (; e < e1; ++e) {
    int sn = __builtin_amdgcn_readfirstlane(col[e]); if ((u32)sn >= (u32)NN) sn = 0;
    Q XJ; XJ.u = *(const uint4*)&xl[(size_t)sn*ld + c8];
    float p = 0.f;
    #pragma unroll
    for (int k=0;k<4;++k) {
      h2 t = XI.h[k] + XJ.h[k];
      t = __builtin_elementwise_max(t, t*k02);
      p = __builtin_amdgcn_fdot2(t, at[k], p, false);
    }
    p += __shfl_xor(p,1); p += __shfl_xor(p,2);
    p += __shfl_xor(p,4); p += __shfl_xor(p,8);
    float w = __expf(p);
    s += w;
    #pragma unroll
    for (int k=0;k<4;++k) {
      acc[2*k]   += w*(float)XJ.h[k][0];
      acc[2*k+1] += w*(float)XJ.h[k][1];
    }
  }
  float inv = 1.f/s;
  u16 hh[8], ll[8];
  #pragma unroll
  for (int j=0;j<8;++j) {
    float o = gelu_f(acc[j]*inv + bias[c8+j]);
    hh[j] = f2us(o);
    ll[j] = f2us(o - us2f(hh[j]));
  }
  uint4 H, L;
  H.x = hh[0]|((u32)hh[1]<<16); H.y = hh[2]|((u32)hh[3]<<16);
  H.z = hh[4]|((u32)hh[5]<<16); H.w = hh[6]|((u32)hh[7]<<16);
  L.x = ll[0]|((u32)ll[1]<<16); L.y = ll[2]|((u32)ll[3]<<16);
  L.z = ll[4]|((u32)ll[5]<<16); L.w = ll[6]|((u32)ll[7]<<16);
  *(uint4*)&z1h[(size_t)wid*C1 + c8] = H;
  *(uint4*)&z1l[(size_t)wid*C1 + c8] = L;
}

// ---------------- edge layer 2: packed-fp16 math, 4-edge unroll, fp16 z2 out ----------------
__global__ __launch_bounds__(256) void k_edge2p(const _Float16* __restrict__ xl,
                                                const _Float16* __restrict__ xr, int ld,
                                                const float* __restrict__ att,
                                                const float* __restrict__ bias,
                                                const int* __restrict__ row_ptr,
                                                const int* __restrict__ col,
                                                _Float16* __restrict__ z2) {
  int wid = (blockIdx.x*blockDim.x + threadIdx.x) >> 6;
  if (wid >= NN) return;
  int lane = threadIdx.x & 63;
  int c2 = lane*2;
  union W { u32 u; h2 h; };
  W XI; XI.u = *(const u32*)&xr[(size_t)wid*ld + c2];
  h2 at; at[0] = (_Float16)att[c2]; at[1] = (_Float16)att[c2+1];
  const h2 k02 = {(_Float16)0.2f, (_Float16)0.2f};
  float s = 0.f, ac0 = 0.f, ac1 = 0.f;
  int e0 = __builtin_amdgcn_readfirstlane(row_ptr[wid]);
  int e1 = __builtin_amdgcn_readfirstlane(row_ptr[wid+1]);
  int e = e0;
  for (; e + 4 <= e1; e += 4) {
    int s1 = __builtin_amdgcn_readfirstlane(col[e]);   if ((u32)s1 >= (u32)NN) s1 = 0;
    int s2 = __builtin_amdgcn_readfirstlane(col[e+1]); if ((u32)s2 >= (u32)NN) s2 = 0;
    int s3 = __builtin_amdgcn_readfirstlane(col[e+2]); if ((u32)s3 >= (u32)NN) s3 = 0;
    int s4 = __builtin_amdgcn_readfirstlane(col[e+3]); if ((u32)s4 >= (u32)NN) s4 = 0;
    W X1, X2, X3, X4;
    X1.u = *(const u32*)&xl[(size_t)s1*ld + c2];
    X2.u = *(const u32*)&xl[(size_t)s2*ld + c2];
    X3.u = *(const u32*)&xl[(size_t)s3*ld + c2];
    X4.u = *(const u32*)&xl[(size_t)s4*ld + c2];
    h2 t1 = XI.h + X1.h; t1 = __builtin_elementwise_max(t1, t1*k02);
    h2 t2 = XI.h + X2.h; t2 = __builtin_elementwise_max(t2, t2*k02);
    h2 t3 = XI.h + X3.h; t3 = __builtin_elementwise_max(t3, t3*k02);
    h2 t4 = XI.h + X4.h; t4 = __builtin_elementwise_max(t4, t4*k02);
    float p1 = __builtin_amdgcn_fdot2(t1, at, 0.f, false);
    float p2 = __builtin_amdgcn_fdot2(t2, at, 0.f, false);
    float p3 = __builtin_amdgcn_fdot2(t3, at, 0.f, false);
    float p4 = __builtin_amdgcn_fdot2(t4, at, 0.f, false);
    p1 += __shfl_xor(p1,1);  p2 += __shfl_xor(p2,1);  p3 += __shfl_xor(p3,1);  p4 += __shfl_xor(p4,1);
    p1 += __shfl_xor(p1,2);  p2 += __shfl_xor(p2,2);  p3 += __shfl_xor(p3,2);  p4 += __shfl_xor(p4,2);
    p1 += __shfl_xor(p1,4);  p2 += __shfl_xor(p2,4);  p3 += __shfl_xor(p3,4);  p4 += __shfl_xor(p4,4);
    p1 += __shfl_xor(p1,8);  p2 += __shfl_xor(p2,8);  p3 += __shfl_xor(p3,8);  p4 += __shfl_xor(p4,8);
    p1 += __shfl_xor(p1,16); p2 += __shfl_xor(p2,16); p3 += __shfl_xor(p3,16); p4 += __shfl_xor(p4,16);
    p1 += __shfl_xor(p1,32); p2 += __shfl_xor(p2,32); p3 += __shfl_xor(p3,32); p4 += __shfl_xor(p4,32);
    float w1 = __expf(p1), w2 = __expf(p2), w3 = __expf(p3), w4 = __expf(p4);
    s += (w1 + w2) + (w3 + w4);
    ac0 += (w1*(float)X1.h[0] + w2*(float)X2.h[0]) + (w3*(float)X3.h[0] + w4*(float)X4.h[0]);
    ac1 += (w1*(float)X1.h[1] + w2*(float)X2.h[1]) + (w3*(float)X3.h[1] + w4*(float)X4.h[1]);
  }
  for (; e < e1; ++e) {
    int sn = __builtin_amdgcn_readfirstlane(col[e]); if ((u32)sn >= (u32)NN) sn = 0;
    W XJ; XJ.u = *(const u32*)&xl[(size_t)sn*ld + c2];
    h2 t = XI.h + XJ.h;
    t = __builtin_elementwise_max(t, t*k02);
    float p = __builtin_amdgcn_fdot2(t, at, 0.f, false);
    p += __shfl_xor(p,1);  p += __shfl_xor(p,2);
    p += __shfl_xor(p,4);  p += __shfl_xor(p,8);
    p += __shfl_xor(p,16); p += __shfl_xor(p,32);
    float w = __expf(p);
    s += w;
    ac0 += w*(float)XJ.h[0];
    ac1 += w*(float)XJ.h[1];
  }
  float inv = 1.f/s;
  union { h2 h; u32 u; } o;
  o.h[0] = (_Float16)(ac0*inv + bias[c2]);
  o.h[1] = (_Float16)(ac1*inv + bias[c2+1]);
  *(u32*)&z2[(size_t)wid*C2 + c2] = o.u;
}

// ================= compact-path fallback kernels =================
__global__ void k_hist(const int* __restrict__ ei, int* __restrict__ cnt) {
  int e = blockIdx.x*blockDim.x + threadIdx.x;
  if (e < ETOT) {
    int d = (e < EE) ? ei[EE + e] : (e - EE);
    if ((u32)d < (u32)NN) atomicAdd(&cnt[d], 1);
  }
}
template <typename AT, typename CT>
__global__ __launch_bounds__(256) void k_gemm(const AT* __restrict__ A,
                                              const float* __restrict__ W,
                                              const float* __restrict__ bias,
                                              CT* __restrict__ C,
                                              int M, int Nc, int K) {
  __shared__ __align__(16) float As[16][64];
  __shared__ __align__(16) float Bs[16][64];
  int tid = threadIdx.x;
  int m0 = blockIdx.x*64, n0 = blockIdx.y*64;
  int ty = tid >> 4, tx = tid & 15;
  int lrow = tid >> 2;
  int lk   = (tid & 3)*4;
  int wk   = tid >> 4;
  int wn   = (tid & 15)*4;
  float acc[4][4] = {};
  for (int k0 = 0; k0 < K; k0 += 16) {
    int row = m0 + lrow;
    if (row < M) {
      float a4[4]; ld4v(&A[(size_t)row*K + k0 + lk], a4);
      As[lk+0][lrow]=a4[0]; As[lk+1][lrow]=a4[1]; As[lk+2][lrow]=a4[2]; As[lk+3][lrow]=a4[3];
    } else {
      #pragma unroll
      for (int j=0;j<4;++j) As[lk+j][lrow]=0.f;
    }
    {
      float4 bv4 = *(const float4*)&W[(size_t)(k0+wk)*Nc + n0 + wn];
      Bs[wk][wn+0]=bv4.x; Bs[wk][wn+1]=bv4.y; Bs[wk][wn+2]=bv4.z; Bs[wk][wn+3]=bv4.w;
    }
    __syncthreads();
    #pragma unroll
    for (int kk=0;kk<16;++kk) {
      float4 av = *(const float4*)&As[kk][ty*4];
      float4 bv = *(const float4*)&Bs[kk][tx*4];
      float a[4]={av.x,av.y,av.z,av.w}, b[4]={bv.x,bv.y,bv.z,bv.w};
      #pragma unroll
      for (int i=0;i<4;++i)
        #pragma unroll
        for (int j=0;j<4;++j)
          acc[i][j] += a[i]*b[j];
    }
    __syncthreads();
  }
  float bv[4];
  #pragma unroll
  for (int j=0;j<4;++j) bv[j] = bias[n0 + tx*4 + j];
  #pragma unroll
  for (int i=0;i<4;++i) {
    int row = m0 + ty*4 + i;
    if (row < M) {
      float o4[4] = {acc[i][0]+bv[0], acc[i][1]+bv[1], acc[i][2]+bv[2], acc[i][3]+bv[3]};
      st4v(&C[(size_t)row*Nc + n0 + tx*4], o4);
    }
  }
}
template <typename TI, typename TO>
__global__ __launch_bounds__(256) void k_edge1c(const TI* __restrict__ xl,
                                                const TI* __restrict__ xr, int ld,
                                                const float* __restrict__ att,
                                                const float* __restrict__ bias,
                                                const int* __restrict__ row_ptr,
                                                const int* __restrict__ col,
                                                TO* __restrict__ z1) {
  int wid = (blockIdx.x*blockDim.x + threadIdx.x) >> 6;
  if (wid >= NN) return;
  int lane = threadIdx.x & 63;
  int c8 = lane*8;
  float xi[8], av[8], acc[8] = {};
  ld8v(&xr[(size_t)wid*ld + c8], xi);
  #pragma unroll
  for (int j=0;j<8;++j) av[j] = att[c8+j];
  float s = 0.f;
  int e0 = row_ptr[wid], e1 = row_ptr[wid+1];
  for (int e = e0; e < e1; ++e) {
    int sn = col[e]; if ((u32)sn >= (u32)NN) sn = 0;
    float xj[8];
    ld8v(&xl[(size_t)sn*ld + c8], xj);
    float p = 0.f;
    #pragma unroll
    for (int j=0;j<8;++j) {
      float t = xi[j] + xj[j];
      t = fmaxf(t, 0.2f*t);
      p += t*av[j];
    }
    p += __shfl_xor(p,1); p += __shfl_xor(p,2);
    p += __shfl_xor(p,4); p += __shfl_xor(p,8);
    float w = __expf(p);
    s += w;
    #pragma unroll
    for (int j=0;j<8;++j) acc[j] += w*xj[j];
  }
  float inv = 1.f/s, o[8];
  #pragma unroll
  for (int j=0;j<8;++j) o[j] = gelu_f(acc[j]*inv + bias[c8+j]);
  st8v(&z1[(size_t)wid*C1 + c8], o);
}
template <typename TI, typename TO>
__global__ __launch_bounds__(256) void k_edge2c(const TI* __restrict__ xl,
                                                const TI* __restrict__ xr, int ld,
                                                const float* __restrict__ att,
                                                const float* __restrict__ bias,
                                                const int* __restrict__ row_ptr,
                                                const int* __restrict__ col,
                                                TO* __restrict__ z2) {
  int wid = (blockIdx.x*blockDim.x + threadIdx.x) >> 6;
  if (wid >= NN) return;
  int lane = threadIdx.x & 63;
  int c2 = lane*2;
  float xiv[2];
  ld2v(&xr[(size_t)wid*ld + c2], xiv);
  float a0 = att[c2], a1 = att[c2+1];
  float s = 0.f, ac0 = 0.f, ac1 = 0.f;
  int e0 = row_ptr[wid], e1 = row_ptr[wid+1];
  for (int e = e0; e < e1; ++e) {
    int sn = col[e]; if ((u32)sn >= (u32)NN) sn = 0;
    float xj[2];
    ld2v(&xl[(size_t)sn*ld + c2], xj);
    float t0 = xiv[0] + xj[0]; t0 = fmaxf(t0, 0.2f*t0);
    float t1 = xiv[1] + xj[1]; t1 = fmaxf(t1, 0.2f*t1);
    float p = t0*a0 + t1*a1;
    p += __shfl_xor(p,1);  p += __shfl_xor(p,2);
    p += __shfl_xor(p,4);  p += __shfl_xor(p,8);
    p += __shfl_xor(p,16); p += __shfl_xor(p,32);
    float w = __expf(p);
    s += w;
    ac0 += w*xj[0];
    ac1 += w*xj[1];
  }
  float inv = 1.f/s;
  z2[(size_t)wid*C2 + c2]   = (TO)(ac0*inv + bias[c2]);
  z2[(size_t)wid*C2 + c2+1] = (TO)(ac1*inv + bias[c2+1]);
}
__global__ __launch_bounds__(256) void k_dec2(const float* __restrict__ z2,
                                              const int* __restrict__ eli,
                                              const float* __restrict__ Wd1,
                                              const float* __restrict__ bd1,
                                              const float* __restrict__ Wd2,
                                              const float* __restrict__ bd2,
                                              float* __restrict__ out) {
  __shared__ __align__(16) float As[16][64];
  __shared__ __align__(16) float Bs[16][128];
  int tid = threadIdx.x;
  int e0 = blockIdx.x * 64;
  int ty = tid >> 4, tx = tid & 15;
  int lrow = tid >> 2;
  int lk   = (tid & 3) * 4;
  int wk   = tid >> 4;
  int wn   = (tid & 15) * 8;
  int e = e0 + lrow;
  bool ev = e < ELN;
  int ia = ev ? eli[e] : 0;       if ((u32)ia >= (u32)NN) ia = 0;
  int ib = ev ? eli[ELN+e] : 0;   if ((u32)ib >= (u32)NN) ib = 0;
  float acc[4][8] = {};
  for (int k0 = 0; k0 < 256; k0 += 16) {
    int kk4 = k0 + lk;
    const float* src = (kk4 < 128) ? &z2[(size_t)ia*128 + kk4]
                                   : &z2[(size_t)ib*128 + (kk4 - 128)];
    float4 a4 = ev ? *(const float4*)src : make_float4(0.f,0.f,0.f,0.f);
    As[lk+0][lrow]=a4.x; As[lk+1][lrow]=a4.y; As[lk+2][lrow]=a4.z; As[lk+3][lrow]=a4.w;
    *(float4*)&Bs[wk][wn]   = *(const float4*)&Wd1[(size_t)(k0+wk)*128 + wn];
    *(float4*)&Bs[wk][wn+4] = *(const float4*)&Wd1[(size_t)(k0+wk)*128 + wn + 4];
    __syncthreads();
    #pragma unroll
    for (int kk = 0; kk < 16; ++kk) {
      float4 av = *(const float4*)&As[kk][ty*4];
      float a[4] = {av.x, av.y, av.z, av.w};
      float4 b0 = *(const float4*)&Bs[kk][tx*4];
      float4 b1 = *(const float4*)&Bs[kk][64 + tx*4];
      float b[8] = {b0.x,b0.y,b0.z,b0.w,b1.x,b1.y,b1.z,b1.w};
      #pragma unroll
      for (int i = 0; i < 4; ++i)
        #pragma unroll
        for (int j = 0; j < 8; ++j)
          acc[i][j] += a[i]*b[j];
    }
    __syncthreads();
  }
  float w2[8], bb[8];
  #pragma unroll
  for (int j = 0; j < 4; ++j) {
    w2[j]   = Wd2[tx*4+j];      bb[j]   = bd1[tx*4+j];
    w2[j+4] = Wd2[64+tx*4+j];   bb[j+4] = bd1[64+tx*4+j];
  }
  float b2 = bd2[0];
  #pragma unroll
  for (int i = 0; i < 4; ++i) {
    float part = 0.f;
    #pragma unroll
    for (int j = 0; j < 8; ++j)
      part += gelu_f(acc[i][j] + bb[j]) * w2[j];
    part += __shfl_xor(part,1); part += __shfl_xor(part,2);
    part += __shfl_xor(part,4); part += __shfl_xor(part,8);
    int row = e0 + ty*4 + i;
    if (tx == 0 && row < ELN) out[row] = part + b2;
  }
}

__global__ void k_tiny(float* out, float code) {
  if (threadIdx.x == 0) out[0] = code;
}

// ---------------- launch ----------------
extern "C" void kernel_launch(void* const* d_in, const int* in_sizes, int n_in,
                              void* d_out, int out_size, void* d_ws, size_t ws_size,
                              hipStream_t stream) {
  const float* x     = (const float*)d_in[0];
  const int*   ei    = (const int*)  d_in[1];
  const int*   eli   = (const int*)  d_in[2];
  const float* Wl1   = (const float*)d_in[3];
  const float* bl1   = (const float*)d_in[4];
  const float* Wr1   = (const float*)d_in[5];
  const float* br1   = (const float*)d_in[6];
  const float* att1  = (const float*)d_in[7];
  const float* bias1 = (const float*)d_in[8];
  const float* Wl2   = (const float*)d_in[9];
  const float* bl2   = (const float*)d_in[10];
  const float* Wr2   = (const float*)d_in[11];
  const float* br2   = (const float*)d_in[12];
  const float* att2  = (const float*)d_in[13];
  const float* bias2 = (const float*)d_in[14];
  const float* Wd1   = (const float*)d_in[15];
  const float* bd1   = (const float*)d_in[16];
  const float* Wd2   = (const float*)d_in[17];
  const float* bd2   = (const float*)d_in[18];
  float* out = (float*)d_out;

  constexpr size_t INTW = (size_t)(NN+1) + NN + ETOT;          // 380001 words
  constexpr size_t FULL_WORDS = 3ull*NN*C1 + INTW;             // ~124.4 MB (proven available)
  constexpr size_t CMP_WORDS  = 3ull*NN*C1/2 + INTW;           // ~63 MB

  bool full    = ws_size >= FULL_WORDS*4;
  bool compact = !full && ws_size >= CMP_WORDS*4;
  if (!full && !compact) {
    size_t mb = ws_size >> 20;
    k_tiny<<<1, 64, 0, stream>>>(out, 16384.f + (float)mb);
    return;
  }

  size_t regA = full ? (size_t)NN*C1 : (size_t)NN*C1/2;   // words per region
  char* base = (char*)d_ws;
  void* wA = base;
  void* wB = base + regA*4;
  void* wC = base + 2*regA*4;
  int* row_ptr = (int*)(base + 3*regA*4);
  int* cnt     = row_ptr + (NN + 1);
  int* col     = cnt + NN;
  int* bsum    = (int*)wA;   // scan scratch: wA dead during CSR phase

  hipMemsetAsync(cnt, 0, NN*sizeof(int), stream);

  if (full) {
    _Float16* xlr1 = (_Float16*)wA;
    _Float16* xlr2 = (_Float16*)wA;
    u16* xth = (u16*)wB;
    u16* xtl = xth + (size_t)NN*INC;
    u16* wt1th = (u16*)((char*)wB + (21u<<20));   // [1024][256]
    u16* wt1tl = wt1th + 1024*256;
    u16* wt2th = wt1tl + 1024*256;                // [256][512]
    u16* wt2tl = wt2th + 256*512;
    u16* wdth  = wt2tl + 256*512;                 // [128][256]
    u16* wdtl  = wdth  + 128*256;
    u16* z1h = (u16*)wC;
    u16* z1l = z1h + (size_t)NN*C1;
    _Float16* z2 = (_Float16*)wC;                 // z1 planes dead after mgemm2

    // fused preprocessing: xsplit + 5 weight splits + hist in one dispatch
    PrepArgs pa;
    pa.x = x; pa.xth = xth; pa.xtl = xtl; pa.nx = NN*INC;
    pa.wsrc[0]=Wl1; pa.wth[0]=wt1th;         pa.wtl[0]=wt1tl;         pa.wK[0]=INC; pa.wN[0]=C1;
    pa.wsrc[1]=Wr1; pa.wth[1]=wt1th+512*256; pa.wtl[1]=wt1tl+512*256; pa.wK[1]=INC; pa.wN[1]=C1;
    pa.wsrc[2]=Wl2; pa.wth[2]=wt2th;         pa.wtl[2]=wt2tl;         pa.wK[2]=C1;  pa.wN[2]=C2;
    pa.wsrc[3]=Wr2; pa.wth[3]=wt2th+128*512; pa.wtl[3]=wt2tl+128*512; pa.wK[3]=C1;  pa.wN[3]=C2;
    pa.wsrc[4]=Wd1; pa.wth[4]=wdth;          pa.wtl[4]=wdtl;          pa.wK[4]=256; pa.wN[4]=C2;
    pa.ei = ei; pa.cnt = cnt;
    k_prep<<<dim3(1344, 7), 256, 0, stream>>>(pa);

    k_scan_a<<<NB, 256, 0, stream>>>(cnt, row_ptr, bsum);
    k_scan_b<<<1, 128, 0, stream>>>(bsum, row_ptr);
    k_scan_c<<<NB, 256, 0, stream>>>(row_ptr, bsum, cnt);
    k_scatter<<<(ETOT+255)/256, 256, 0, stream>>>(ei, cnt, col);

    k_mgemm_a<<<157*8, 256, 0, stream>>>(xth, xtl, wt1th, wt1tl,
                                         bl1, br1, 512, xlr1, NN, 1024, INC, 8);
    k_edge1p<<<NN/4, 256, 0, stream>>>(xlr1, xlr1+512, 1024, att1, bias1, row_ptr, col, z1h, z1l);
    k_mgemm_a<<<157*2, 256, 0, stream>>>(z1h, z1l, wt2th, wt2tl,
                                         bl2, br2, 128, xlr2, NN, 256, C1, 2);
    k_edge2p<<<NN/4, 256, 0, stream>>>(xlr2, xlr2+128, 256, att2, bias2, row_ptr, col, z2);
    k_dec3<<<(ELN+127)/128, 256, 0, stream>>>(z2, eli, wdth, wdtl, bd1, Wd2, bd2, out);
  } else {
    u16* xl1 = (u16*)wA;
    u16* xr1 = (u16*)wB;
    u16* z1  = (u16*)wC;
    float* xl2 = (float*)wA;
    float* xr2 = (float*)wB;
    float* z2  = (float*)wC;
    k_hist<<<(ETOT+255)/256, 256, 0, stream>>>(ei, cnt);
    k_scan_a<<<NB, 256, 0, stream>>>(cnt, row_ptr, bsum);
    k_scan_b<<<1, 128, 0, stream>>>(bsum, row_ptr);
    k_scan_c<<<NB, 256, 0, stream>>>(row_ptr, bsum, cnt);
    k_scatter<<<(ETOT+255)/256, 256, 0, stream>>>(ei, cnt, col);
    dim3 g1((NN+63)/64, C1/64);
    dim3 g2((NN+63)/64, C2/64);
    k_gemm<float,u16><<<g1, 256, 0, stream>>>(x, Wl1, bl1, xl1, NN, C1, INC);
    k_gemm<float,u16><<<g1, 256, 0, stream>>>(x, Wr1, br1, xr1, NN, C1, INC);
    k_edge1c<u16,u16><<<NN/4, 256, 0, stream>>>(xl1, xr1, C1, att1, bias1, row_ptr, col, z1);
    k_gemm<u16,float><<<g2, 256, 0, stream>>>(z1, Wl2, bl2, xl2, NN, C2, C1);
    k_gemm<u16,float><<<g2, 256, 0, stream>>>(z1, Wr2, br2, xr2, NN, C2, C1);
    k_edge2c<float,float><<<NN/4, 256, 0, stream>>>(xl2, xr2, C2, att2, bias2, row_ptr, col, z2);
    k_dec2<<<(ELN+63)/64, 256, 0, stream>>>(z2, eli, Wd1, bd1, Wd2, bd2, out);
  }
}